// Round 7
// baseline (213.438 us; speedup 1.0000x reference)
//
#include <hip/hip_runtime.h>

typedef unsigned short u16;
typedef unsigned int   u32;

#define NQd 10000
#define NSd 500
#define Bd  32
#define Sd  200
#define Td  199   // S-1
#define Dd  128
#define NR  6368  // Bd*Td
#define PB  208   // padded per-batch stride for ev/invZ/pm/pred_acc

typedef __attribute__((ext_vector_type(8))) short bf16x8;
typedef __attribute__((ext_vector_type(4))) float f32x4;

__device__ __forceinline__ float sigf(float x) {
  return __builtin_amdgcn_rcpf(1.f + __expf(-x));
}
__device__ __forceinline__ float tanh_f(float x) {
  float ax = fminf(fabsf(x), 15.f);
  float e = __expf(2.f * ax);
  float r = 1.f - 2.f * __builtin_amdgcn_rcpf(e + 1.f);
  return copysignf(r, x);
}
__device__ __forceinline__ float bf2f(u16 u) { return __uint_as_float(((u32)u) << 16); }
__device__ __forceinline__ u16 f2bf(float f) {            // round-to-nearest-even
  u32 b = __float_as_uint(f);
  b += 0x7FFFu + ((b >> 16) & 1u);
  return (u16)(b >> 16);
}
__device__ __forceinline__ void unp2(u32 u, float &a, float &b) {
  a = __uint_as_float(u << 16);
  b = __uint_as_float(u & 0xffff0000u);
}
__device__ __forceinline__ void unpack16(uint4 a0, uint4 a1, float* f) {
  unp2(a0.x, f[0], f[1]);  unp2(a0.y, f[2], f[3]);
  unp2(a0.z, f[4], f[5]);  unp2(a0.w, f[6], f[7]);
  unp2(a1.x, f[8], f[9]);  unp2(a1.y, f[10], f[11]);
  unp2(a1.z, f[12], f[13]); unp2(a1.w, f[14], f[15]);
}

struct Args {
  const int *question, *response, *q_nb, *s_nb, *qs_sk;
  const float *emb_q, *emb_s, *emb_r;
  const float *W_ih, *b_ih, *b_hh, *ft_W, *ft_b, *agg_W, *agg_b, *last_W, *last_b;
  const float *q_W, *q_b, *k_W, *k_b, *w_W;
  u16 *tabA, *tabB, *tabC, *tabs1, *tabs2, *states, *embq_bf, *embs_bf, *wts, *wiht;
  float *a_state, *qw, *kw, *scal, *er_part, *ev, *invZ, *pred_acc, *pm;
  int *qid_map, *resp_map;
};

// --- 128-thread / 16-row x 128-col tile machinery -------------------------
// LDS: Wl 128x136 u16 (34,816B) + Al 16x136 u16 (4,352B) = 39,168B -> 4 blk/CU
#define SM16_U16 (128 * 136 + 16 * 136)

__device__ __forceinline__ void stageW128(const u16* Wt, int tid, u16* Wl)
{
  for (int i = tid; i < 2048; i += 128) {
    int col = i >> 4, seg = i & 15;
    *(uint4*)&Wl[col * 136 + seg * 8] = *(const uint4*)&Wt[(long)col * 128 + seg * 8];
  }
}

template <int K>
__device__ __forceinline__ void stageA16(const u16* Atab, const u16* Btab,
                                         const int* nbr, int tile0, int rows,
                                         int tid, u16* Al, int* ids)
{
  int r = tid & 15, k0 = (tid >> 4) * 16;
  int row = tile0 + r; if (row >= rows) row = rows - 1;
  const u16* ap = Atab + (long)row * 128 + k0;
  if (K == 0) {
    *(uint4*)&Al[r * 136 + k0]     = *(const uint4*)ap;
    *(uint4*)&Al[r * 136 + k0 + 8] = *(const uint4*)(ap + 8);
  } else {
    float f[16];
    unpack16(*(const uint4*)ap, *(const uint4*)(ap + 8), f);
    float s[16];
#pragma unroll
    for (int q = 0; q < 16; ++q) s[q] = 0.f;
#pragma unroll
    for (int l = 0; l < K; ++l) ids[l] = nbr[(long)row * K + l];
#pragma unroll
    for (int l = 0; l < K; ++l) {
      const u16* np = Btab + (long)ids[l] * 128 + k0;
      float g[16];
      unpack16(*(const uint4*)np, *(const uint4*)(np + 8), g);
#pragma unroll
      for (int q = 0; q < 16; ++q) s[q] += g[q];
    }
    const float inv = 1.f / (float)K;
#pragma unroll
    for (int q = 0; q < 16; ++q) f[q] += s[q] * inv;
    u32 p[8];
#pragma unroll
    for (int q = 0; q < 8; ++q)
      p[q] = (u32)f2bf(f[2 * q]) | ((u32)f2bf(f[2 * q + 1]) << 16);
    *(uint4*)&Al[r * 136 + k0]     = make_uint4(p[0], p[1], p[2], p[3]);
    *(uint4*)&Al[r * 136 + k0 + 8] = make_uint4(p[4], p[5], p[6], p[7]);
  }
}

// Al := Al + mean_{l<4} Btab[ids[l]]   (f32 math, bf16 repack)
__device__ __forceinline__ void updateA16(const u16* Btab, const int* ids, int tid, u16* Al)
{
  int r = tid & 15, k0 = (tid >> 4) * 16;
  float f[16];
  unpack16(*(const uint4*)&Al[r * 136 + k0], *(const uint4*)&Al[r * 136 + k0 + 8], f);
  float s[16];
#pragma unroll
  for (int q = 0; q < 16; ++q) s[q] = 0.f;
#pragma unroll
  for (int l = 0; l < 4; ++l) {
    const u16* np = Btab + (long)ids[l] * 128 + k0;
    float g[16];
    unpack16(*(const uint4*)np, *(const uint4*)(np + 8), g);
#pragma unroll
    for (int q = 0; q < 16; ++q) s[q] += g[q];
  }
#pragma unroll
  for (int q = 0; q < 16; ++q) f[q] += s[q] * 0.25f;
  u32 p[8];
#pragma unroll
  for (int q = 0; q < 8; ++q)
    p[q] = (u32)f2bf(f[2 * q]) | ((u32)f2bf(f[2 * q + 1]) << 16);
  *(uint4*)&Al[r * 136 + k0]     = make_uint4(p[0], p[1], p[2], p[3]);
  *(uint4*)&Al[r * 136 + k0 + 8] = make_uint4(p[4], p[5], p[6], p[7]);
}

__device__ __forceinline__ void zero4(f32x4 acc[4]) {
#pragma unroll
  for (int nt = 0; nt < 4; ++nt) acc[nt] = (f32x4){0.f, 0.f, 0.f, 0.f};
}

__device__ __forceinline__ void mfma16(const u16* Al, const u16* Wl,
                                       int l15, int quad, int cw4, f32x4 acc[4])
{
#pragma unroll
  for (int kc = 0; kc < 4; ++kc) {
    const int ko = kc * 32 + quad * 8;
    bf16x8 af = *(const bf16x8*)&Al[l15 * 136 + ko];
#pragma unroll
    for (int nt = 0; nt < 4; ++nt)
      acc[nt] = __builtin_amdgcn_mfma_f32_16x16x32_bf16(
          af, *(const bf16x8*)&Wl[(cw4 + nt * 16 + l15) * 136 + ko], acc[nt], 0, 0, 0);
  }
}

__device__ __forceinline__ void epi_tanh_G16(const f32x4 acc[4], const float* cb,
                                             u16* out, int rows, int tile0,
                                             int l15, int quad, int cw4)
{
#pragma unroll
  for (int nt = 0; nt < 4; ++nt) {
    int col = cw4 + nt * 16 + l15;
    float c = cb[col];
#pragma unroll
    for (int i = 0; i < 4; ++i) {
      int row = tile0 + quad * 4 + i;
      if (row < rows) out[(long)row * 128 + col] = f2bf(tanh_f(acc[nt][i] + c));
    }
  }
}

__device__ __forceinline__ void epi_tanh_L16(const f32x4 acc[4], const float* cb,
                                             u16* Al, int l15, int quad, int cw4)
{
#pragma unroll
  for (int nt = 0; nt < 4; ++nt) {
    int col = cw4 + nt * 16 + l15;
    float c = cb[col];
#pragma unroll
    for (int i = 0; i < 4; ++i) {
      int rL = quad * 4 + i;
      Al[rL * 136 + col] = f2bf(tanh_f(acc[nt][i] + c));
    }
  }
}

// ---------------------------------------------------------------------------
// prep_all: bf16 emb copies, transposed bf16 weights, maps, small dots
// ---------------------------------------------------------------------------
__global__ __launch_bounds__(256) void prep_all(Args a)
{
  const int T = gridDim.x * 256;
  for (int i = blockIdx.x * 256 + threadIdx.x; i < 491106; i += T) {
    if (i < 320000) {
      float4 v = *(const float4*)&a.emb_q[(long)i * 4];
      ((uint2*)a.embq_bf)[i] = make_uint2(
          (u32)f2bf(v.x) | ((u32)f2bf(v.y) << 16),
          (u32)f2bf(v.z) | ((u32)f2bf(v.w) << 16));
    } else if (i < 336000) {
      int c = i - 320000;
      float4 v = *(const float4*)&a.emb_s[(long)c * 4];
      ((uint2*)a.embs_bf)[c] = make_uint2(
          (u32)f2bf(v.x) | ((u32)f2bf(v.y) << 16),
          (u32)f2bf(v.z) | ((u32)f2bf(v.w) << 16));
    } else if (i < 417920) {
      int e = i - 336000;
      int seg = e >> 14, r = e & 16383;
      int col = r >> 7, k = r & 127;
      const float* src = (seg < 3) ? (a.agg_W + seg * 16384)
                                   : (seg == 3 ? a.last_W : a.ft_W);
      a.wts[e] = f2bf(src[k * 128 + col]);
    } else if (i < 483456) {
      int e = i - 417920;
      int col = e >> 7, k = e & 127;
      a.wiht[e] = f2bf(a.W_ih[k * 512 + col]);
    } else if (i < 489824) {
      int j = i - 483456;
      int b = j / Td, s = j - b * Td;
      a.qid_map[j]  = a.question[b * Sd + s];
      a.resp_map[j] = a.response[b * Sd + s];
    } else {
      int s = i - 489824;
      if (s < 128) {
        float acc = 0;
        for (int e = 0; e < 128; ++e) acc += a.q_W[s * 128 + e] * a.w_W[e];
        a.qw[s] = acc;
      } else if (s < 256) {
        int d = s - 128; float acc = 0;
        for (int e = 0; e < 128; ++e) acc += a.k_W[d * 128 + e] * a.w_W[128 + e];
        a.kw[d] = acc;
      } else if (s == 256) {
        float acc = 0;
        for (int e = 0; e < 128; ++e) acc += a.q_b[e] * a.w_W[e];
        a.scal[0] = acc;
      } else if (s == 257) {
        float acc = 0;
        for (int e = 0; e < 128; ++e) acc += a.k_b[e] * a.w_W[128 + e];
        a.scal[1] = acc;
      } else {
        int e2 = s - 258, rr = e2 >> 9, col = e2 & 511;
        float acc = a.b_ih[col] + a.b_hh[col];
        for (int d = 0; d < 128; ++d) acc += a.emb_r[rr * Dd + d] * a.W_ih[(128 + d) * 512 + col];
        a.er_part[rr * 512 + col] = acc;
      }
    }
  }
}

// level1m: blocks 0..624: f2 AND f0 (shared gather, two W phases); 625..656: f1
__global__ __launch_bounds__(128) void level1m(Args a)
{
  __shared__ __align__(16) u16 smem[SM16_U16];
  u16* Wl = smem;
  u16* Al = smem + 128 * 136;
  const int i = blockIdx.x, tid = threadIdx.x;
  const int lane = tid & 63, wv = tid >> 6;
  const int l15 = lane & 15, quad = lane >> 4, cw4 = wv * 64;
  f32x4 acc[4];
  int ids[10];
  if (i >= 625) {  // f1 over 500 s-rows
    const int tile0 = (i - 625) * 16;
    stageW128(a.wts + 16384, tid, Wl);
    stageA16<10>(a.embs_bf, a.embq_bf, a.s_nb, tile0, NSd, tid, Al, ids);
    __syncthreads();
    zero4(acc);
    mfma16(Al, Wl, l15, quad, cw4, acc);
    epi_tanh_G16(acc, a.agg_b + 128, a.tabs1, NSd, tile0, l15, quad, cw4);
    return;
  }
  const int tile0 = i * 16;
  stageW128(a.wts + 2 * 16384, tid, Wl);   // aggW2^T
  stageA16<4>(a.embq_bf, a.embs_bf, a.q_nb, tile0, NQd, tid, Al, ids);
  __syncthreads();
  zero4(acc);
  mfma16(Al, Wl, l15, quad, cw4, acc);
  epi_tanh_G16(acc, a.agg_b + 256, a.tabA, NQd, tile0, l15, quad, cw4);  // f2
  __syncthreads();                         // Wl reads done
  stageW128(a.wts, tid, Wl);               // aggW0^T
  __syncthreads();
  zero4(acc);
  mfma16(Al, Wl, l15, quad, cw4, acc);
  epi_tanh_G16(acc, a.agg_b, a.tabB, NQd, tile0, l15, quad, cw4);        // f0
}

// g1k: g1 = tanh((f1 + mean f2[s_nb]) @ W1 + b1), 32 blocks
__global__ __launch_bounds__(128) void g1k(Args a)
{
  __shared__ __align__(16) u16 smem[SM16_U16];
  u16* Wl = smem;
  u16* Al = smem + 128 * 136;
  const int tid = threadIdx.x;
  const int tile0 = blockIdx.x * 16;
  const int lane = tid & 63, wv = tid >> 6;
  const int l15 = lane & 15, quad = lane >> 4, cw4 = wv * 64;
  f32x4 acc[4];
  int ids[10];
  stageW128(a.wts + 16384, tid, Wl);
  stageA16<10>(a.tabs1, a.tabA, a.s_nb, tile0, NSd, tid, Al, ids);  // f1 + mean f2
  __syncthreads();
  zero4(acc);
  mfma16(Al, Wl, l15, quad, cw4, acc);
  epi_tanh_G16(acc, a.agg_b + 128, a.tabs2, NSd, tile0, l15, quad, cw4);
}

// chain4: g0 -> h0 -> agg -> qt fused in-block (g0/h0/agg never hit global)
__global__ __launch_bounds__(128) void chain4(Args a)
{
  __shared__ __align__(16) u16 smem[SM16_U16];
  u16* Wl = smem;
  u16* Al = smem + 128 * 136;
  const int tid = threadIdx.x;
  const int tile0 = blockIdx.x * 16;
  const int lane = tid & 63, wv = tid >> 6;
  const int l15 = lane & 15, quad = lane >> 4, cw4 = wv * 64;
  f32x4 acc[4];
  int ids[4];

  // phase 0: g0 = tanh((f0 + mean f1[q_nb]) @ W0 + b0)
  stageW128(a.wts, tid, Wl);               // aggW0^T (reused for h0)
  stageA16<4>(a.tabB, a.tabs1, a.q_nb, tile0, NQd, tid, Al, ids);
  __syncthreads();
  zero4(acc);
  mfma16(Al, Wl, l15, quad, cw4, acc);
  __syncthreads();
  epi_tanh_L16(acc, a.agg_b, Al, l15, quad, cw4);      // Al = g0
  __syncthreads();
  // phase 1: h0 = tanh((g0 + mean g1[q_nb]) @ W0 + b0)   (same ids!)
  updateA16(a.tabs2, ids, tid, Al);                    // Al = g0 + mean g1
  __syncthreads();
  zero4(acc);
  mfma16(Al, Wl, l15, quad, cw4, acc);
  __syncthreads();
  epi_tanh_L16(acc, a.agg_b, Al, l15, quad, cw4);      // Al = h0
  stageW128(a.wts + 3 * 16384, tid, Wl);               // lastt
  __syncthreads();
  // phase 2: agg = tanh(h0 @ last_W + last_b)
  zero4(acc);
  mfma16(Al, Wl, l15, quad, cw4, acc);
  __syncthreads();
  epi_tanh_L16(acc, a.last_b, Al, l15, quad, cw4);     // Al = agg
  stageW128(a.wts + 4 * 16384, tid, Wl);               // ftt
  __syncthreads();
  // phase 3: qt = relu(agg @ ft_W + ft_b) -> tabA
  zero4(acc);
  mfma16(Al, Wl, l15, quad, cw4, acc);
#pragma unroll
  for (int nt = 0; nt < 4; ++nt) {
    int col = cw4 + nt * 16 + l15;
    float cb = a.ft_b[col];
#pragma unroll
    for (int i = 0; i < 4; ++i) {
      int row = tile0 + quad * 4 + i;
      a.tabA[(long)row * 128 + col] = f2bf(fmaxf(acc[nt][i] + cb, 0.f));
    }
  }
}

// gates (i,g,o) + LSTM pointwise + a_state. 398 blocks x 16 rows.
__global__ __launch_bounds__(128) void gates_k(Args a)
{
  __shared__ __align__(16) u16 smem[SM16_U16];
  u16* Wl = smem;
  u16* Al = smem + 128 * 136;
  const int tid = threadIdx.x;
  const int tile0 = blockIdx.x * 16;
  {
    int r = tid & 15, k0 = (tid >> 4) * 16;
    int row = tile0 + r;                    // NR = 398*16 exact
    int arow = a.qid_map[row];
    const u16* ap = a.tabA + (long)arow * 128 + k0;
    *(uint4*)&Al[r * 136 + k0]     = *(const uint4*)ap;
    *(uint4*)&Al[r * 136 + k0 + 8] = *(const uint4*)(ap + 8);
  }
  const int lane = tid & 63, wv = tid >> 6;
  const int l15 = lane & 15, quad = lane >> 4, cw4 = wv * 64;
  f32x4 acc[3][4];
  const int goff[3] = {0, 256, 384};
#pragma unroll
  for (int p = 0; p < 3; ++p) {
    __syncthreads();
    stageW128(a.wiht + (long)goff[p] * 128, tid, Wl);
    __syncthreads();
    zero4(acc[p]);
    mfma16(Al, Wl, l15, quad, cw4, acc[p]);
  }
  __syncthreads();
  float* hb = (float*)Wl;    // [16][132] f32 = 8448B, fits Wl region
#pragma unroll
  for (int nt = 0; nt < 4; ++nt) {
    int col = cw4 + nt * 16 + l15;
#pragma unroll
    for (int i = 0; i < 4; ++i) {
      int rL = quad * 4 + i;
      int row = tile0 + rL;
      const float* rb = a.er_part + (long)a.resp_map[row] * 512;
      float iv = acc[0][nt][i] + rb[col];
      float gv = acc[1][nt][i] + rb[256 + col];
      float ov = acc[2][nt][i] + rb[384 + col];
      float c = sigf(iv) * tanh_f(gv);
      float h = sigf(ov) * tanh_f(c);
      a.states[(long)row * 128 + col] = f2bf(h);
      hb[rL * 132 + col] = h;
    }
  }
  __syncthreads();
#pragma unroll
  for (int rr = 0; rr < 8; ++rr) {
    int rL = wv * 8 + rr;
    float p = hb[rL * 132 + lane] * a.qw[lane] + hb[rL * 132 + 64 + lane] * a.qw[64 + lane];
#pragma unroll
    for (int off = 32; off > 0; off >>= 1) p += __shfl_xor(p, off);
    if (lane == 0) a.a_state[tile0 + rL] = p + a.scal[0];
  }
}

// ---------------------------------------------------------------------------
// bprep: per-batch: gmax -> ev, prefix-scan Z -> invZ, pm softmax5, zero pred_acc
// ---------------------------------------------------------------------------
__global__ __launch_bounds__(256) void bprep(Args a)
{
  __shared__ float red[256];
  __shared__ float evl[256];
  __shared__ float kwl[128];
  const int b = blockIdx.x, tid = threadIdx.x;
  if (tid < 128) kwl[tid] = a.kw[tid];
  float v = (tid < Td) ? a.a_state[b * Td + tid] : -1e30f;
  red[tid] = v; __syncthreads();
  for (int s = 128; s > 0; s >>= 1) { if (tid < s) red[tid] = fmaxf(red[tid], red[tid + s]); __syncthreads(); }
  float gmax = red[0];
  float e = (tid < Td) ? __expf(v - gmax) : 0.f;
  evl[tid] = e;
  if (tid < Td) { a.ev[b * PB + tid] = e; a.pred_acc[b * PB + tid] = 0.f; }
  __syncthreads();
  // inclusive Hillis–Steele scan
  for (int off = 1; off < 256; off <<= 1) {
    float add = (tid >= off) ? evl[tid - off] : 0.f;
    __syncthreads();
    evl[tid] += add;
    __syncthreads();
  }
  if (tid < Td) {
    a.invZ[b * PB + tid] = 1.f / evl[tid];
    // pm softmax over 5 m's for (b, t=tid)
    int qn = a.question[b * Sd + tid + 1];
    float am[5];
#pragma unroll
    for (int m = 0; m < 5; ++m) {
      const u16* src = (m == 0) ? a.embq_bf + (long)qn * 128
                                : a.embs_bf + (long)a.qs_sk[qn * 4 + (m - 1)] * 128;
      float s = 0.f;
      for (int k = 0; k < 128; k += 8) {
        uint4 u = *(const uint4*)&src[k];
        float f[8];
        unp2(u.x, f[0], f[1]); unp2(u.y, f[2], f[3]);
        unp2(u.z, f[4], f[5]); unp2(u.w, f[6], f[7]);
#pragma unroll
        for (int q = 0; q < 8; ++q) s = fmaf(f[q], kwl[k + q], s);
      }
      am[m] = s + a.scal[1];
    }
    float mx = am[0];
#pragma unroll
    for (int m = 1; m < 5; ++m) mx = fmaxf(mx, am[m]);
    float ex[5], z = 0.f;
#pragma unroll
    for (int m = 0; m < 5; ++m) { ex[m] = __expf(am[m] - mx); z += ex[m]; }
    float iz = 1.f / z;
#pragma unroll
    for (int m = 0; m < 5; ++m) a.pm[((long)b * PB + tid) * 5 + m] = ex[m] * iz;
  }
}

// ---------------------------------------------------------------------------
// gk_pred: sigmoid(states.qs) * ev[n] * pm[t,m] reduced into pred_acc[b,t]
// ---------------------------------------------------------------------------
__global__ __launch_bounds__(256) void gk_pred(Args a)
{
  const int n0 = blockIdx.x * 32;
  const int c0 = blockIdx.y * 128;
  const int b  = blockIdx.z;
  int c_hi = c0 + 127; if (c_hi > 994) c_hi = 994;
  const int tmax = c_hi / 5, tmin = c0 / 5;
  if (n0 > tmax) return;

  __shared__ __align__(16) u16 smem[128 * 136 + 32 * 136];
  __shared__ float predl[32];
  u16* Ql = smem;
  u16* Sl = smem + 128 * 136;
  const int tid = threadIdx.x;
  if (tid < 32) predl[tid] = 0.f;
  {
    int r = tid & 31, k0 = (tid >> 5) * 16;
    int n = n0 + r; if (n > 198) n = 198;
    const u16* sp = a.states + ((long)b * Td + n) * 128 + k0;
    *(uint4*)&Sl[r * 136 + k0]     = *(const uint4*)sp;
    *(uint4*)&Sl[r * 136 + k0 + 8] = *(const uint4*)(sp + 8);
  }
  {
    int j = tid >> 1, k0 = (tid & 1) * 64;
    int col = c0 + j;
    uint4* dst = (uint4*)&Ql[j * 136 + k0];
    if (col < 995) {
      int t = col / 5, m = col - t * 5;
      int qn = a.question[b * Sd + t + 1];
      const u16* src = (m == 0) ? a.embq_bf + (long)qn * 128
                                : a.embs_bf + (long)a.qs_sk[qn * 4 + (m - 1)] * 128;
      src += k0;
#pragma unroll
      for (int q = 0; q < 8; ++q) dst[q] = ((const uint4*)src)[q];
    } else {
      uint4 z = make_uint4(0, 0, 0, 0);
#pragma unroll
      for (int q = 0; q < 8; ++q) dst[q] = z;
    }
  }
  __syncthreads();
  const int lane = tid & 63, wv = tid >> 6;
  const int l15 = lane & 15, quad = lane >> 4;
  const int cw = wv * 32;
  f32x4 acc[2][2];
#pragma unroll
  for (int x = 0; x < 2; ++x)
#pragma unroll
    for (int y = 0; y < 2; ++y) acc[x][y] = (f32x4){0.f, 0.f, 0.f, 0.f};
#pragma unroll
  for (int kc = 0; kc < 4; ++kc) {
    const int ko = kc * 32 + quad * 8;
    bf16x8 af[2], bfv[2];
    af[0]  = *(const bf16x8*)&Sl[l15 * 136 + ko];
    af[1]  = *(const bf16x8*)&Sl[(16 + l15) * 136 + ko];
    bfv[0] = *(const bf16x8*)&Ql[(cw + l15) * 136 + ko];
    bfv[1] = *(const bf16x8*)&Ql[(cw + 16 + l15) * 136 + ko];
#pragma unroll
    for (int mt = 0; mt < 2; ++mt)
#pragma unroll
      for (int nt = 0; nt < 2; ++nt)
        acc[mt][nt] = __builtin_amdgcn_mfma_f32_16x16x32_bf16(af[mt], bfv[nt], acc[mt][nt], 0, 0, 0);
  }

#pragma unroll
  for (int nt = 0; nt < 2; ++nt) {
    int col = c0 + cw + nt * 16 + l15;
    if (col >= 995) continue;
    int t = col / 5, m = col - t * 5;
    float pmv = a.pm[((long)b * PB + t) * 5 + m];
    float part = 0.f;
#pragma unroll
    for (int mt = 0; mt < 2; ++mt) {
      int nb = n0 + mt * 16 + quad * 4;
      if (nb > t) continue;
      float4 ev4 = *(const float4*)&a.ev[b * PB + nb];
      float evv[4] = {ev4.x, ev4.y, ev4.z, ev4.w};
#pragma unroll
      for (int i = 0; i < 4; ++i) {
        int n = nb + i;
        if (n > t || n > 198) continue;
        part += evv[i] * sigf(acc[mt][nt][i]);
      }
    }
    part *= pmv;
    if (part != 0.f) atomicAdd(&predl[t - tmin], part);
  }
  __syncthreads();
  const int tcnt = tmax - tmin + 1;
  if (tid < tcnt) {
    float pv = predl[tid];
    if (pv != 0.f) atomicAdd(&a.pred_acc[b * PB + tmin + tid], pv);
  }
}

// finalize: out[b,0]=0; out[b,t+1] = pred_acc[b,t] * invZ[b,t]
__global__ __launch_bounds__(256) void finalize(Args a, float* __restrict__ out)
{
  int i = blockIdx.x * 256 + threadIdx.x;
  if (i >= Bd * Sd) return;
  int b = i / Sd, s = i - b * Sd;
  out[i] = (s == 0) ? 0.f : a.pred_acc[b * PB + s - 1] * a.invZ[b * PB + s - 1];
}

// ---------------------------------------------------------------------------
extern "C" void kernel_launch(void* const* d_in, const int* in_sizes, int n_in,
                              void* d_out, int out_size, void* d_ws, size_t ws_size,
                              hipStream_t stream)
{
  Args a;
  a.question = (const int*)d_in[0];
  a.response = (const int*)d_in[1];
  a.q_nb     = (const int*)d_in[3];
  a.s_nb     = (const int*)d_in[4];
  a.qs_sk    = (const int*)d_in[5];
  a.emb_q    = (const float*)d_in[6];
  a.emb_s    = (const float*)d_in[7];
  a.emb_r    = (const float*)d_in[8];
  a.W_ih     = (const float*)d_in[9];
  a.b_ih     = (const float*)d_in[10];
  a.b_hh     = (const float*)d_in[11];
  a.ft_W     = (const float*)d_in[12];
  a.ft_b     = (const float*)d_in[13];
  a.agg_W    = (const float*)d_in[14];
  a.agg_b    = (const float*)d_in[15];
  a.last_W   = (const float*)d_in[16];
  a.last_b   = (const float*)d_in[17];
  a.q_W      = (const float*)d_in[18];
  a.q_b      = (const float*)d_in[19];
  a.k_W      = (const float*)d_in[20];
  a.k_b      = (const float*)d_in[21];
  a.w_W      = (const float*)d_in[22];

  u16* wsu = (u16*)d_ws;
  const long NT = 1280000, ST = 64000, RT = (long)NR * Dd;
  a.tabA  = wsu;                 // NT (f2, later qt)
  a.tabB  = a.tabA + NT;         // NT (f0)
  a.tabC  = a.tabB + NT;         // NT (unused now)
  a.tabs1 = a.tabC + NT;         // ST (f1)
  a.tabs2 = a.tabs1 + ST;        // ST (g1)
  a.states  = a.tabs2 + ST;      // RT
  a.embq_bf = a.states + RT;     // NT
  a.embs_bf = a.embq_bf + NT;    // ST
  a.wts     = a.embs_bf + ST;    // 5*16384
  a.wiht    = a.wts + 5 * 16384; // 65536
  float* fp = (float*)(a.wiht + 65536);
  a.a_state = fp;                       // 6368
  a.qw      = fp + 6368;                // 128
  a.kw      = fp + 6496;                // 128
  a.scal    = fp + 6624;                // 16
  a.er_part = fp + 6640;                // 1024
  a.ev       = fp + 7664;               // 32*208
  a.invZ     = a.ev + 32 * PB;
  a.pred_acc = a.invZ + 32 * PB;
  a.pm       = a.pred_acc + 32 * PB;    // 32*208*5
  a.qid_map  = (int*)(a.pm + 32 * PB * 5);
  a.resp_map = a.qid_map + NR;

  float* out = (float*)d_out;

  prep_all<<<640, 256, 0, stream>>>(a);
  level1m<<<657, 128, 0, stream>>>(a);
  g1k<<<32, 128, 0, stream>>>(a);
  chain4<<<625, 128, 0, stream>>>(a);
  gates_k<<<398, 128, 0, stream>>>(a);
  bprep<<<Bd, 256, 0, stream>>>(a);
  gk_pred<<<dim3(7, 8, Bd), 256, 0, stream>>>(a);
  finalize<<<25, 256, 0, stream>>>(a, out);
}

// Round 8
// 197.493 us; speedup vs baseline: 1.0807x; 1.0807x over previous
//
#include <hip/hip_runtime.h>

typedef unsigned short u16;
typedef unsigned int   u32;

#define NQd 10000
#define NSd 500
#define Bd  32
#define Sd  200
#define Td  199   // S-1
#define Dd  128
#define NR  6368  // Bd*Td
#define PB  208   // padded per-batch stride for ev/invZ/pm/pred_acc

typedef __attribute__((ext_vector_type(8))) short bf16x8;
typedef __attribute__((ext_vector_type(4))) float f32x4;

__device__ __forceinline__ float sigf(float x) {
  return __builtin_amdgcn_rcpf(1.f + __expf(-x));
}
__device__ __forceinline__ float tanh_f(float x) {
  float ax = fminf(fabsf(x), 15.f);
  float e = __expf(2.f * ax);
  float r = 1.f - 2.f * __builtin_amdgcn_rcpf(e + 1.f);
  return copysignf(r, x);
}
__device__ __forceinline__ float bf2f(u16 u) { return __uint_as_float(((u32)u) << 16); }
__device__ __forceinline__ u16 f2bf(float f) {            // round-to-nearest-even
  u32 b = __float_as_uint(f);
  b += 0x7FFFu + ((b >> 16) & 1u);
  return (u16)(b >> 16);
}
__device__ __forceinline__ void unp2(u32 u, float &a, float &b) {
  a = __uint_as_float(u << 16);
  b = __uint_as_float(u & 0xffff0000u);
}
__device__ __forceinline__ void unpack16(uint4 a0, uint4 a1, float* f) {
  unp2(a0.x, f[0], f[1]);  unp2(a0.y, f[2], f[3]);
  unp2(a0.z, f[4], f[5]);  unp2(a0.w, f[6], f[7]);
  unp2(a1.x, f[8], f[9]);  unp2(a1.y, f[10], f[11]);
  unp2(a1.z, f[12], f[13]); unp2(a1.w, f[14], f[15]);
}

struct Args {
  const int *question, *response, *q_nb, *s_nb, *qs_sk;
  const float *emb_q, *emb_s, *emb_r;
  const float *W_ih, *b_ih, *b_hh, *ft_W, *ft_b, *agg_W, *agg_b, *last_W, *last_b;
  const float *q_W, *q_b, *k_W, *k_b, *w_W;
  u16 *tabA, *tabB, *tabs1, *tabs2, *states, *embq_bf, *embs_bf, *wts, *wiht;
  float *a_state, *qw, *kw, *scal, *er_part, *ev, *invZ, *pred_acc, *pm;
  int *qid_map, *resp_map;
};

// LDS: 21760 u16 = 43,520 B.  Wl = [0,17408) u16; Al = [17408, 21760).
#define SMEM_U16 21760

__device__ __forceinline__ void mfma_accum(const u16* Al, const u16* Wl,
                                           int l15, int quad, int cw, f32x4 acc[2][2])
{
#pragma unroll
  for (int kc = 0; kc < 4; ++kc) {
    const int ko = kc * 32 + quad * 8;
    bf16x8 af[2], bfv[2];
    af[0]  = *(const bf16x8*)&Al[l15 * 136 + ko];
    af[1]  = *(const bf16x8*)&Al[(16 + l15) * 136 + ko];
    bfv[0] = *(const bf16x8*)&Wl[(cw + l15) * 136 + ko];
    bfv[1] = *(const bf16x8*)&Wl[(cw + 16 + l15) * 136 + ko];
#pragma unroll
    for (int mt = 0; mt < 2; ++mt)
#pragma unroll
      for (int nt = 0; nt < 2; ++nt)
        acc[mt][nt] = __builtin_amdgcn_mfma_f32_16x16x32_bf16(af[mt], bfv[nt], acc[mt][nt], 0, 0, 0);
  }
}

__device__ __forceinline__ void zero_acc(f32x4 acc[2][2]) {
#pragma unroll
  for (int x = 0; x < 2; ++x)
#pragma unroll
    for (int y = 0; y < 2; ++y) acc[x][y] = (f32x4){0.f, 0.f, 0.f, 0.f};
}

// stage one 32-row gathered input tile into Al (bf16), K = neighbor count
__device__ __forceinline__ void stage_A(const u16* Atab, const u16* Btab,
                                        const int* nbr, int K, int tile0, int rows,
                                        int tid, u16* Al)
{
  int r = tid & 31, k0 = (tid >> 5) * 16;
  int row = tile0 + r; if (row >= rows) row = rows - 1;
  const u16* ap = Atab + (long)row * 128 + k0;
  if (K == 0) {
    *(uint4*)&Al[r * 136 + k0]     = *(const uint4*)ap;
    *(uint4*)&Al[r * 136 + k0 + 8] = *(const uint4*)(ap + 8);
  } else {
    float f[16];
    unpack16(*(const uint4*)ap, *(const uint4*)(ap + 8), f);
    float s[16];
#pragma unroll
    for (int q = 0; q < 16; ++q) s[q] = 0.f;
    for (int l = 0; l < K; ++l) {
      int id = nbr[(long)row * K + l];
      const u16* np = Btab + (long)id * 128 + k0;
      float g[16];
      unpack16(*(const uint4*)np, *(const uint4*)(np + 8), g);
#pragma unroll
      for (int q = 0; q < 16; ++q) s[q] += g[q];
    }
    float inv = 1.f / (float)K;
#pragma unroll
    for (int q = 0; q < 16; ++q) f[q] += s[q] * inv;
    u32 p[8];
#pragma unroll
    for (int q = 0; q < 8; ++q)
      p[q] = (u32)f2bf(f[2 * q]) | ((u32)f2bf(f[2 * q + 1]) << 16);
    *(uint4*)&Al[r * 136 + k0]     = make_uint4(p[0], p[1], p[2], p[3]);
    *(uint4*)&Al[r * 136 + k0 + 8] = make_uint4(p[4], p[5], p[6], p[7]);
  }
}

// Al := bf16(Al + mean_{l<4} Btab[nbr[row*4+l]])  (ids reloaded, L2-hot)
__device__ __forceinline__ void update_A(const u16* Btab, const int* nbr,
                                         int tile0, int rows, int tid, u16* Al)
{
  int r = tid & 31, k0 = (tid >> 5) * 16;
  int row = tile0 + r; if (row >= rows) row = rows - 1;
  float f[16];
  unpack16(*(const uint4*)&Al[r * 136 + k0], *(const uint4*)&Al[r * 136 + k0 + 8], f);
  float s[16];
#pragma unroll
  for (int q = 0; q < 16; ++q) s[q] = 0.f;
#pragma unroll
  for (int l = 0; l < 4; ++l) {
    int id = nbr[(long)row * 4 + l];
    const u16* np = Btab + (long)id * 128 + k0;
    float g[16];
    unpack16(*(const uint4*)np, *(const uint4*)(np + 8), g);
#pragma unroll
    for (int q = 0; q < 16; ++q) s[q] += g[q];
  }
#pragma unroll
  for (int q = 0; q < 16; ++q) f[q] += s[q] * 0.25f;
  u32 p[8];
#pragma unroll
  for (int q = 0; q < 8; ++q)
    p[q] = (u32)f2bf(f[2 * q]) | ((u32)f2bf(f[2 * q + 1]) << 16);
  *(uint4*)&Al[r * 136 + k0]     = make_uint4(p[0], p[1], p[2], p[3]);
  *(uint4*)&Al[r * 136 + k0 + 8] = make_uint4(p[4], p[5], p[6], p[7]);
}

__device__ __forceinline__ void stage_W(const u16* Wt, int tid, u16* Wl)
{
  for (int i = tid; i < 2048; i += 256) {
    int col = i >> 4, seg = i & 15;
    *(uint4*)&Wl[col * 136 + seg * 8] = *(const uint4*)&Wt[(long)col * 128 + seg * 8];
  }
}

// epilogue: tanh -> global table
__device__ __forceinline__ void epi_tanh_global(const f32x4 acc[2][2], const float* cbias,
                                                u16* out, int rows, int tile0,
                                                int l15, int quad, int cw)
{
#pragma unroll
  for (int nt = 0; nt < 2; ++nt) {
    int col = cw + nt * 16 + l15;
    float cb = cbias[col];
#pragma unroll
    for (int mt = 0; mt < 2; ++mt) {
      int rbase = tile0 + mt * 16 + quad * 4;
#pragma unroll
      for (int i = 0; i < 4; ++i) {
        int row = rbase + i;
        if (row >= rows) continue;
        out[(long)row * 128 + col] = f2bf(tanh_f(acc[mt][nt][i] + cb));
      }
    }
  }
}

// epilogue: tanh -> LDS Al
__device__ __forceinline__ void epi_tanh_lds(const f32x4 acc[2][2], const float* cbias,
                                             u16* Al, int l15, int quad, int cw)
{
#pragma unroll
  for (int nt = 0; nt < 2; ++nt) {
    int col = cw + nt * 16 + l15;
    float cb = cbias[col];
#pragma unroll
    for (int mt = 0; mt < 2; ++mt)
#pragma unroll
      for (int i = 0; i < 4; ++i) {
        int rL = mt * 16 + quad * 4 + i;
        Al[rL * 136 + col] = f2bf(tanh_f(acc[mt][nt][i] + cb));
      }
  }
}

// full 32x128 GEMM tile: out = tanh(in @ Wt^T + cbias)
__device__ __forceinline__ void gemm_tile(
    const u16* __restrict__ Atab, const u16* __restrict__ Btab,
    const int* __restrict__ nbr, int K,
    const u16* __restrict__ Wt, const float* __restrict__ cbias,
    u16* __restrict__ out, int rows, int tile0, int tid, u16* smem)
{
  u16* Wl = smem;
  u16* Al = smem + 17408;
  stage_W(Wt, tid, Wl);
  stage_A(Atab, Btab, nbr, K, tile0, rows, tid, Al);
  __syncthreads();
  const int lane = tid & 63, wv = tid >> 6;
  const int l15 = lane & 15, quad = lane >> 4, cw = wv * 32;
  f32x4 acc[2][2];
  zero_acc(acc);
  mfma_accum(Al, Wl, l15, quad, cw, acc);
  epi_tanh_global(acc, cbias, out, rows, tile0, l15, quad, cw);
}

// ---------------------------------------------------------------------------
// prep_all: bf16 emb copies, transposed bf16 weights, maps, small dots
// ---------------------------------------------------------------------------
__global__ __launch_bounds__(256) void prep_all(Args a)
{
  const int T = gridDim.x * 256;
  for (int i = blockIdx.x * 256 + threadIdx.x; i < 491106; i += T) {
    if (i < 320000) {
      float4 v = *(const float4*)&a.emb_q[(long)i * 4];
      ((uint2*)a.embq_bf)[i] = make_uint2(
          (u32)f2bf(v.x) | ((u32)f2bf(v.y) << 16),
          (u32)f2bf(v.z) | ((u32)f2bf(v.w) << 16));
    } else if (i < 336000) {
      int c = i - 320000;
      float4 v = *(const float4*)&a.emb_s[(long)c * 4];
      ((uint2*)a.embs_bf)[c] = make_uint2(
          (u32)f2bf(v.x) | ((u32)f2bf(v.y) << 16),
          (u32)f2bf(v.z) | ((u32)f2bf(v.w) << 16));
    } else if (i < 417920) {
      int e = i - 336000;
      int seg = e >> 14, r = e & 16383;
      int col = r >> 7, k = r & 127;
      const float* src = (seg < 3) ? (a.agg_W + seg * 16384)
                                   : (seg == 3 ? a.last_W : a.ft_W);
      a.wts[e] = f2bf(src[k * 128 + col]);
    } else if (i < 483456) {
      int e = i - 417920;
      int col = e >> 7, k = e & 127;
      a.wiht[e] = f2bf(a.W_ih[k * 512 + col]);
    } else if (i < 489824) {
      int j = i - 483456;
      int b = j / Td, s = j - b * Td;
      a.qid_map[j]  = a.question[b * Sd + s];
      a.resp_map[j] = a.response[b * Sd + s];
    } else {
      int s = i - 489824;
      if (s < 128) {
        float acc = 0;
        for (int e = 0; e < 128; ++e) acc += a.q_W[s * 128 + e] * a.w_W[e];
        a.qw[s] = acc;
      } else if (s < 256) {
        int d = s - 128; float acc = 0;
        for (int e = 0; e < 128; ++e) acc += a.k_W[d * 128 + e] * a.w_W[128 + e];
        a.kw[d] = acc;
      } else if (s == 256) {
        float acc = 0;
        for (int e = 0; e < 128; ++e) acc += a.q_b[e] * a.w_W[e];
        a.scal[0] = acc;
      } else if (s == 257) {
        float acc = 0;
        for (int e = 0; e < 128; ++e) acc += a.k_b[e] * a.w_W[128 + e];
        a.scal[1] = acc;
      } else {
        int e2 = s - 258, rr = e2 >> 9, col = e2 & 511;
        float acc = a.b_ih[col] + a.b_hh[col];
        for (int d = 0; d < 128; ++d) acc += a.emb_r[rr * Dd + d] * a.W_ih[(128 + d) * 512 + col];
        a.er_part[rr * 512 + col] = acc;
      }
    }
  }
}

// level1m: blocks 0..312: f2 AND f0 from ONE gathered A-tile; 313..328: f1
__global__ __launch_bounds__(256) void level1m(Args a)
{
  __shared__ __align__(16) u16 smem[SMEM_U16];
  const int i = blockIdx.x, tid = threadIdx.x;
  if (i >= 313) {
    gemm_tile(a.embs_bf, a.embq_bf, a.s_nb, 10, a.wts + 16384,
              a.agg_b + 128, a.tabs1, NSd, (i - 313) * 32, tid, smem);
    return;
  }
  u16* Wl = smem;
  u16* Al = smem + 17408;
  const int tile0 = i * 32;
  const int lane = tid & 63, wv = tid >> 6;
  const int l15 = lane & 15, quad = lane >> 4, cw = wv * 32;
  f32x4 acc[2][2];
  stage_W(a.wts + 2 * 16384, tid, Wl);       // aggW2^T
  stage_A(a.embq_bf, a.embs_bf, a.q_nb, 4, tile0, NQd, tid, Al);
  __syncthreads();
  zero_acc(acc);
  mfma_accum(Al, Wl, l15, quad, cw, acc);
  epi_tanh_global(acc, a.agg_b + 256, a.tabA, NQd, tile0, l15, quad, cw);  // f2
  __syncthreads();                           // Wl reads done
  stage_W(a.wts, tid, Wl);                   // aggW0^T
  __syncthreads();
  zero_acc(acc);
  mfma_accum(Al, Wl, l15, quad, cw, acc);
  epi_tanh_global(acc, a.agg_b, a.tabB, NQd, tile0, l15, quad, cw);        // f0
}

// g1k: g1 = tanh((f1 + mean f2[s_nb]) @ W1 + b1), 16 blocks
__global__ __launch_bounds__(256) void g1k(Args a)
{
  __shared__ __align__(16) u16 smem[SMEM_U16];
  const int tid = threadIdx.x;
  gemm_tile(a.tabs1, a.tabA, a.s_nb, 10, a.wts + 16384,
            a.agg_b + 128, a.tabs2, NSd, blockIdx.x * 32, tid, smem);
}

// chain4: g0 -> h0 -> agg -> qt fused in-block (g0/h0/agg never hit global).
// 313 blocks. W0 staged once, reused for both g0 and h0 (identical weights).
__global__ __launch_bounds__(256) void chain4(Args a)
{
  __shared__ __align__(16) u16 smem[SMEM_U16];
  u16* Wl = smem;
  u16* Al = smem + 17408;
  const int tid = threadIdx.x;
  const int tile0 = blockIdx.x * 32;
  const int lane = tid & 63, wv = tid >> 6;
  const int l15 = lane & 15, quad = lane >> 4, cw = wv * 32;
  f32x4 acc[2][2];

  // phase 0: g0 = tanh((f0 + mean f1[q_nb]) @ W0 + b0)
  stage_W(a.wts, tid, Wl);                             // aggW0^T (kept for h0)
  stage_A(a.tabB, a.tabs1, a.q_nb, 4, tile0, NQd, tid, Al);
  __syncthreads();
  zero_acc(acc);
  mfma_accum(Al, Wl, l15, quad, cw, acc);
  __syncthreads();                                     // Al reads done
  epi_tanh_lds(acc, a.agg_b, Al, l15, quad, cw);       // Al = g0
  __syncthreads();

  // phase 1: h0 = tanh((g0 + mean g1[q_nb]) @ W0 + b0)  (same W, same ids)
  update_A(a.tabs2, a.q_nb, tile0, NQd, tid, Al);      // Al = g0 + mean g1
  __syncthreads();
  zero_acc(acc);
  mfma_accum(Al, Wl, l15, quad, cw, acc);
  __syncthreads();
  epi_tanh_lds(acc, a.agg_b, Al, l15, quad, cw);       // Al = h0
  stage_W(a.wts + 3 * 16384, tid, Wl);                 // lastt
  __syncthreads();

  // phase 2: agg = tanh(h0 @ last_W + last_b)
  zero_acc(acc);
  mfma_accum(Al, Wl, l15, quad, cw, acc);
  __syncthreads();
  epi_tanh_lds(acc, a.last_b, Al, l15, quad, cw);      // Al = agg
  stage_W(a.wts + 4 * 16384, tid, Wl);                 // ftt
  __syncthreads();

  // phase 3: qt = relu(agg @ ft_W + ft_b) -> tabA
  zero_acc(acc);
  mfma_accum(Al, Wl, l15, quad, cw, acc);
#pragma unroll
  for (int nt = 0; nt < 2; ++nt) {
    int col = cw + nt * 16 + l15;
    float cb = a.ft_b[col];
#pragma unroll
    for (int mt = 0; mt < 2; ++mt) {
      int rbase = tile0 + mt * 16 + quad * 4;
#pragma unroll
      for (int i = 0; i < 4; ++i) {
        int row = rbase + i;
        if (row >= NQd) continue;
        a.tabA[(long)row * 128 + col] = f2bf(fmaxf(acc[mt][nt][i] + cb, 0.f));
      }
    }
  }
}

// gates (i,g,o) + LSTM pointwise + a_state. 199 blocks x 32 rows.
__global__ __launch_bounds__(256) void gates_k(Args a)
{
  __shared__ __align__(16) u16 smem[SMEM_U16];
  u16* Wl = smem;
  u16* Al = smem + 17408;
  const int tid = threadIdx.x;
  const int tile0 = blockIdx.x * 32;
  {
    int r = tid & 31, k0 = (tid >> 5) * 16;
    int row = tile0 + r;
    int arow = a.qid_map[row];
    const u16* ap = a.tabA + (long)arow * 128 + k0;
    *(uint4*)&Al[r * 136 + k0]     = *(const uint4*)ap;
    *(uint4*)&Al[r * 136 + k0 + 8] = *(const uint4*)(ap + 8);
  }
  const int lane = tid & 63, wv = tid >> 6;
  const int l15 = lane & 15, quad = lane >> 4, cw = wv * 32;
  f32x4 acc[3][2][2];
  const int goff[3] = {0, 256, 384};
#pragma unroll
  for (int p = 0; p < 3; ++p) {
    __syncthreads();
    stage_W(a.wiht + (long)goff[p] * 128, tid, Wl);
    __syncthreads();
    zero_acc(acc[p]);
    mfma_accum(Al, Wl, l15, quad, cw, acc[p]);
  }
  __syncthreads();
  float* hb = (float*)Wl;    // [32][132] f32
#pragma unroll
  for (int nt = 0; nt < 2; ++nt) {
    int colL = cw + nt * 16 + l15;
#pragma unroll
    for (int mt = 0; mt < 2; ++mt) {
#pragma unroll
      for (int i = 0; i < 4; ++i) {
        int rL = mt * 16 + quad * 4 + i;
        int row = tile0 + rL;
        const float* rb = a.er_part + (long)a.resp_map[row] * 512;
        float iv = acc[0][mt][nt][i] + rb[colL];
        float gv = acc[1][mt][nt][i] + rb[256 + colL];
        float ov = acc[2][mt][nt][i] + rb[384 + colL];
        float c = sigf(iv) * tanh_f(gv);
        float h = sigf(ov) * tanh_f(c);
        a.states[(long)row * 128 + colL] = f2bf(h);
        hb[rL * 132 + colL] = h;
      }
    }
  }
  __syncthreads();
#pragma unroll
  for (int rr = 0; rr < 8; ++rr) {
    int rL = wv * 8 + rr;
    float p = hb[rL * 132 + lane] * a.qw[lane] + hb[rL * 132 + 64 + lane] * a.qw[64 + lane];
#pragma unroll
    for (int off = 32; off > 0; off >>= 1) p += __shfl_xor(p, off);
    if (lane == 0) a.a_state[tile0 + rL] = p + a.scal[0];
  }
}

// ---------------------------------------------------------------------------
// bprep: per-batch: gmax -> ev, prefix-scan Z -> invZ, pm softmax5, zero pred_acc
// ---------------------------------------------------------------------------
__global__ __launch_bounds__(256) void bprep(Args a)
{
  __shared__ float red[256];
  __shared__ float evl[256];
  __shared__ float kwl[128];
  const int b = blockIdx.x, tid = threadIdx.x;
  if (tid < 128) kwl[tid] = a.kw[tid];
  float v = (tid < Td) ? a.a_state[b * Td + tid] : -1e30f;
  red[tid] = v; __syncthreads();
  for (int s = 128; s > 0; s >>= 1) { if (tid < s) red[tid] = fmaxf(red[tid], red[tid + s]); __syncthreads(); }
  float gmax = red[0];
  float e = (tid < Td) ? __expf(v - gmax) : 0.f;
  evl[tid] = e;
  if (tid < Td) { a.ev[b * PB + tid] = e; a.pred_acc[b * PB + tid] = 0.f; }
  __syncthreads();
  // inclusive Hillis–Steele scan
  for (int off = 1; off < 256; off <<= 1) {
    float add = (tid >= off) ? evl[tid - off] : 0.f;
    __syncthreads();
    evl[tid] += add;
    __syncthreads();
  }
  if (tid < Td) {
    a.invZ[b * PB + tid] = 1.f / evl[tid];
    int qn = a.question[b * Sd + tid + 1];
    float am[5];
#pragma unroll
    for (int m = 0; m < 5; ++m) {
      const u16* src = (m == 0) ? a.embq_bf + (long)qn * 128
                                : a.embs_bf + (long)a.qs_sk[qn * 4 + (m - 1)] * 128;
      float s = 0.f;
      for (int k = 0; k < 128; k += 8) {
        uint4 u = *(const uint4*)&src[k];
        float f[8];
        unp2(u.x, f[0], f[1]); unp2(u.y, f[2], f[3]);
        unp2(u.z, f[4], f[5]); unp2(u.w, f[6], f[7]);
#pragma unroll
        for (int q = 0; q < 8; ++q) s = fmaf(f[q], kwl[k + q], s);
      }
      am[m] = s + a.scal[1];
    }
    float mx = am[0];
#pragma unroll
    for (int m = 1; m < 5; ++m) mx = fmaxf(mx, am[m]);
    float ex[5], z = 0.f;
#pragma unroll
    for (int m = 0; m < 5; ++m) { ex[m] = __expf(am[m] - mx); z += ex[m]; }
    float iz = 1.f / z;
#pragma unroll
    for (int m = 0; m < 5; ++m) a.pm[((long)b * PB + tid) * 5 + m] = ex[m] * iz;
  }
}

// ---------------------------------------------------------------------------
// gk_pred: sigmoid(states.qs) * ev[n] * pm[t,m] reduced into pred_acc[b,t]
// ---------------------------------------------------------------------------
__global__ __launch_bounds__(256) void gk_pred(Args a)
{
  const int n0 = blockIdx.x * 32;
  const int c0 = blockIdx.y * 128;
  const int b  = blockIdx.z;
  int c_hi = c0 + 127; if (c_hi > 994) c_hi = 994;
  const int tmax = c_hi / 5, tmin = c0 / 5;
  if (n0 > tmax) return;

  __shared__ __align__(16) u16 smem[SMEM_U16];
  __shared__ float predl[32];
  u16* Ql = smem;
  u16* Sl = smem + 17408;
  const int tid = threadIdx.x;
  if (tid < 32) predl[tid] = 0.f;
  {
    int r = tid & 31, k0 = (tid >> 5) * 16;
    int n = n0 + r; if (n > 198) n = 198;
    const u16* sp = a.states + ((long)b * Td + n) * 128 + k0;
    *(uint4*)&Sl[r * 136 + k0]     = *(const uint4*)sp;
    *(uint4*)&Sl[r * 136 + k0 + 8] = *(const uint4*)(sp + 8);
  }
  {
    int j = tid >> 1, k0 = (tid & 1) * 64;
    int col = c0 + j;
    uint4* dst = (uint4*)&Ql[j * 136 + k0];
    if (col < 995) {
      int t = col / 5, m = col - t * 5;
      int qn = a.question[b * Sd + t + 1];
      const u16* src = (m == 0) ? a.embq_bf + (long)qn * 128
                                : a.embs_bf + (long)a.qs_sk[qn * 4 + (m - 1)] * 128;
      src += k0;
#pragma unroll
      for (int q = 0; q < 8; ++q) dst[q] = ((const uint4*)src)[q];
    } else {
      uint4 z = make_uint4(0, 0, 0, 0);
#pragma unroll
      for (int q = 0; q < 8; ++q) dst[q] = z;
    }
  }
  __syncthreads();
  const int lane = tid & 63, wv = tid >> 6;
  const int l15 = lane & 15, quad = lane >> 4, cw = wv * 32;
  f32x4 acc[2][2];
  zero_acc(acc);
  mfma_accum(Sl, Ql, l15, quad, cw, acc);

#pragma unroll
  for (int nt = 0; nt < 2; ++nt) {
    int col = c0 + cw + nt * 16 + l15;
    if (col >= 995) continue;
    int t = col / 5, m = col - t * 5;
    float pmv = a.pm[((long)b * PB + t) * 5 + m];
    float part = 0.f;
#pragma unroll
    for (int mt = 0; mt < 2; ++mt) {
      int nb = n0 + mt * 16 + quad * 4;
      if (nb > t) continue;
      float4 ev4 = *(const float4*)&a.ev[b * PB + nb];
      float evv[4] = {ev4.x, ev4.y, ev4.z, ev4.w};
#pragma unroll
      for (int i = 0; i < 4; ++i) {
        int n = nb + i;
        if (n > t || n > 198) continue;
        part += evv[i] * sigf(acc[mt][nt][i]);
      }
    }
    part *= pmv;
    if (part != 0.f) atomicAdd(&predl[t - tmin], part);
  }
  __syncthreads();
  const int tcnt = tmax - tmin + 1;
  if (tid < tcnt) {
    float pv = predl[tid];
    if (pv != 0.f) atomicAdd(&a.pred_acc[b * PB + tmin + tid], pv);
  }
}

// finalize: out[b,0]=0; out[b,t+1] = pred_acc[b,t] * invZ[b,t]
__global__ __launch_bounds__(256) void finalize(Args a, float* __restrict__ out)
{
  int i = blockIdx.x * 256 + threadIdx.x;
  if (i >= Bd * Sd) return;
  int b = i / Sd, s = i - b * Sd;
  out[i] = (s == 0) ? 0.f : a.pred_acc[b * PB + s - 1] * a.invZ[b * PB + s - 1];
}

// ---------------------------------------------------------------------------
extern "C" void kernel_launch(void* const* d_in, const int* in_sizes, int n_in,
                              void* d_out, int out_size, void* d_ws, size_t ws_size,
                              hipStream_t stream)
{
  Args a;
  a.question = (const int*)d_in[0];
  a.response = (const int*)d_in[1];
  a.q_nb     = (const int*)d_in[3];
  a.s_nb     = (const int*)d_in[4];
  a.qs_sk    = (const int*)d_in[5];
  a.emb_q    = (const float*)d_in[6];
  a.emb_s    = (const float*)d_in[7];
  a.emb_r    = (const float*)d_in[8];
  a.W_ih     = (const float*)d_in[9];
  a.b_ih     = (const float*)d_in[10];
  a.b_hh     = (const float*)d_in[11];
  a.ft_W     = (const float*)d_in[12];
  a.ft_b     = (const float*)d_in[13];
  a.agg_W    = (const float*)d_in[14];
  a.agg_b    = (const float*)d_in[15];
  a.last_W   = (const float*)d_in[16];
  a.last_b   = (const float*)d_in[17];
  a.q_W      = (const float*)d_in[18];
  a.q_b      = (const float*)d_in[19];
  a.k_W      = (const float*)d_in[20];
  a.k_b      = (const float*)d_in[21];
  a.w_W      = (const float*)d_in[22];

  u16* wsu = (u16*)d_ws;
  const long NT = 1280000, ST = 64000, RT = (long)NR * Dd;
  a.tabA  = wsu;                 // NT (f2, later qt)
  a.tabB  = a.tabA + NT;         // NT (f0)
  a.tabs1 = a.tabB + NT;         // ST (f1)
  a.tabs2 = a.tabs1 + ST;        // ST (g1)
  a.states  = a.tabs2 + ST;      // RT
  a.embq_bf = a.states + RT;     // NT
  a.embs_bf = a.embq_bf + NT;    // ST
  a.wts     = a.embs_bf + ST;    // 5*16384
  a.wiht    = a.wts + 5 * 16384; // 65536
  float* fp = (float*)(a.wiht + 65536);
  a.a_state = fp;                       // 6368
  a.qw      = fp + 6368;                // 128
  a.kw      = fp + 6496;                // 128
  a.scal    = fp + 6624;                // 16
  a.er_part = fp + 6640;                // 1024
  a.ev       = fp + 7664;               // 32*208
  a.invZ     = a.ev + 32 * PB;
  a.pred_acc = a.invZ + 32 * PB;
  a.pm       = a.pred_acc + 32 * PB;    // 32*208*5
  a.qid_map  = (int*)(a.pm + 32 * PB * 5);
  a.resp_map = a.qid_map + NR;

  float* out = (float*)d_out;

  prep_all<<<640, 256, 0, stream>>>(a);
  level1m<<<329, 256, 0, stream>>>(a);
  g1k<<<16, 256, 0, stream>>>(a);
  chain4<<<313, 256, 0, stream>>>(a);
  gates_k<<<199, 256, 0, stream>>>(a);
  bprep<<<Bd, 256, 0, stream>>>(a);
  gk_pred<<<dim3(7, 8, Bd), 256, 0, stream>>>(a);
  finalize<<<25, 256, 0, stream>>>(a, out);
}

// Round 9
// 196.634 us; speedup vs baseline: 1.0855x; 1.0044x over previous
//
#include <hip/hip_runtime.h>

typedef unsigned short u16;
typedef unsigned int   u32;

#define NQd 10000
#define NSd 500
#define Bd  32
#define Sd  200
#define Td  199   // S-1
#define Dd  128
#define NR  6368  // Bd*Td
#define PB  208   // padded per-batch stride for ev/invZ/pm/pred_acc

typedef __attribute__((ext_vector_type(8))) short bf16x8;
typedef __attribute__((ext_vector_type(4))) float f32x4;

__device__ __forceinline__ float sigf(float x) {
  return __builtin_amdgcn_rcpf(1.f + __expf(-x));
}
__device__ __forceinline__ float tanh_f(float x) {
  float ax = fminf(fabsf(x), 15.f);
  float e = __expf(2.f * ax);
  float r = 1.f - 2.f * __builtin_amdgcn_rcpf(e + 1.f);
  return copysignf(r, x);
}
__device__ __forceinline__ float bf2f(u16 u) { return __uint_as_float(((u32)u) << 16); }
__device__ __forceinline__ u16 f2bf(float f) {            // round-to-nearest-even
  u32 b = __float_as_uint(f);
  b += 0x7FFFu + ((b >> 16) & 1u);
  return (u16)(b >> 16);
}
__device__ __forceinline__ void unp2(u32 u, float &a, float &b) {
  a = __uint_as_float(u << 16);
  b = __uint_as_float(u & 0xffff0000u);
}
__device__ __forceinline__ void unpack16(uint4 a0, uint4 a1, float* f) {
  unp2(a0.x, f[0], f[1]);  unp2(a0.y, f[2], f[3]);
  unp2(a0.z, f[4], f[5]);  unp2(a0.w, f[6], f[7]);
  unp2(a1.x, f[8], f[9]);  unp2(a1.y, f[10], f[11]);
  unp2(a1.z, f[12], f[13]); unp2(a1.w, f[14], f[15]);
}

struct Args {
  const int *question, *response, *q_nb, *s_nb, *qs_sk;
  const float *emb_q, *emb_s, *emb_r;
  const float *W_ih, *b_ih, *b_hh, *ft_W, *ft_b, *agg_W, *agg_b, *last_W, *last_b;
  const float *q_W, *q_b, *k_W, *k_b, *w_W;
  u16 *tabA, *tabB, *tabs1, *tabs2, *states, *embq_bf, *embs_bf, *wts, *wiht;
  float *a_state, *qw, *kw, *scal, *er_part, *ev, *invZ, *pred_acc, *pm;
  int *qid_map, *resp_map;
};

// W fragment held in registers: 2 n-tiles x 4 k-chunks x bf16x8 = 16 VGPR
struct WF { bf16x8 v[2][4]; };

__device__ __forceinline__ void load_WF(const u16* Wt, int l15, int quad, int cw, WF& w)
{
#pragma unroll
  for (int nt = 0; nt < 2; ++nt)
#pragma unroll
    for (int kc = 0; kc < 4; ++kc)
      w.v[nt][kc] = *(const bf16x8*)&Wt[(long)(cw + nt * 16 + l15) * 128 + kc * 32 + quad * 8];
}

__device__ __forceinline__ void zero_acc(f32x4 acc[2][2]) {
#pragma unroll
  for (int x = 0; x < 2; ++x)
#pragma unroll
    for (int y = 0; y < 2; ++y) acc[x][y] = (f32x4){0.f, 0.f, 0.f, 0.f};
}

// MFMA with A from LDS, B from register fragments (same op order as before)
__device__ __forceinline__ void mfma_WF(const u16* Al, const WF& w,
                                        int l15, int quad, f32x4 acc[2][2])
{
#pragma unroll
  for (int kc = 0; kc < 4; ++kc) {
    const int ko = kc * 32 + quad * 8;
    bf16x8 a0 = *(const bf16x8*)&Al[l15 * 136 + ko];
    bf16x8 a1 = *(const bf16x8*)&Al[(16 + l15) * 136 + ko];
    acc[0][0] = __builtin_amdgcn_mfma_f32_16x16x32_bf16(a0, w.v[0][kc], acc[0][0], 0, 0, 0);
    acc[0][1] = __builtin_amdgcn_mfma_f32_16x16x32_bf16(a0, w.v[1][kc], acc[0][1], 0, 0, 0);
    acc[1][0] = __builtin_amdgcn_mfma_f32_16x16x32_bf16(a1, w.v[0][kc], acc[1][0], 0, 0, 0);
    acc[1][1] = __builtin_amdgcn_mfma_f32_16x16x32_bf16(a1, w.v[1][kc], acc[1][1], 0, 0, 0);
  }
}

// stage one 32-row gathered input tile into Al (bf16), K = neighbor count
__device__ __forceinline__ void stage_A(const u16* Atab, const u16* Btab,
                                        const int* nbr, int K, int tile0, int rows,
                                        int tid, u16* Al)
{
  int r = tid & 31, k0 = (tid >> 5) * 16;
  int row = tile0 + r; if (row >= rows) row = rows - 1;
  const u16* ap = Atab + (long)row * 128 + k0;
  if (K == 0) {
    *(uint4*)&Al[r * 136 + k0]     = *(const uint4*)ap;
    *(uint4*)&Al[r * 136 + k0 + 8] = *(const uint4*)(ap + 8);
  } else {
    float f[16];
    unpack16(*(const uint4*)ap, *(const uint4*)(ap + 8), f);
    float s[16];
#pragma unroll
    for (int q = 0; q < 16; ++q) s[q] = 0.f;
    for (int l = 0; l < K; ++l) {
      int id = nbr[(long)row * K + l];
      const u16* np = Btab + (long)id * 128 + k0;
      float g[16];
      unpack16(*(const uint4*)np, *(const uint4*)(np + 8), g);
#pragma unroll
      for (int q = 0; q < 16; ++q) s[q] += g[q];
    }
    float inv = 1.f / (float)K;
#pragma unroll
    for (int q = 0; q < 16; ++q) f[q] += s[q] * inv;
    u32 p[8];
#pragma unroll
    for (int q = 0; q < 8; ++q)
      p[q] = (u32)f2bf(f[2 * q]) | ((u32)f2bf(f[2 * q + 1]) << 16);
    *(uint4*)&Al[r * 136 + k0]     = make_uint4(p[0], p[1], p[2], p[3]);
    *(uint4*)&Al[r * 136 + k0 + 8] = make_uint4(p[4], p[5], p[6], p[7]);
  }
}

// Al := bf16(Al + mean_{l<4} Btab[nbr[row*4+l]])
__device__ __forceinline__ void update_A(const u16* Btab, const int* nbr,
                                         int tile0, int rows, int tid, u16* Al)
{
  int r = tid & 31, k0 = (tid >> 5) * 16;
  int row = tile0 + r; if (row >= rows) row = rows - 1;
  float f[16];
  unpack16(*(const uint4*)&Al[r * 136 + k0], *(const uint4*)&Al[r * 136 + k0 + 8], f);
  float s[16];
#pragma unroll
  for (int q = 0; q < 16; ++q) s[q] = 0.f;
#pragma unroll
  for (int l = 0; l < 4; ++l) {
    int id = nbr[(long)row * 4 + l];
    const u16* np = Btab + (long)id * 128 + k0;
    float g[16];
    unpack16(*(const uint4*)np, *(const uint4*)(np + 8), g);
#pragma unroll
    for (int q = 0; q < 16; ++q) s[q] += g[q];
  }
#pragma unroll
  for (int q = 0; q < 16; ++q) f[q] += s[q] * 0.25f;
  u32 p[8];
#pragma unroll
  for (int q = 0; q < 8; ++q)
    p[q] = (u32)f2bf(f[2 * q]) | ((u32)f2bf(f[2 * q + 1]) << 16);
  *(uint4*)&Al[r * 136 + k0]     = make_uint4(p[0], p[1], p[2], p[3]);
  *(uint4*)&Al[r * 136 + k0 + 8] = make_uint4(p[4], p[5], p[6], p[7]);
}

// epilogue: tanh -> global table
__device__ __forceinline__ void epi_tanh_global(const f32x4 acc[2][2], const float* cbias,
                                                u16* out, int rows, int tile0,
                                                int l15, int quad, int cw)
{
#pragma unroll
  for (int nt = 0; nt < 2; ++nt) {
    int col = cw + nt * 16 + l15;
    float cb = cbias[col];
#pragma unroll
    for (int mt = 0; mt < 2; ++mt) {
      int rbase = tile0 + mt * 16 + quad * 4;
#pragma unroll
      for (int i = 0; i < 4; ++i) {
        int row = rbase + i;
        if (row >= rows) continue;
        out[(long)row * 128 + col] = f2bf(tanh_f(acc[mt][nt][i] + cb));
      }
    }
  }
}

// epilogue: tanh -> LDS Al
__device__ __forceinline__ void epi_tanh_lds(const f32x4 acc[2][2], const float* cbias,
                                             u16* Al, int l15, int quad, int cw)
{
#pragma unroll
  for (int nt = 0; nt < 2; ++nt) {
    int col = cw + nt * 16 + l15;
    float cb = cbias[col];
#pragma unroll
    for (int mt = 0; mt < 2; ++mt)
#pragma unroll
      for (int i = 0; i < 4; ++i) {
        int rL = mt * 16 + quad * 4 + i;
        Al[rL * 136 + col] = f2bf(tanh_f(acc[mt][nt][i] + cb));
      }
  }
}

// ---------------------------------------------------------------------------
// prep_all: bf16 emb copies, transposed bf16 weights, maps, small dots
// ---------------------------------------------------------------------------
__global__ __launch_bounds__(256) void prep_all(Args a)
{
  const int T = gridDim.x * 256;
  for (int i = blockIdx.x * 256 + threadIdx.x; i < 491106; i += T) {
    if (i < 320000) {
      float4 v = *(const float4*)&a.emb_q[(long)i * 4];
      ((uint2*)a.embq_bf)[i] = make_uint2(
          (u32)f2bf(v.x) | ((u32)f2bf(v.y) << 16),
          (u32)f2bf(v.z) | ((u32)f2bf(v.w) << 16));
    } else if (i < 336000) {
      int c = i - 320000;
      float4 v = *(const float4*)&a.emb_s[(long)c * 4];
      ((uint2*)a.embs_bf)[c] = make_uint2(
          (u32)f2bf(v.x) | ((u32)f2bf(v.y) << 16),
          (u32)f2bf(v.z) | ((u32)f2bf(v.w) << 16));
    } else if (i < 417920) {
      int e = i - 336000;
      int seg = e >> 14, r = e & 16383;
      int col = r >> 7, k = r & 127;
      const float* src = (seg < 3) ? (a.agg_W + seg * 16384)
                                   : (seg == 3 ? a.last_W : a.ft_W);
      a.wts[e] = f2bf(src[k * 128 + col]);
    } else if (i < 483456) {
      int e = i - 417920;
      int col = e >> 7, k = e & 127;
      a.wiht[e] = f2bf(a.W_ih[k * 512 + col]);
    } else if (i < 489824) {
      int j = i - 483456;
      int b = j / Td, s = j - b * Td;
      a.qid_map[j]  = a.question[b * Sd + s];
      a.resp_map[j] = a.response[b * Sd + s];
    } else {
      int s = i - 489824;
      if (s < 128) {
        float acc = 0;
        for (int e = 0; e < 128; ++e) acc += a.q_W[s * 128 + e] * a.w_W[e];
        a.qw[s] = acc;
      } else if (s < 256) {
        int d = s - 128; float acc = 0;
        for (int e = 0; e < 128; ++e) acc += a.k_W[d * 128 + e] * a.w_W[128 + e];
        a.kw[d] = acc;
      } else if (s == 256) {
        float acc = 0;
        for (int e = 0; e < 128; ++e) acc += a.q_b[e] * a.w_W[e];
        a.scal[0] = acc;
      } else if (s == 257) {
        float acc = 0;
        for (int e = 0; e < 128; ++e) acc += a.k_b[e] * a.w_W[128 + e];
        a.scal[1] = acc;
      } else {
        int e2 = s - 258, rr = e2 >> 9, col = e2 & 511;
        float acc = a.b_ih[col] + a.b_hh[col];
        for (int d = 0; d < 128; ++d) acc += a.emb_r[rr * Dd + d] * a.W_ih[(128 + d) * 512 + col];
        a.er_part[rr * 512 + col] = acc;
      }
    }
  }
}

// level1m: 0..312: f2+f0 (one gather, W in regs, no inter-phase barrier);
// 313..328: f1; 329..353: pm table (independent filler work)
__global__ __launch_bounds__(256) void level1m(Args a)
{
  __shared__ __align__(16) u16 Al[32 * 136];
  const int i = blockIdx.x, tid = threadIdx.x;
  const int lane = tid & 63, wv = tid >> 6;
  const int l15 = lane & 15, quad = lane >> 4, cw = wv * 32;

  if (i >= 329) {   // pm: one (b,t) per thread
    int item = (i - 329) * 256 + tid;
    if (item >= NR) return;
    int b = item / Td, t = item - b * Td;
    int qn = a.question[b * Sd + t + 1];
    float am[5];
#pragma unroll
    for (int m = 0; m < 5; ++m) {
      const u16* src = (m == 0) ? a.embq_bf + (long)qn * 128
                                : a.embs_bf + (long)a.qs_sk[qn * 4 + (m - 1)] * 128;
      float s = 0.f;
      for (int k = 0; k < 128; k += 8) {
        uint4 u = *(const uint4*)&src[k];
        float f[8];
        unp2(u.x, f[0], f[1]); unp2(u.y, f[2], f[3]);
        unp2(u.z, f[4], f[5]); unp2(u.w, f[6], f[7]);
#pragma unroll
        for (int q = 0; q < 8; ++q) s = fmaf(f[q], a.kw[k + q], s);
      }
      am[m] = s + a.scal[1];
    }
    float mx = am[0];
#pragma unroll
    for (int m = 1; m < 5; ++m) mx = fmaxf(mx, am[m]);
    float ex[5], z = 0.f;
#pragma unroll
    for (int m = 0; m < 5; ++m) { ex[m] = __expf(am[m] - mx); z += ex[m]; }
    float iz = __builtin_amdgcn_rcpf(z);
#pragma unroll
    for (int m = 0; m < 5; ++m) a.pm[((long)b * PB + t) * 5 + m] = ex[m] * iz;
    return;
  }

  f32x4 acc[2][2];
  if (i >= 313) {   // f1
    const int tile0 = (i - 313) * 32;
    WF w1; load_WF(a.wts + 16384, l15, quad, cw, w1);
    stage_A(a.embs_bf, a.embq_bf, a.s_nb, 10, tile0, NSd, tid, Al);
    __syncthreads();
    zero_acc(acc);
    mfma_WF(Al, w1, l15, quad, acc);
    epi_tanh_global(acc, a.agg_b + 128, a.tabs1, NSd, tile0, l15, quad, cw);
    return;
  }
  const int tile0 = i * 32;
  WF w2, w0;
  load_WF(a.wts + 2 * 16384, l15, quad, cw, w2);
  load_WF(a.wts, l15, quad, cw, w0);
  stage_A(a.embq_bf, a.embs_bf, a.q_nb, 4, tile0, NQd, tid, Al);
  __syncthreads();
  zero_acc(acc);
  mfma_WF(Al, w2, l15, quad, acc);
  epi_tanh_global(acc, a.agg_b + 256, a.tabA, NQd, tile0, l15, quad, cw);  // f2
  zero_acc(acc);                            // Al unchanged: no barrier needed
  mfma_WF(Al, w0, l15, quad, acc);
  epi_tanh_global(acc, a.agg_b, a.tabB, NQd, tile0, l15, quad, cw);        // f0
}

// g1k: g1 = tanh((f1 + mean f2[s_nb]) @ W1 + b1), 16 blocks
__global__ __launch_bounds__(256) void g1k(Args a)
{
  __shared__ __align__(16) u16 Al[32 * 136];
  const int tid = threadIdx.x, tile0 = blockIdx.x * 32;
  const int lane = tid & 63, wv = tid >> 6;
  const int l15 = lane & 15, quad = lane >> 4, cw = wv * 32;
  WF w1; load_WF(a.wts + 16384, l15, quad, cw, w1);
  stage_A(a.tabs1, a.tabA, a.s_nb, 10, tile0, NSd, tid, Al);
  __syncthreads();
  f32x4 acc[2][2];
  zero_acc(acc);
  mfma_WF(Al, w1, l15, quad, acc);
  epi_tanh_global(acc, a.agg_b + 128, a.tabs2, NSd, tile0, l15, quad, cw);
}

// chain4: g0 -> h0 -> agg -> qt fused in-block, W0/last/ft in registers
__global__ __launch_bounds__(256) void chain4(Args a)
{
  __shared__ __align__(16) u16 Al[32 * 136];
  const int tid = threadIdx.x, tile0 = blockIdx.x * 32;
  const int lane = tid & 63, wv = tid >> 6;
  const int l15 = lane & 15, quad = lane >> 4, cw = wv * 32;
  WF w0, w3, w4;
  load_WF(a.wts, l15, quad, cw, w0);
  load_WF(a.wts + 3 * 16384, l15, quad, cw, w3);
  load_WF(a.wts + 4 * 16384, l15, quad, cw, w4);
  f32x4 acc[2][2];

  // phase 0: g0 = tanh((f0 + mean f1[q_nb]) @ W0 + b0)
  stage_A(a.tabB, a.tabs1, a.q_nb, 4, tile0, NQd, tid, Al);
  __syncthreads();
  zero_acc(acc);
  mfma_WF(Al, w0, l15, quad, acc);
  __syncthreads();
  epi_tanh_lds(acc, a.agg_b, Al, l15, quad, cw);       // Al = g0
  __syncthreads();
  // phase 1: h0 = tanh((g0 + mean g1[q_nb]) @ W0 + b0)
  update_A(a.tabs2, a.q_nb, tile0, NQd, tid, Al);
  __syncthreads();
  zero_acc(acc);
  mfma_WF(Al, w0, l15, quad, acc);
  __syncthreads();
  epi_tanh_lds(acc, a.agg_b, Al, l15, quad, cw);       // Al = h0
  __syncthreads();
  // phase 2: agg = tanh(h0 @ last_W + last_b)
  zero_acc(acc);
  mfma_WF(Al, w3, l15, quad, acc);
  __syncthreads();
  epi_tanh_lds(acc, a.last_b, Al, l15, quad, cw);      // Al = agg
  __syncthreads();
  // phase 3: qt = relu(agg @ ft_W + ft_b) -> tabA
  zero_acc(acc);
  mfma_WF(Al, w4, l15, quad, acc);
#pragma unroll
  for (int nt = 0; nt < 2; ++nt) {
    int col = cw + nt * 16 + l15;
    float cb = a.ft_b[col];
#pragma unroll
    for (int mt = 0; mt < 2; ++mt) {
      int rbase = tile0 + mt * 16 + quad * 4;
#pragma unroll
      for (int i = 0; i < 4; ++i) {
        int row = rbase + i;
        if (row >= NQd) continue;
        a.tabA[(long)row * 128 + col] = f2bf(fmaxf(acc[mt][nt][i] + cb, 0.f));
      }
    }
  }
}

// gates (i,g,o) + LSTM pointwise + a_state. 199 blocks x 32 rows.
__global__ __launch_bounds__(256) void gates_k(Args a)
{
  __shared__ __align__(16) u16 Al[32 * 136];
  __shared__ float hb[32 * 132];
  const int tid = threadIdx.x, tile0 = blockIdx.x * 32;
  const int lane = tid & 63, wv = tid >> 6;
  const int l15 = lane & 15, quad = lane >> 4, cw = wv * 32;
  WF wg0, wg1, wg2;
  load_WF(a.wiht, l15, quad, cw, wg0);                     // i-gate
  load_WF(a.wiht + (long)256 * 128, l15, quad, cw, wg1);   // g-gate
  load_WF(a.wiht + (long)384 * 128, l15, quad, cw, wg2);   // o-gate
  {
    int r = tid & 31, k0 = (tid >> 5) * 16;
    int row = tile0 + r;
    int arow = a.qid_map[row];
    const u16* ap = a.tabA + (long)arow * 128 + k0;
    *(uint4*)&Al[r * 136 + k0]     = *(const uint4*)ap;
    *(uint4*)&Al[r * 136 + k0 + 8] = *(const uint4*)(ap + 8);
  }
  __syncthreads();
  f32x4 acc[3][2][2];
  zero_acc(acc[0]); mfma_WF(Al, wg0, l15, quad, acc[0]);
  zero_acc(acc[1]); mfma_WF(Al, wg1, l15, quad, acc[1]);
  zero_acc(acc[2]); mfma_WF(Al, wg2, l15, quad, acc[2]);
#pragma unroll
  for (int nt = 0; nt < 2; ++nt) {
    int colL = cw + nt * 16 + l15;
#pragma unroll
    for (int mt = 0; mt < 2; ++mt) {
#pragma unroll
      for (int i = 0; i < 4; ++i) {
        int rL = mt * 16 + quad * 4 + i;
        int row = tile0 + rL;
        const float* rb = a.er_part + (long)a.resp_map[row] * 512;
        float iv = acc[0][mt][nt][i] + rb[colL];
        float gv = acc[1][mt][nt][i] + rb[256 + colL];
        float ov = acc[2][mt][nt][i] + rb[384 + colL];
        float c = sigf(iv) * tanh_f(gv);
        float h = sigf(ov) * tanh_f(c);
        a.states[(long)row * 128 + colL] = f2bf(h);
        hb[rL * 132 + colL] = h;
      }
    }
  }
  __syncthreads();
#pragma unroll
  for (int rr = 0; rr < 8; ++rr) {
    int rL = wv * 8 + rr;
    float p = hb[rL * 132 + lane] * a.qw[lane] + hb[rL * 132 + 64 + lane] * a.qw[64 + lane];
#pragma unroll
    for (int off = 32; off > 0; off >>= 1) p += __shfl_xor(p, off);
    if (lane == 0) a.a_state[tile0 + rL] = p + a.scal[0];
  }
}

// ---------------------------------------------------------------------------
// bprep: per-batch: gmax -> ev, prefix-scan Z -> invZ, zero pred_acc
// ---------------------------------------------------------------------------
__global__ __launch_bounds__(256) void bprep(Args a)
{
  __shared__ float red[256];
  __shared__ float evl[256];
  const int b = blockIdx.x, tid = threadIdx.x;
  float v = (tid < Td) ? a.a_state[b * Td + tid] : -1e30f;
  red[tid] = v; __syncthreads();
  for (int s = 128; s > 0; s >>= 1) { if (tid < s) red[tid] = fmaxf(red[tid], red[tid + s]); __syncthreads(); }
  float gmax = red[0];
  float e = (tid < Td) ? __expf(v - gmax) : 0.f;
  evl[tid] = e;
  if (tid < Td) { a.ev[b * PB + tid] = e; a.pred_acc[b * PB + tid] = 0.f; }
  __syncthreads();
  for (int off = 1; off < 256; off <<= 1) {
    float add = (tid >= off) ? evl[tid - off] : 0.f;
    __syncthreads();
    evl[tid] += add;
    __syncthreads();
  }
  if (tid < Td) a.invZ[b * PB + tid] = 1.f / evl[tid];
}

// ---------------------------------------------------------------------------
// gk_pred: sigmoid(states.qs) * ev[n] * pm[t,m] reduced into pred_acc[b,t]
// ---------------------------------------------------------------------------
__global__ __launch_bounds__(256) void gk_pred(Args a)
{
  const int n0 = blockIdx.x * 32;
  const int c0 = blockIdx.y * 128;
  const int b  = blockIdx.z;
  int c_hi = c0 + 127; if (c_hi > 994) c_hi = 994;
  const int tmax = c_hi / 5, tmin = c0 / 5;
  if (n0 > tmax) return;

  __shared__ __align__(16) u16 smem[21760];
  __shared__ float predl[32];
  u16* Ql = smem;
  u16* Sl = smem + 17408;
  const int tid = threadIdx.x;
  if (tid < 32) predl[tid] = 0.f;
  {
    int r = tid & 31, k0 = (tid >> 5) * 16;
    int n = n0 + r; if (n > 198) n = 198;
    const u16* sp = a.states + ((long)b * Td + n) * 128 + k0;
    *(uint4*)&Sl[r * 136 + k0]     = *(const uint4*)sp;
    *(uint4*)&Sl[r * 136 + k0 + 8] = *(const uint4*)(sp + 8);
  }
  {
    int j = tid >> 1, k0 = (tid & 1) * 64;
    int col = c0 + j;
    uint4* dst = (uint4*)&Ql[j * 136 + k0];
    if (col < 995) {
      int t = col / 5, m = col - t * 5;
      int qn = a.question[b * Sd + t + 1];
      const u16* src = (m == 0) ? a.embq_bf + (long)qn * 128
                                : a.embs_bf + (long)a.qs_sk[qn * 4 + (m - 1)] * 128;
      src += k0;
#pragma unroll
      for (int q = 0; q < 8; ++q) dst[q] = ((const uint4*)src)[q];
    } else {
      uint4 z = make_uint4(0, 0, 0, 0);
#pragma unroll
      for (int q = 0; q < 8; ++q) dst[q] = z;
    }
  }
  __syncthreads();
  const int lane = tid & 63, wv = tid >> 6;
  const int l15 = lane & 15, quad = lane >> 4, cw = wv * 32;
  f32x4 acc[2][2];
  zero_acc(acc);
#pragma unroll
  for (int kc = 0; kc < 4; ++kc) {
    const int ko = kc * 32 + quad * 8;
    bf16x8 af[2], bfv[2];
    af[0]  = *(const bf16x8*)&Sl[l15 * 136 + ko];
    af[1]  = *(const bf16x8*)&Sl[(16 + l15) * 136 + ko];
    bfv[0] = *(const bf16x8*)&Ql[(cw + l15) * 136 + ko];
    bfv[1] = *(const bf16x8*)&Ql[(cw + 16 + l15) * 136 + ko];
#pragma unroll
    for (int mt = 0; mt < 2; ++mt)
#pragma unroll
      for (int nt = 0; nt < 2; ++nt)
        acc[mt][nt] = __builtin_amdgcn_mfma_f32_16x16x32_bf16(af[mt], bfv[nt], acc[mt][nt], 0, 0, 0);
  }

#pragma unroll
  for (int nt = 0; nt < 2; ++nt) {
    int col = c0 + cw + nt * 16 + l15;
    if (col >= 995) continue;
    int t = col / 5, m = col - t * 5;
    float pmv = a.pm[((long)b * PB + t) * 5 + m];
    float part = 0.f;
#pragma unroll
    for (int mt = 0; mt < 2; ++mt) {
      int nb = n0 + mt * 16 + quad * 4;
      if (nb > t) continue;
      float4 ev4 = *(const float4*)&a.ev[b * PB + nb];
      float evv[4] = {ev4.x, ev4.y, ev4.z, ev4.w};
#pragma unroll
      for (int i = 0; i < 4; ++i) {
        int n = nb + i;
        if (n > t || n > 198) continue;
        part += evv[i] * sigf(acc[mt][nt][i]);
      }
    }
    part *= pmv;
    if (part != 0.f) atomicAdd(&predl[t - tmin], part);
  }
  __syncthreads();
  const int tcnt = tmax - tmin + 1;
  if (tid < tcnt) {
    float pv = predl[tid];
    if (pv != 0.f) atomicAdd(&a.pred_acc[b * PB + tmin + tid], pv);
  }
}

// finalize: out[b,0]=0; out[b,t+1] = pred_acc[b,t] * invZ[b,t]
__global__ __launch_bounds__(256) void finalize(Args a, float* __restrict__ out)
{
  int i = blockIdx.x * 256 + threadIdx.x;
  if (i >= Bd * Sd) return;
  int b = i / Sd, s = i - b * Sd;
  out[i] = (s == 0) ? 0.f : a.pred_acc[b * PB + s - 1] * a.invZ[b * PB + s - 1];
}

// ---------------------------------------------------------------------------
extern "C" void kernel_launch(void* const* d_in, const int* in_sizes, int n_in,
                              void* d_out, int out_size, void* d_ws, size_t ws_size,
                              hipStream_t stream)
{
  Args a;
  a.question = (const int*)d_in[0];
  a.response = (const int*)d_in[1];
  a.q_nb     = (const int*)d_in[3];
  a.s_nb     = (const int*)d_in[4];
  a.qs_sk    = (const int*)d_in[5];
  a.emb_q    = (const float*)d_in[6];
  a.emb_s    = (const float*)d_in[7];
  a.emb_r    = (const float*)d_in[8];
  a.W_ih     = (const float*)d_in[9];
  a.b_ih     = (const float*)d_in[10];
  a.b_hh     = (const float*)d_in[11];
  a.ft_W     = (const float*)d_in[12];
  a.ft_b     = (const float*)d_in[13];
  a.agg_W    = (const float*)d_in[14];
  a.agg_b    = (const float*)d_in[15];
  a.last_W   = (const float*)d_in[16];
  a.last_b   = (const float*)d_in[17];
  a.q_W      = (const float*)d_in[18];
  a.q_b      = (const float*)d_in[19];
  a.k_W      = (const float*)d_in[20];
  a.k_b      = (const float*)d_in[21];
  a.w_W      = (const float*)d_in[22];

  u16* wsu = (u16*)d_ws;
  const long NT = 1280000, ST = 64000, RT = (long)NR * Dd;
  a.tabA  = wsu;                 // NT (f2, later qt)
  a.tabB  = a.tabA + NT;         // NT (f0)
  a.tabs1 = a.tabB + NT;         // ST (f1)
  a.tabs2 = a.tabs1 + ST;        // ST (g1)
  a.states  = a.tabs2 + ST;      // RT
  a.embq_bf = a.states + RT;     // NT
  a.embs_bf = a.embq_bf + NT;    // ST
  a.wts     = a.embs_bf + ST;    // 5*16384
  a.wiht    = a.wts + 5 * 16384; // 65536
  float* fp = (float*)(a.wiht + 65536);
  a.a_state = fp;                       // 6368
  a.qw      = fp + 6368;                // 128
  a.kw      = fp + 6496;                // 128
  a.scal    = fp + 6624;                // 16
  a.er_part = fp + 6640;                // 1024
  a.ev       = fp + 7664;               // 32*208
  a.invZ     = a.ev + 32 * PB;
  a.pred_acc = a.invZ + 32 * PB;
  a.pm       = a.pred_acc + 32 * PB;    // 32*208*5
  a.qid_map  = (int*)(a.pm + 32 * PB * 5);
  a.resp_map = a.qid_map + NR;

  float* out = (float*)d_out;

  prep_all<<<640, 256, 0, stream>>>(a);
  level1m<<<354, 256, 0, stream>>>(a);     // f2/f0 | f1 | pm filler
  g1k<<<16, 256, 0, stream>>>(a);
  chain4<<<313, 256, 0, stream>>>(a);
  gates_k<<<199, 256, 0, stream>>>(a);
  bprep<<<Bd, 256, 0, stream>>>(a);
  gk_pred<<<dim3(7, 8, Bd), 256, 0, stream>>>(a);
  finalize<<<25, 256, 0, stream>>>(a, out);
}

// Round 10
// 191.040 us; speedup vs baseline: 1.1172x; 1.0293x over previous
//
#include <hip/hip_runtime.h>

typedef unsigned short u16;
typedef unsigned int   u32;

#define NQd 10000
#define NSd 500
#define Bd  32
#define Sd  200
#define Td  199   // S-1
#define Dd  128
#define NR  6368  // Bd*Td
#define PB  208   // padded per-batch stride for ev/invZ/pm

typedef __attribute__((ext_vector_type(8))) short bf16x8;
typedef __attribute__((ext_vector_type(4))) float f32x4;

__device__ __forceinline__ float sigf(float x) {
  return __builtin_amdgcn_rcpf(1.f + __expf(-x));
}
__device__ __forceinline__ float tanh_f(float x) {
  float ax = fminf(fabsf(x), 15.f);
  float e = __expf(2.f * ax);
  float r = 1.f - 2.f * __builtin_amdgcn_rcpf(e + 1.f);
  return copysignf(r, x);
}
__device__ __forceinline__ float bf2f(u16 u) { return __uint_as_float(((u32)u) << 16); }
__device__ __forceinline__ u16 f2bf(float f) {            // round-to-nearest-even
  u32 b = __float_as_uint(f);
  b += 0x7FFFu + ((b >> 16) & 1u);
  return (u16)(b >> 16);
}
__device__ __forceinline__ void unp2(u32 u, float &a, float &b) {
  a = __uint_as_float(u << 16);
  b = __uint_as_float(u & 0xffff0000u);
}
__device__ __forceinline__ void unpack16(uint4 a0, uint4 a1, float* f) {
  unp2(a0.x, f[0], f[1]);  unp2(a0.y, f[2], f[3]);
  unp2(a0.z, f[4], f[5]);  unp2(a0.w, f[6], f[7]);
  unp2(a1.x, f[8], f[9]);  unp2(a1.y, f[10], f[11]);
  unp2(a1.z, f[12], f[13]); unp2(a1.w, f[14], f[15]);
}

struct Args {
  const int *question, *response, *q_nb, *s_nb, *qs_sk;
  const float *emb_q, *emb_s, *emb_r;
  const float *W_ih, *b_ih, *b_hh, *ft_W, *ft_b, *agg_W, *agg_b, *last_W, *last_b;
  const float *q_W, *q_b, *k_W, *k_b, *w_W;
  u16 *tabA, *tabB, *tabs1, *tabs2, *states, *embq_bf, *embs_bf, *wts, *wiht;
  float *a_state, *qw, *kw, *scal, *er_part, *ev, *invZ, *pm;
  int *qid_map, *resp_map, *flag, *cnt, *list, *newidx;
};

// W fragment held in registers: 2 n-tiles x 4 k-chunks x bf16x8 = 16 VGPR
struct WF { bf16x8 v[2][4]; };

__device__ __forceinline__ void load_WF(const u16* Wt, int l15, int quad, int cw, WF& w)
{
#pragma unroll
  for (int nt = 0; nt < 2; ++nt)
#pragma unroll
    for (int kc = 0; kc < 4; ++kc)
      w.v[nt][kc] = *(const bf16x8*)&Wt[(long)(cw + nt * 16 + l15) * 128 + kc * 32 + quad * 8];
}

__device__ __forceinline__ void zero_acc(f32x4 acc[2][2]) {
#pragma unroll
  for (int x = 0; x < 2; ++x)
#pragma unroll
    for (int y = 0; y < 2; ++y) acc[x][y] = (f32x4){0.f, 0.f, 0.f, 0.f};
}

// MFMA with A from LDS, B from register fragments
__device__ __forceinline__ void mfma_WF(const u16* Al, const WF& w,
                                        int l15, int quad, f32x4 acc[2][2])
{
#pragma unroll
  for (int kc = 0; kc < 4; ++kc) {
    const int ko = kc * 32 + quad * 8;
    bf16x8 a0 = *(const bf16x8*)&Al[l15 * 136 + ko];
    bf16x8 a1 = *(const bf16x8*)&Al[(16 + l15) * 136 + ko];
    acc[0][0] = __builtin_amdgcn_mfma_f32_16x16x32_bf16(a0, w.v[0][kc], acc[0][0], 0, 0, 0);
    acc[0][1] = __builtin_amdgcn_mfma_f32_16x16x32_bf16(a0, w.v[1][kc], acc[0][1], 0, 0, 0);
    acc[1][0] = __builtin_amdgcn_mfma_f32_16x16x32_bf16(a1, w.v[0][kc], acc[1][0], 0, 0, 0);
    acc[1][1] = __builtin_amdgcn_mfma_f32_16x16x32_bf16(a1, w.v[1][kc], acc[1][1], 0, 0, 0);
  }
}

// stage one 32-row gathered input tile into Al (bf16). rowmap: optional compaction.
__device__ __forceinline__ void stage_A(const u16* Atab, const u16* Btab,
                                        const int* nbr, int K, const int* rowmap,
                                        int tile0, int rows, int tid, u16* Al)
{
  int r = tid & 31, k0 = (tid >> 5) * 16;
  int row = tile0 + r; if (row >= rows) row = rows - 1;
  int arow = rowmap ? rowmap[row] : row;
  const u16* ap = Atab + (long)arow * 128 + k0;
  if (K == 0) {
    *(uint4*)&Al[r * 136 + k0]     = *(const uint4*)ap;
    *(uint4*)&Al[r * 136 + k0 + 8] = *(const uint4*)(ap + 8);
  } else {
    float f[16];
    unpack16(*(const uint4*)ap, *(const uint4*)(ap + 8), f);
    float s[16];
#pragma unroll
    for (int q = 0; q < 16; ++q) s[q] = 0.f;
    for (int l = 0; l < K; ++l) {
      int id = nbr[(long)arow * K + l];
      const u16* np = Btab + (long)id * 128 + k0;
      float g[16];
      unpack16(*(const uint4*)np, *(const uint4*)(np + 8), g);
#pragma unroll
      for (int q = 0; q < 16; ++q) s[q] += g[q];
    }
    float inv = 1.f / (float)K;
#pragma unroll
    for (int q = 0; q < 16; ++q) f[q] += s[q] * inv;
    u32 p[8];
#pragma unroll
    for (int q = 0; q < 8; ++q)
      p[q] = (u32)f2bf(f[2 * q]) | ((u32)f2bf(f[2 * q + 1]) << 16);
    *(uint4*)&Al[r * 136 + k0]     = make_uint4(p[0], p[1], p[2], p[3]);
    *(uint4*)&Al[r * 136 + k0 + 8] = make_uint4(p[4], p[5], p[6], p[7]);
  }
}

// Al := bf16(Al + mean_{l<4} Btab[nbr[arow*4+l]])
__device__ __forceinline__ void update_A(const u16* Btab, const int* nbr,
                                         const int* rowmap, int tile0, int rows,
                                         int tid, u16* Al)
{
  int r = tid & 31, k0 = (tid >> 5) * 16;
  int row = tile0 + r; if (row >= rows) row = rows - 1;
  int arow = rowmap ? rowmap[row] : row;
  float f[16];
  unpack16(*(const uint4*)&Al[r * 136 + k0], *(const uint4*)&Al[r * 136 + k0 + 8], f);
  float s[16];
#pragma unroll
  for (int q = 0; q < 16; ++q) s[q] = 0.f;
#pragma unroll
  for (int l = 0; l < 4; ++l) {
    int id = nbr[(long)arow * 4 + l];
    const u16* np = Btab + (long)id * 128 + k0;
    float g[16];
    unpack16(*(const uint4*)np, *(const uint4*)(np + 8), g);
#pragma unroll
    for (int q = 0; q < 16; ++q) s[q] += g[q];
  }
#pragma unroll
  for (int q = 0; q < 16; ++q) f[q] += s[q] * 0.25f;
  u32 p[8];
#pragma unroll
  for (int q = 0; q < 8; ++q)
    p[q] = (u32)f2bf(f[2 * q]) | ((u32)f2bf(f[2 * q + 1]) << 16);
  *(uint4*)&Al[r * 136 + k0]     = make_uint4(p[0], p[1], p[2], p[3]);
  *(uint4*)&Al[r * 136 + k0 + 8] = make_uint4(p[4], p[5], p[6], p[7]);
}

// epilogue: tanh -> global table
__device__ __forceinline__ void epi_tanh_global(const f32x4 acc[2][2], const float* cbias,
                                                u16* out, int rows, int tile0,
                                                int l15, int quad, int cw)
{
#pragma unroll
  for (int nt = 0; nt < 2; ++nt) {
    int col = cw + nt * 16 + l15;
    float cb = cbias[col];
#pragma unroll
    for (int mt = 0; mt < 2; ++mt) {
      int rbase = tile0 + mt * 16 + quad * 4;
#pragma unroll
      for (int i = 0; i < 4; ++i) {
        int row = rbase + i;
        if (row >= rows) continue;
        out[(long)row * 128 + col] = f2bf(tanh_f(acc[mt][nt][i] + cb));
      }
    }
  }
}

// epilogue: tanh -> LDS Al
__device__ __forceinline__ void epi_tanh_lds(const f32x4 acc[2][2], const float* cbias,
                                             u16* Al, int l15, int quad, int cw)
{
#pragma unroll
  for (int nt = 0; nt < 2; ++nt) {
    int col = cw + nt * 16 + l15;
    float cb = cbias[col];
#pragma unroll
    for (int mt = 0; mt < 2; ++mt)
#pragma unroll
      for (int i = 0; i < 4; ++i) {
        int rL = mt * 16 + quad * 4 + i;
        Al[rL * 136 + col] = f2bf(tanh_f(acc[mt][nt][i] + cb));
      }
  }
}

// ---------------------------------------------------------------------------
// prep_all: bf16 emb copies, transposed bf16 weights, maps + used-qid list,
// small dots, zero d_out
// ---------------------------------------------------------------------------
__global__ __launch_bounds__(256) void prep_all(Args a, float* __restrict__ out)
{
  const int T = gridDim.x * 256;
  for (int i = blockIdx.x * 256 + threadIdx.x; i < 497506; i += T) {
    if (i < 320000) {
      float4 v = *(const float4*)&a.emb_q[(long)i * 4];
      ((uint2*)a.embq_bf)[i] = make_uint2(
          (u32)f2bf(v.x) | ((u32)f2bf(v.y) << 16),
          (u32)f2bf(v.z) | ((u32)f2bf(v.w) << 16));
    } else if (i < 336000) {
      int c = i - 320000;
      float4 v = *(const float4*)&a.emb_s[(long)c * 4];
      ((uint2*)a.embs_bf)[c] = make_uint2(
          (u32)f2bf(v.x) | ((u32)f2bf(v.y) << 16),
          (u32)f2bf(v.z) | ((u32)f2bf(v.w) << 16));
    } else if (i < 417920) {
      int e = i - 336000;
      int seg = e >> 14, r = e & 16383;
      int col = r >> 7, k = r & 127;
      const float* src = (seg < 3) ? (a.agg_W + seg * 16384)
                                   : (seg == 3 ? a.last_W : a.ft_W);
      a.wts[e] = f2bf(src[k * 128 + col]);
    } else if (i < 483456) {
      int e = i - 417920;
      int col = e >> 7, k = e & 127;
      a.wiht[e] = f2bf(a.W_ih[k * 512 + col]);
    } else if (i < 489824) {
      int j = i - 483456;
      int b = j / Td, s = j - b * Td;
      int qid = a.question[b * Sd + s];
      a.qid_map[j]  = qid;
      a.resp_map[j] = a.response[b * Sd + s];
      if (atomicExch(&a.flag[qid], 1) == 0) {     // first toucher appends
        int idx = atomicAdd(a.cnt, 1);
        a.list[idx] = qid;
        a.newidx[qid] = idx;
      }
    } else if (i < 491106) {
      int s = i - 489824;
      if (s < 128) {
        float acc = 0;
        for (int e = 0; e < 128; ++e) acc += a.q_W[s * 128 + e] * a.w_W[e];
        a.qw[s] = acc;
      } else if (s < 256) {
        int d = s - 128; float acc = 0;
        for (int e = 0; e < 128; ++e) acc += a.k_W[d * 128 + e] * a.w_W[128 + e];
        a.kw[d] = acc;
      } else if (s == 256) {
        float acc = 0;
        for (int e = 0; e < 128; ++e) acc += a.q_b[e] * a.w_W[e];
        a.scal[0] = acc;
      } else if (s == 257) {
        float acc = 0;
        for (int e = 0; e < 128; ++e) acc += a.k_b[e] * a.w_W[128 + e];
        a.scal[1] = acc;
      } else {
        int e2 = s - 258, rr = e2 >> 9, col = e2 & 511;
        float acc = a.b_ih[col] + a.b_hh[col];
        for (int d = 0; d < 128; ++d) acc += a.emb_r[rr * Dd + d] * a.W_ih[(128 + d) * 512 + col];
        a.er_part[rr * 512 + col] = acc;
      }
    } else {
      out[i - 491106] = 0.f;       // zero d_out (gk_pred accumulates into it)
    }
  }
}

// level1m: 0..312: f2+f0 (one gather, W in regs); 313..328: f1; 329..353: pm
__global__ __launch_bounds__(256) void level1m(Args a)
{
  __shared__ __align__(16) u16 Al[32 * 136];
  const int i = blockIdx.x, tid = threadIdx.x;
  const int lane = tid & 63, wv = tid >> 6;
  const int l15 = lane & 15, quad = lane >> 4, cw = wv * 32;

  if (i >= 329) {   // pm: one (b,t) per thread
    int item = (i - 329) * 256 + tid;
    if (item >= NR) return;
    int b = item / Td, t = item - b * Td;
    int qn = a.question[b * Sd + t + 1];
    float am[5];
#pragma unroll
    for (int m = 0; m < 5; ++m) {
      const u16* src = (m == 0) ? a.embq_bf + (long)qn * 128
                                : a.embs_bf + (long)a.qs_sk[qn * 4 + (m - 1)] * 128;
      float s = 0.f;
      for (int k = 0; k < 128; k += 8) {
        uint4 u = *(const uint4*)&src[k];
        float f[8];
        unp2(u.x, f[0], f[1]); unp2(u.y, f[2], f[3]);
        unp2(u.z, f[4], f[5]); unp2(u.w, f[6], f[7]);
#pragma unroll
        for (int q = 0; q < 8; ++q) s = fmaf(f[q], a.kw[k + q], s);
      }
      am[m] = s + a.scal[1];
    }
    float mx = am[0];
#pragma unroll
    for (int m = 1; m < 5; ++m) mx = fmaxf(mx, am[m]);
    float ex[5], z = 0.f;
#pragma unroll
    for (int m = 0; m < 5; ++m) { ex[m] = __expf(am[m] - mx); z += ex[m]; }
    float iz = __builtin_amdgcn_rcpf(z);
#pragma unroll
    for (int m = 0; m < 5; ++m) a.pm[((long)b * PB + t) * 5 + m] = ex[m] * iz;
    return;
  }

  f32x4 acc[2][2];
  if (i >= 313) {   // f1
    const int tile0 = (i - 313) * 32;
    WF w1; load_WF(a.wts + 16384, l15, quad, cw, w1);
    stage_A(a.embs_bf, a.embq_bf, a.s_nb, 10, nullptr, tile0, NSd, tid, Al);
    __syncthreads();
    zero_acc(acc);
    mfma_WF(Al, w1, l15, quad, acc);
    epi_tanh_global(acc, a.agg_b + 128, a.tabs1, NSd, tile0, l15, quad, cw);
    return;
  }
  const int tile0 = i * 32;
  WF w2, w0;
  load_WF(a.wts + 2 * 16384, l15, quad, cw, w2);
  load_WF(a.wts, l15, quad, cw, w0);
  stage_A(a.embq_bf, a.embs_bf, a.q_nb, 4, nullptr, tile0, NQd, tid, Al);
  __syncthreads();
  zero_acc(acc);
  mfma_WF(Al, w2, l15, quad, acc);
  epi_tanh_global(acc, a.agg_b + 256, a.tabA, NQd, tile0, l15, quad, cw);  // f2
  zero_acc(acc);                            // Al unchanged: no barrier needed
  mfma_WF(Al, w0, l15, quad, acc);
  epi_tanh_global(acc, a.agg_b, a.tabB, NQd, tile0, l15, quad, cw);        // f0
}

// g1k: g1 = tanh((f1 + mean f2[s_nb]) @ W1 + b1), 16 blocks
__global__ __launch_bounds__(256) void g1k(Args a)
{
  __shared__ __align__(16) u16 Al[32 * 136];
  const int tid = threadIdx.x, tile0 = blockIdx.x * 32;
  const int lane = tid & 63, wv = tid >> 6;
  const int l15 = lane & 15, quad = lane >> 4, cw = wv * 32;
  WF w1; load_WF(a.wts + 16384, l15, quad, cw, w1);
  stage_A(a.tabs1, a.tabA, a.s_nb, 10, nullptr, tile0, NSd, tid, Al);
  __syncthreads();
  f32x4 acc[2][2];
  zero_acc(acc);
  mfma_WF(Al, w1, l15, quad, acc);
  epi_tanh_global(acc, a.agg_b + 128, a.tabs2, NSd, tile0, l15, quad, cw);
}

// chain4: g0 -> h0 -> agg -> qt fused in-block, COMPACT rows (used qids only).
// qt written to compact tabA rows; consumed via newidx in gates_k.
__global__ __launch_bounds__(256) void chain4(Args a)
{
  const int cnt = *a.cnt;
  const int tile0 = blockIdx.x * 32;
  if (tile0 >= cnt) return;
  __shared__ __align__(16) u16 Al[32 * 136];
  const int tid = threadIdx.x;
  const int lane = tid & 63, wv = tid >> 6;
  const int l15 = lane & 15, quad = lane >> 4, cw = wv * 32;
  WF w0, w3, w4;
  load_WF(a.wts, l15, quad, cw, w0);
  load_WF(a.wts + 3 * 16384, l15, quad, cw, w3);
  load_WF(a.wts + 4 * 16384, l15, quad, cw, w4);
  f32x4 acc[2][2];

  // phase 0: g0 = tanh((f0 + mean f1[q_nb]) @ W0 + b0)
  stage_A(a.tabB, a.tabs1, a.q_nb, 4, a.list, tile0, cnt, tid, Al);
  __syncthreads();
  zero_acc(acc);
  mfma_WF(Al, w0, l15, quad, acc);
  __syncthreads();
  epi_tanh_lds(acc, a.agg_b, Al, l15, quad, cw);       // Al = g0
  __syncthreads();
  // phase 1: h0 = tanh((g0 + mean g1[q_nb]) @ W0 + b0)
  update_A(a.tabs2, a.q_nb, a.list, tile0, cnt, tid, Al);
  __syncthreads();
  zero_acc(acc);
  mfma_WF(Al, w0, l15, quad, acc);
  __syncthreads();
  epi_tanh_lds(acc, a.agg_b, Al, l15, quad, cw);       // Al = h0
  __syncthreads();
  // phase 2: agg = tanh(h0 @ last_W + last_b)
  zero_acc(acc);
  mfma_WF(Al, w3, l15, quad, acc);
  __syncthreads();
  epi_tanh_lds(acc, a.last_b, Al, l15, quad, cw);      // Al = agg
  __syncthreads();
  // phase 3: qt = relu(agg @ ft_W + ft_b) -> compact tabA
  zero_acc(acc);
  mfma_WF(Al, w4, l15, quad, acc);
#pragma unroll
  for (int nt = 0; nt < 2; ++nt) {
    int col = cw + nt * 16 + l15;
    float cb = a.ft_b[col];
#pragma unroll
    for (int mt = 0; mt < 2; ++mt) {
      int rbase = tile0 + mt * 16 + quad * 4;
#pragma unroll
      for (int i = 0; i < 4; ++i) {
        int row = rbase + i;
        if (row >= cnt) continue;
        a.tabA[(long)row * 128 + col] = f2bf(fmaxf(acc[mt][nt][i] + cb, 0.f));
      }
    }
  }
}

// gates (i,g,o) + LSTM pointwise + a_state. 199 blocks x 32 rows.
__global__ __launch_bounds__(256) void gates_k(Args a)
{
  __shared__ __align__(16) u16 Al[32 * 136];
  __shared__ float hb[32 * 132];
  const int tid = threadIdx.x, tile0 = blockIdx.x * 32;
  const int lane = tid & 63, wv = tid >> 6;
  const int l15 = lane & 15, quad = lane >> 4, cw = wv * 32;
  WF wg0, wg1, wg2;
  load_WF(a.wiht, l15, quad, cw, wg0);                     // i-gate
  load_WF(a.wiht + (long)256 * 128, l15, quad, cw, wg1);   // g-gate
  load_WF(a.wiht + (long)384 * 128, l15, quad, cw, wg2);   // o-gate
  {
    int r = tid & 31, k0 = (tid >> 5) * 16;
    int row = tile0 + r;
    int arow = a.newidx[a.qid_map[row]];                   // compact qt row
    const u16* ap = a.tabA + (long)arow * 128 + k0;
    *(uint4*)&Al[r * 136 + k0]     = *(const uint4*)ap;
    *(uint4*)&Al[r * 136 + k0 + 8] = *(const uint4*)(ap + 8);
  }
  __syncthreads();
  f32x4 acc[3][2][2];
  zero_acc(acc[0]); mfma_WF(Al, wg0, l15, quad, acc[0]);
  zero_acc(acc[1]); mfma_WF(Al, wg1, l15, quad, acc[1]);
  zero_acc(acc[2]); mfma_WF(Al, wg2, l15, quad, acc[2]);
#pragma unroll
  for (int nt = 0; nt < 2; ++nt) {
    int colL = cw + nt * 16 + l15;
#pragma unroll
    for (int mt = 0; mt < 2; ++mt) {
#pragma unroll
      for (int i = 0; i < 4; ++i) {
        int rL = mt * 16 + quad * 4 + i;
        int row = tile0 + rL;
        const float* rb = a.er_part + (long)a.resp_map[row] * 512;
        float iv = acc[0][mt][nt][i] + rb[colL];
        float gv = acc[1][mt][nt][i] + rb[256 + colL];
        float ov = acc[2][mt][nt][i] + rb[384 + colL];
        float c = sigf(iv) * tanh_f(gv);
        float h = sigf(ov) * tanh_f(c);
        a.states[(long)row * 128 + colL] = f2bf(h);
        hb[rL * 132 + colL] = h;
      }
    }
  }
  __syncthreads();
#pragma unroll
  for (int rr = 0; rr < 8; ++rr) {
    int rL = wv * 8 + rr;
    float p = hb[rL * 132 + lane] * a.qw[lane] + hb[rL * 132 + 64 + lane] * a.qw[64 + lane];
#pragma unroll
    for (int off = 32; off > 0; off >>= 1) p += __shfl_xor(p, off);
    if (lane == 0) a.a_state[tile0 + rL] = p + a.scal[0];
  }
}

// ---------------------------------------------------------------------------
// bprep: per-batch: gmax -> ev, prefix-scan Z -> invZ
// ---------------------------------------------------------------------------
__global__ __launch_bounds__(256) void bprep(Args a)
{
  __shared__ float red[256];
  __shared__ float evl[256];
  const int b = blockIdx.x, tid = threadIdx.x;
  float v = (tid < Td) ? a.a_state[b * Td + tid] : -1e30f;
  red[tid] = v; __syncthreads();
  for (int s = 128; s > 0; s >>= 1) { if (tid < s) red[tid] = fmaxf(red[tid], red[tid + s]); __syncthreads(); }
  float gmax = red[0];
  float e = (tid < Td) ? __expf(v - gmax) : 0.f;
  evl[tid] = e;
  if (tid < Td) a.ev[b * PB + tid] = e;
  __syncthreads();
  for (int off = 1; off < 256; off <<= 1) {
    float add = (tid >= off) ? evl[tid - off] : 0.f;
    __syncthreads();
    evl[tid] += add;
    __syncthreads();
  }
  if (tid < Td) a.invZ[b * PB + tid] = 1.f / evl[tid];
}

// ---------------------------------------------------------------------------
// gk_pred: sigmoid(states.qs) * ev[n] * pm[t,m] * invZ[t] accumulated
// DIRECTLY into out[b, t+1] (out pre-zeroed in prep_all)
// ---------------------------------------------------------------------------
__global__ __launch_bounds__(256) void gk_pred(Args a, float* __restrict__ out)
{
  const int n0 = blockIdx.x * 32;
  const int c0 = blockIdx.y * 128;
  const int b  = blockIdx.z;
  int c_hi = c0 + 127; if (c_hi > 994) c_hi = 994;
  const int tmax = c_hi / 5, tmin = c0 / 5;
  if (n0 > tmax) return;

  __shared__ __align__(16) u16 smem[21760];
  __shared__ float predl[32];
  u16* Ql = smem;
  u16* Sl = smem + 17408;
  const int tid = threadIdx.x;
  if (tid < 32) predl[tid] = 0.f;
  {
    int r = tid & 31, k0 = (tid >> 5) * 16;
    int n = n0 + r; if (n > 198) n = 198;
    const u16* sp = a.states + ((long)b * Td + n) * 128 + k0;
    *(uint4*)&Sl[r * 136 + k0]     = *(const uint4*)sp;
    *(uint4*)&Sl[r * 136 + k0 + 8] = *(const uint4*)(sp + 8);
  }
  {
    int j = tid >> 1, k0 = (tid & 1) * 64;
    int col = c0 + j;
    uint4* dst = (uint4*)&Ql[j * 136 + k0];
    if (col < 995) {
      int t = col / 5, m = col - t * 5;
      int qn = a.question[b * Sd + t + 1];
      const u16* src = (m == 0) ? a.embq_bf + (long)qn * 128
                                : a.embs_bf + (long)a.qs_sk[qn * 4 + (m - 1)] * 128;
      src += k0;
#pragma unroll
      for (int q = 0; q < 8; ++q) dst[q] = ((const uint4*)src)[q];
    } else {
      uint4 z = make_uint4(0, 0, 0, 0);
#pragma unroll
      for (int q = 0; q < 8; ++q) dst[q] = z;
    }
  }
  __syncthreads();
  const int lane = tid & 63, wv = tid >> 6;
  const int l15 = lane & 15, quad = lane >> 4, cw = wv * 32;
  f32x4 acc[2][2];
  zero_acc(acc);
#pragma unroll
  for (int kc = 0; kc < 4; ++kc) {
    const int ko = kc * 32 + quad * 8;
    bf16x8 af[2], bfv[2];
    af[0]  = *(const bf16x8*)&Sl[l15 * 136 + ko];
    af[1]  = *(const bf16x8*)&Sl[(16 + l15) * 136 + ko];
    bfv[0] = *(const bf16x8*)&Ql[(cw + l15) * 136 + ko];
    bfv[1] = *(const bf16x8*)&Ql[(cw + 16 + l15) * 136 + ko];
#pragma unroll
    for (int mt = 0; mt < 2; ++mt)
#pragma unroll
      for (int nt = 0; nt < 2; ++nt)
        acc[mt][nt] = __builtin_amdgcn_mfma_f32_16x16x32_bf16(af[mt], bfv[nt], acc[mt][nt], 0, 0, 0);
  }

#pragma unroll
  for (int nt = 0; nt < 2; ++nt) {
    int col = c0 + cw + nt * 16 + l15;
    if (col >= 995) continue;
    int t = col / 5, m = col - t * 5;
    float pmv = a.pm[((long)b * PB + t) * 5 + m];
    float part = 0.f;
#pragma unroll
    for (int mt = 0; mt < 2; ++mt) {
      int nb = n0 + mt * 16 + quad * 4;
      if (nb > t) continue;
      float4 ev4 = *(const float4*)&a.ev[b * PB + nb];
      float evv[4] = {ev4.x, ev4.y, ev4.z, ev4.w};
#pragma unroll
      for (int i = 0; i < 4; ++i) {
        int n = nb + i;
        if (n > t || n > 198) continue;
        part += evv[i] * sigf(acc[mt][nt][i]);
      }
    }
    part *= pmv;
    if (part != 0.f) atomicAdd(&predl[t - tmin], part);
  }
  __syncthreads();
  const int tcnt = tmax - tmin + 1;
  if (tid < tcnt) {
    int t = tmin + tid;
    float pv = predl[tid];
    if (pv != 0.f)
      atomicAdd(&out[b * Sd + t + 1], pv * a.invZ[b * PB + t]);
  }
}

// ---------------------------------------------------------------------------
extern "C" void kernel_launch(void* const* d_in, const int* in_sizes, int n_in,
                              void* d_out, int out_size, void* d_ws, size_t ws_size,
                              hipStream_t stream)
{
  Args a;
  a.question = (const int*)d_in[0];
  a.response = (const int*)d_in[1];
  a.q_nb     = (const int*)d_in[3];
  a.s_nb     = (const int*)d_in[4];
  a.qs_sk    = (const int*)d_in[5];
  a.emb_q    = (const float*)d_in[6];
  a.emb_s    = (const float*)d_in[7];
  a.emb_r    = (const float*)d_in[8];
  a.W_ih     = (const float*)d_in[9];
  a.b_ih     = (const float*)d_in[10];
  a.b_hh     = (const float*)d_in[11];
  a.ft_W     = (const float*)d_in[12];
  a.ft_b     = (const float*)d_in[13];
  a.agg_W    = (const float*)d_in[14];
  a.agg_b    = (const float*)d_in[15];
  a.last_W   = (const float*)d_in[16];
  a.last_b   = (const float*)d_in[17];
  a.q_W      = (const float*)d_in[18];
  a.q_b      = (const float*)d_in[19];
  a.k_W      = (const float*)d_in[20];
  a.k_b      = (const float*)d_in[21];
  a.w_W      = (const float*)d_in[22];

  u16* wsu = (u16*)d_ws;
  const long NT = 1280000, ST = 64000, RT = (long)NR * Dd;
  a.tabA  = wsu;                 // NT (f2, later compact qt)
  a.tabB  = a.tabA + NT;         // NT (f0)
  a.tabs1 = a.tabB + NT;         // ST (f1)
  a.tabs2 = a.tabs1 + ST;        // ST (g1)
  a.states  = a.tabs2 + ST;      // RT
  a.embq_bf = a.states + RT;     // NT
  a.embs_bf = a.embq_bf + NT;    // ST
  a.wts     = a.embs_bf + ST;    // 5*16384
  a.wiht    = a.wts + 5 * 16384; // 65536
  float* fp = (float*)(a.wiht + 65536);
  a.a_state = fp;                       // 6368
  a.qw      = fp + 6368;                // 128
  a.kw      = fp + 6496;                // 128
  a.scal    = fp + 6624;                // 16
  a.er_part = fp + 6640;                // 1024
  a.ev      = fp + 7664;                // 32*208
  a.invZ    = a.ev + 32 * PB;
  a.pm      = a.invZ + 32 * PB;         // 32*208*5
  a.qid_map  = (int*)(a.pm + 32 * PB * 5);
  a.resp_map = a.qid_map + NR;
  a.flag     = a.resp_map + NR;         // 10000  (memset 0)
  a.cnt      = a.flag + NQd;            // 4      (memset 0)
  a.list     = a.cnt + 4;               // 10000
  a.newidx   = a.list + NQd;            // 10000

  float* out = (float*)d_out;

  hipMemsetAsync(a.flag, 0, (NQd + 4) * sizeof(int), stream);  // flag + cnt
  prep_all<<<640, 256, 0, stream>>>(a, out);
  level1m<<<354, 256, 0, stream>>>(a);     // f2/f0 | f1 | pm filler
  g1k<<<16, 256, 0, stream>>>(a);
  chain4<<<199, 256, 0, stream>>>(a);      // compact rows, early-exit on cnt
  gates_k<<<199, 256, 0, stream>>>(a);
  bprep<<<Bd, 256, 0, stream>>>(a);
  gk_pred<<<dim3(7, 8, Bd), 256, 0, stream>>>(a, out);
}

// Round 11
// 186.381 us; speedup vs baseline: 1.1452x; 1.0250x over previous
//
#include <hip/hip_runtime.h>

typedef unsigned short u16;
typedef unsigned int   u32;

#define NQd 10000
#define NSd 500
#define Bd  32
#define Sd  200
#define Td  199   // S-1
#define Dd  128
#define NR  6368  // Bd*Td
#define PB  208   // padded per-batch stride for ev/invZ/pm

typedef __attribute__((ext_vector_type(8))) short bf16x8;
typedef __attribute__((ext_vector_type(4))) float f32x4;

__device__ __forceinline__ float sigf(float x) {
  return __builtin_amdgcn_rcpf(1.f + __expf(-x));
}
__device__ __forceinline__ float tanh_f(float x) {
  float ax = fminf(fabsf(x), 15.f);
  float e = __expf(2.f * ax);
  float r = 1.f - 2.f * __builtin_amdgcn_rcpf(e + 1.f);
  return copysignf(r, x);
}
__device__ __forceinline__ float bf2f(u16 u) { return __uint_as_float(((u32)u) << 16); }
__device__ __forceinline__ u16 f2bf(float f) {            // round-to-nearest-even
  u32 b = __float_as_uint(f);
  b += 0x7FFFu + ((b >> 16) & 1u);
  return (u16)(b >> 16);
}
__device__ __forceinline__ float rnd(float x) { return bf2f(f2bf(x)); }  // bf16 round
__device__ __forceinline__ void unp2(u32 u, float &a, float &b) {
  a = __uint_as_float(u << 16);
  b = __uint_as_float(u & 0xffff0000u);
}
__device__ __forceinline__ void unpack16(uint4 a0, uint4 a1, float* f) {
  unp2(a0.x, f[0], f[1]);  unp2(a0.y, f[2], f[3]);
  unp2(a0.z, f[4], f[5]);  unp2(a0.w, f[6], f[7]);
  unp2(a1.x, f[8], f[9]);  unp2(a1.y, f[10], f[11]);
  unp2(a1.z, f[12], f[13]); unp2(a1.w, f[14], f[15]);
}

struct Args {
  const int *question, *response, *q_nb, *s_nb, *qs_sk;
  const float *emb_q, *emb_s, *emb_r;
  const float *W_ih, *b_ih, *b_hh, *ft_W, *ft_b, *agg_W, *agg_b, *last_W, *last_b;
  const float *q_W, *q_b, *k_W, *k_b, *w_W;
  u16 *tabA, *tabB, *tabs1, *tabs2, *states, *embq_bf, *embs_bf, *wts, *wiht;
  float *a_state, *qw, *kw, *scal, *er_part, *ev, *invZ, *pm;
  int *qid_map, *resp_map, *flag, *cnt, *list, *newidx;
};

// W fragment held in registers: 2 n-tiles x 4 k-chunks x bf16x8 = 16 VGPR
struct WF { bf16x8 v[2][4]; };

__device__ __forceinline__ void load_WF(const u16* Wt, int l15, int quad, int cw, WF& w)
{
#pragma unroll
  for (int nt = 0; nt < 2; ++nt)
#pragma unroll
    for (int kc = 0; kc < 4; ++kc)
      w.v[nt][kc] = *(const bf16x8*)&Wt[(long)(cw + nt * 16 + l15) * 128 + kc * 32 + quad * 8];
}

// same fragment loaded straight from f32 W[k][col] with inline bf16 rounding
__device__ __forceinline__ void load_WF_f32(const float* W, int l15, int quad, int cw, WF& w)
{
#pragma unroll
  for (int nt = 0; nt < 2; ++nt) {
    int col = cw + nt * 16 + l15;
#pragma unroll
    for (int kc = 0; kc < 4; ++kc) {
      int kb = kc * 32 + quad * 8;
      bf16x8 t;
#pragma unroll
      for (int j = 0; j < 8; ++j) t[j] = (short)f2bf(W[(long)(kb + j) * 128 + col]);
      w.v[nt][kc] = t;
    }
  }
}

__device__ __forceinline__ void zero_acc(f32x4 acc[2][2]) {
#pragma unroll
  for (int x = 0; x < 2; ++x)
#pragma unroll
    for (int y = 0; y < 2; ++y) acc[x][y] = (f32x4){0.f, 0.f, 0.f, 0.f};
}

// MFMA with A from LDS, B from register fragments
__device__ __forceinline__ void mfma_WF(const u16* Al, const WF& w,
                                        int l15, int quad, f32x4 acc[2][2])
{
#pragma unroll
  for (int kc = 0; kc < 4; ++kc) {
    const int ko = kc * 32 + quad * 8;
    bf16x8 a0 = *(const bf16x8*)&Al[l15 * 136 + ko];
    bf16x8 a1 = *(const bf16x8*)&Al[(16 + l15) * 136 + ko];
    acc[0][0] = __builtin_amdgcn_mfma_f32_16x16x32_bf16(a0, w.v[0][kc], acc[0][0], 0, 0, 0);
    acc[0][1] = __builtin_amdgcn_mfma_f32_16x16x32_bf16(a0, w.v[1][kc], acc[0][1], 0, 0, 0);
    acc[1][0] = __builtin_amdgcn_mfma_f32_16x16x32_bf16(a1, w.v[0][kc], acc[1][0], 0, 0, 0);
    acc[1][1] = __builtin_amdgcn_mfma_f32_16x16x32_bf16(a1, w.v[1][kc], acc[1][1], 0, 0, 0);
  }
}

// stage one 32-row gathered input tile into Al (bf16). rowmap: optional compaction.
__device__ __forceinline__ void stage_A(const u16* Atab, const u16* Btab,
                                        const int* nbr, int K, const int* rowmap,
                                        int tile0, int rows, int tid, u16* Al)
{
  int r = tid & 31, k0 = (tid >> 5) * 16;
  int row = tile0 + r; if (row >= rows) row = rows - 1;
  int arow = rowmap ? rowmap[row] : row;
  const u16* ap = Atab + (long)arow * 128 + k0;
  if (K == 0) {
    *(uint4*)&Al[r * 136 + k0]     = *(const uint4*)ap;
    *(uint4*)&Al[r * 136 + k0 + 8] = *(const uint4*)(ap + 8);
  } else {
    float f[16];
    unpack16(*(const uint4*)ap, *(const uint4*)(ap + 8), f);
    float s[16];
#pragma unroll
    for (int q = 0; q < 16; ++q) s[q] = 0.f;
    for (int l = 0; l < K; ++l) {
      int id = nbr[(long)arow * K + l];
      const u16* np = Btab + (long)id * 128 + k0;
      float g[16];
      unpack16(*(const uint4*)np, *(const uint4*)(np + 8), g);
#pragma unroll
      for (int q = 0; q < 16; ++q) s[q] += g[q];
    }
    float inv = 1.f / (float)K;
#pragma unroll
    for (int q = 0; q < 16; ++q) f[q] += s[q] * inv;
    u32 p[8];
#pragma unroll
    for (int q = 0; q < 8; ++q)
      p[q] = (u32)f2bf(f[2 * q]) | ((u32)f2bf(f[2 * q + 1]) << 16);
    *(uint4*)&Al[r * 136 + k0]     = make_uint4(p[0], p[1], p[2], p[3]);
    *(uint4*)&Al[r * 136 + k0 + 8] = make_uint4(p[4], p[5], p[6], p[7]);
  }
}

// gather from RAW f32 tables with inline bf16 rounding (bit-identical to
// staging through the bf16 copies)
__device__ __forceinline__ void ld16_rnd(const float* p, float* f)
{
#pragma unroll
  for (int q4 = 0; q4 < 4; ++q4) {
    float4 v = *(const float4*)(p + q4 * 4);
    f[q4 * 4 + 0] = rnd(v.x); f[q4 * 4 + 1] = rnd(v.y);
    f[q4 * 4 + 2] = rnd(v.z); f[q4 * 4 + 3] = rnd(v.w);
  }
}

__device__ __forceinline__ void stage_A_f32(const float* Atab, const float* Btab,
                                            const int* nbr, int K,
                                            int tile0, int rows, int tid, u16* Al)
{
  int r = tid & 31, k0 = (tid >> 5) * 16;
  int row = tile0 + r; if (row >= rows) row = rows - 1;
  float f[16];
  ld16_rnd(Atab + (long)row * 128 + k0, f);
  float s[16];
#pragma unroll
  for (int q = 0; q < 16; ++q) s[q] = 0.f;
  for (int l = 0; l < K; ++l) {
    int id = nbr[(long)row * K + l];
    float g[16];
    ld16_rnd(Btab + (long)id * 128 + k0, g);
#pragma unroll
    for (int q = 0; q < 16; ++q) s[q] += g[q];
  }
  float inv = 1.f / (float)K;
#pragma unroll
  for (int q = 0; q < 16; ++q) f[q] += s[q] * inv;
  u32 p[8];
#pragma unroll
  for (int q = 0; q < 8; ++q)
    p[q] = (u32)f2bf(f[2 * q]) | ((u32)f2bf(f[2 * q + 1]) << 16);
  *(uint4*)&Al[r * 136 + k0]     = make_uint4(p[0], p[1], p[2], p[3]);
  *(uint4*)&Al[r * 136 + k0 + 8] = make_uint4(p[4], p[5], p[6], p[7]);
}

// Al := bf16(Al + mean_{l<4} Btab[nbr[arow*4+l]])
__device__ __forceinline__ void update_A(const u16* Btab, const int* nbr,
                                         const int* rowmap, int tile0, int rows,
                                         int tid, u16* Al)
{
  int r = tid & 31, k0 = (tid >> 5) * 16;
  int row = tile0 + r; if (row >= rows) row = rows - 1;
  int arow = rowmap ? rowmap[row] : row;
  float f[16];
  unpack16(*(const uint4*)&Al[r * 136 + k0], *(const uint4*)&Al[r * 136 + k0 + 8], f);
  float s[16];
#pragma unroll
  for (int q = 0; q < 16; ++q) s[q] = 0.f;
#pragma unroll
  for (int l = 0; l < 4; ++l) {
    int id = nbr[(long)arow * 4 + l];
    const u16* np = Btab + (long)id * 128 + k0;
    float g[16];
    unpack16(*(const uint4*)np, *(const uint4*)(np + 8), g);
#pragma unroll
    for (int q = 0; q < 16; ++q) s[q] += g[q];
  }
#pragma unroll
  for (int q = 0; q < 16; ++q) f[q] += s[q] * 0.25f;
  u32 p[8];
#pragma unroll
  for (int q = 0; q < 8; ++q)
    p[q] = (u32)f2bf(f[2 * q]) | ((u32)f2bf(f[2 * q + 1]) << 16);
  *(uint4*)&Al[r * 136 + k0]     = make_uint4(p[0], p[1], p[2], p[3]);
  *(uint4*)&Al[r * 136 + k0 + 8] = make_uint4(p[4], p[5], p[6], p[7]);
}

// epilogue: tanh -> global table
__device__ __forceinline__ void epi_tanh_global(const f32x4 acc[2][2], const float* cbias,
                                                u16* out, int rows, int tile0,
                                                int l15, int quad, int cw)
{
#pragma unroll
  for (int nt = 0; nt < 2; ++nt) {
    int col = cw + nt * 16 + l15;
    float cb = cbias[col];
#pragma unroll
    for (int mt = 0; mt < 2; ++mt) {
      int rbase = tile0 + mt * 16 + quad * 4;
#pragma unroll
      for (int i = 0; i < 4; ++i) {
        int row = rbase + i;
        if (row >= rows) continue;
        out[(long)row * 128 + col] = f2bf(tanh_f(acc[mt][nt][i] + cb));
      }
    }
  }
}

// epilogue: tanh -> LDS Al
__device__ __forceinline__ void epi_tanh_lds(const f32x4 acc[2][2], const float* cbias,
                                             u16* Al, int l15, int quad, int cw)
{
#pragma unroll
  for (int nt = 0; nt < 2; ++nt) {
    int col = cw + nt * 16 + l15;
    float cb = cbias[col];
#pragma unroll
    for (int mt = 0; mt < 2; ++mt)
#pragma unroll
      for (int i = 0; i < 4; ++i) {
        int rL = mt * 16 + quad * 4 + i;
        Al[rL * 136 + col] = f2bf(tanh_f(acc[mt][nt][i] + cb));
      }
  }
}

// ---------------------------------------------------------------------------
// prep2: ONE launch with all mutually-independent work:
//   blocks 0..312   : f2 + f0 tiles (gather + W straight from f32 inputs)
//   blocks 313..328 : f1 tiles (f32 inputs)
//   blocks 329..968 : conversions, transposed weights, maps+list, small dots,
//                     zero d_out (grid-stride)
// ---------------------------------------------------------------------------
__global__ __launch_bounds__(256) void prep2(Args a, float* __restrict__ out)
{
  __shared__ __align__(16) u16 Al[32 * 136];
  const int i = blockIdx.x, tid = threadIdx.x;
  const int lane = tid & 63, wv = tid >> 6;
  const int l15 = lane & 15, quad = lane >> 4, cw = wv * 32;

  if (i < 313) {           // f2 + f0 from one gather
    const int tile0 = i * 32;
    WF w2, w0;
    load_WF_f32(a.agg_W + 2 * 16384, l15, quad, cw, w2);
    load_WF_f32(a.agg_W, l15, quad, cw, w0);
    stage_A_f32(a.emb_q, a.emb_s, a.q_nb, 4, tile0, NQd, tid, Al);
    __syncthreads();
    f32x4 acc[2][2];
    zero_acc(acc);
    mfma_WF(Al, w2, l15, quad, acc);
    epi_tanh_global(acc, a.agg_b + 256, a.tabA, NQd, tile0, l15, quad, cw);  // f2
    zero_acc(acc);
    mfma_WF(Al, w0, l15, quad, acc);
    epi_tanh_global(acc, a.agg_b, a.tabB, NQd, tile0, l15, quad, cw);        // f0
    return;
  }
  if (i < 329) {           // f1
    const int tile0 = (i - 313) * 32;
    WF w1;
    load_WF_f32(a.agg_W + 16384, l15, quad, cw, w1);
    stage_A_f32(a.emb_s, a.emb_q, a.s_nb, 10, tile0, NSd, tid, Al);
    __syncthreads();
    f32x4 acc[2][2];
    zero_acc(acc);
    mfma_WF(Al, w1, l15, quad, acc);
    epi_tanh_global(acc, a.agg_b + 128, a.tabs1, NSd, tile0, l15, quad, cw);
    return;
  }

  // conversion / scalar region
  const int T = 640 * 256;
  for (int j = (i - 329) * 256 + tid; j < 497506; j += T) {
    if (j < 320000) {
      float4 v = *(const float4*)&a.emb_q[(long)j * 4];
      ((uint2*)a.embq_bf)[j] = make_uint2(
          (u32)f2bf(v.x) | ((u32)f2bf(v.y) << 16),
          (u32)f2bf(v.z) | ((u32)f2bf(v.w) << 16));
    } else if (j < 336000) {
      int c = j - 320000;
      float4 v = *(const float4*)&a.emb_s[(long)c * 4];
      ((uint2*)a.embs_bf)[c] = make_uint2(
          (u32)f2bf(v.x) | ((u32)f2bf(v.y) << 16),
          (u32)f2bf(v.z) | ((u32)f2bf(v.w) << 16));
    } else if (j < 417920) {
      int e = j - 336000;
      int seg = e >> 14, r = e & 16383;
      int col = r >> 7, k = r & 127;
      const float* src = (seg < 3) ? (a.agg_W + seg * 16384)
                                   : (seg == 3 ? a.last_W : a.ft_W);
      a.wts[e] = f2bf(src[k * 128 + col]);
    } else if (j < 483456) {
      int e = j - 417920;
      int col = e >> 7, k = e & 127;
      a.wiht[e] = f2bf(a.W_ih[k * 512 + col]);
    } else if (j < 489824) {
      int jj = j - 483456;
      int b = jj / Td, s = jj - b * Td;
      int qid = a.question[b * Sd + s];
      a.qid_map[jj]  = qid;
      a.resp_map[jj] = a.response[b * Sd + s];
      if (atomicExch(&a.flag[qid], 1) == 0) {     // first toucher appends
        int idx = atomicAdd(a.cnt, 1);
        a.list[idx] = qid;
        a.newidx[qid] = idx;
      }
    } else if (j < 491106) {
      int s = j - 489824;
      if (s < 128) {
        float acc = 0;
        for (int e = 0; e < 128; ++e) acc += a.q_W[s * 128 + e] * a.w_W[e];
        a.qw[s] = acc;
      } else if (s < 256) {
        int d = s - 128; float acc = 0;
        for (int e = 0; e < 128; ++e) acc += a.k_W[d * 128 + e] * a.w_W[128 + e];
        a.kw[d] = acc;
      } else if (s == 256) {
        float acc = 0;
        for (int e = 0; e < 128; ++e) acc += a.q_b[e] * a.w_W[e];
        a.scal[0] = acc;
      } else if (s == 257) {
        float acc = 0;
        for (int e = 0; e < 128; ++e) acc += a.k_b[e] * a.w_W[128 + e];
        a.scal[1] = acc;
      } else {
        int e2 = s - 258, rr = e2 >> 9, col = e2 & 511;
        float acc = a.b_ih[col] + a.b_hh[col];
        for (int d = 0; d < 128; ++d) acc += a.emb_r[rr * Dd + d] * a.W_ih[(128 + d) * 512 + col];
        a.er_part[rr * 512 + col] = acc;
      }
    } else {
      out[j - 491106] = 0.f;     // zero d_out (gk_pred accumulates into it)
    }
  }
}

// g1k: g1 = tanh((f1 + mean f2[s_nb]) @ W1 + b1), 16 blocks
__global__ __launch_bounds__(256) void g1k(Args a)
{
  __shared__ __align__(16) u16 Al[32 * 136];
  const int tid = threadIdx.x, tile0 = blockIdx.x * 32;
  const int lane = tid & 63, wv = tid >> 6;
  const int l15 = lane & 15, quad = lane >> 4, cw = wv * 32;
  WF w1; load_WF(a.wts + 16384, l15, quad, cw, w1);
  stage_A(a.tabs1, a.tabA, a.s_nb, 10, nullptr, tile0, NSd, tid, Al);
  __syncthreads();
  f32x4 acc[2][2];
  zero_acc(acc);
  mfma_WF(Al, w1, l15, quad, acc);
  epi_tanh_global(acc, a.agg_b + 128, a.tabs2, NSd, tile0, l15, quad, cw);
}

// chain4: g0 -> h0 -> agg -> qt fused in-block, COMPACT rows (used qids only)
__global__ __launch_bounds__(256) void chain4(Args a)
{
  const int cnt = *a.cnt;
  const int tile0 = blockIdx.x * 32;
  if (tile0 >= cnt) return;
  __shared__ __align__(16) u16 Al[32 * 136];
  const int tid = threadIdx.x;
  const int lane = tid & 63, wv = tid >> 6;
  const int l15 = lane & 15, quad = lane >> 4, cw = wv * 32;
  WF w0, w3, w4;
  load_WF(a.wts, l15, quad, cw, w0);
  load_WF(a.wts + 3 * 16384, l15, quad, cw, w3);
  load_WF(a.wts + 4 * 16384, l15, quad, cw, w4);
  f32x4 acc[2][2];

  // phase 0: g0 = tanh((f0 + mean f1[q_nb]) @ W0 + b0)
  stage_A(a.tabB, a.tabs1, a.q_nb, 4, a.list, tile0, cnt, tid, Al);
  __syncthreads();
  zero_acc(acc);
  mfma_WF(Al, w0, l15, quad, acc);
  __syncthreads();
  epi_tanh_lds(acc, a.agg_b, Al, l15, quad, cw);       // Al = g0
  __syncthreads();
  // phase 1: h0 = tanh((g0 + mean g1[q_nb]) @ W0 + b0)
  update_A(a.tabs2, a.q_nb, a.list, tile0, cnt, tid, Al);
  __syncthreads();
  zero_acc(acc);
  mfma_WF(Al, w0, l15, quad, acc);
  __syncthreads();
  epi_tanh_lds(acc, a.agg_b, Al, l15, quad, cw);       // Al = h0
  __syncthreads();
  // phase 2: agg = tanh(h0 @ last_W + last_b)
  zero_acc(acc);
  mfma_WF(Al, w3, l15, quad, acc);
  __syncthreads();
  epi_tanh_lds(acc, a.last_b, Al, l15, quad, cw);      // Al = agg
  __syncthreads();
  // phase 3: qt = relu(agg @ ft_W + ft_b) -> compact tabA
  zero_acc(acc);
  mfma_WF(Al, w4, l15, quad, acc);
#pragma unroll
  for (int nt = 0; nt < 2; ++nt) {
    int col = cw + nt * 16 + l15;
    float cb = a.ft_b[col];
#pragma unroll
    for (int mt = 0; mt < 2; ++mt) {
      int rbase = tile0 + mt * 16 + quad * 4;
#pragma unroll
      for (int i = 0; i < 4; ++i) {
        int row = rbase + i;
        if (row >= cnt) continue;
        a.tabA[(long)row * 128 + col] = f2bf(fmaxf(acc[mt][nt][i] + cb, 0.f));
      }
    }
  }
}

// gates (i,g,o) + LSTM + a_state (blocks 0..198) | pm table (blocks 199..223)
__global__ __launch_bounds__(256) void gates_k(Args a)
{
  __shared__ __align__(16) u16 Al[32 * 136];
  __shared__ float hb[32 * 132];
  const int tid = threadIdx.x;
  const int lane = tid & 63, wv = tid >> 6;
  const int l15 = lane & 15, quad = lane >> 4, cw = wv * 32;

  if (blockIdx.x >= 199) {   // pm: one (b,t) per thread
    int item = (blockIdx.x - 199) * 256 + tid;
    if (item >= NR) return;
    int b = item / Td, t = item - b * Td;
    int qn = a.question[b * Sd + t + 1];
    float am[5];
#pragma unroll
    for (int m = 0; m < 5; ++m) {
      const u16* src = (m == 0) ? a.embq_bf + (long)qn * 128
                                : a.embs_bf + (long)a.qs_sk[qn * 4 + (m - 1)] * 128;
      float s = 0.f;
      for (int k = 0; k < 128; k += 8) {
        uint4 u = *(const uint4*)&src[k];
        float f[8];
        unp2(u.x, f[0], f[1]); unp2(u.y, f[2], f[3]);
        unp2(u.z, f[4], f[5]); unp2(u.w, f[6], f[7]);
#pragma unroll
        for (int q = 0; q < 8; ++q) s = fmaf(f[q], a.kw[k + q], s);
      }
      am[m] = s + a.scal[1];
    }
    float mx = am[0];
#pragma unroll
    for (int m = 1; m < 5; ++m) mx = fmaxf(mx, am[m]);
    float ex[5], z = 0.f;
#pragma unroll
    for (int m = 0; m < 5; ++m) { ex[m] = __expf(am[m] - mx); z += ex[m]; }
    float iz = __builtin_amdgcn_rcpf(z);
#pragma unroll
    for (int m = 0; m < 5; ++m) a.pm[((long)b * PB + t) * 5 + m] = ex[m] * iz;
    return;
  }

  const int tile0 = blockIdx.x * 32;
  WF wg0, wg1, wg2;
  load_WF(a.wiht, l15, quad, cw, wg0);                     // i-gate
  load_WF(a.wiht + (long)256 * 128, l15, quad, cw, wg1);   // g-gate
  load_WF(a.wiht + (long)384 * 128, l15, quad, cw, wg2);   // o-gate
  {
    int r = tid & 31, k0 = (tid >> 5) * 16;
    int row = tile0 + r;
    int arow = a.newidx[a.qid_map[row]];                   // compact qt row
    const u16* ap = a.tabA + (long)arow * 128 + k0;
    *(uint4*)&Al[r * 136 + k0]     = *(const uint4*)ap;
    *(uint4*)&Al[r * 136 + k0 + 8] = *(const uint4*)(ap + 8);
  }
  __syncthreads();
  f32x4 acc[3][2][2];
  zero_acc(acc[0]); mfma_WF(Al, wg0, l15, quad, acc[0]);
  zero_acc(acc[1]); mfma_WF(Al, wg1, l15, quad, acc[1]);
  zero_acc(acc[2]); mfma_WF(Al, wg2, l15, quad, acc[2]);
#pragma unroll
  for (int nt = 0; nt < 2; ++nt) {
    int colL = cw + nt * 16 + l15;
#pragma unroll
    for (int mt = 0; mt < 2; ++mt) {
#pragma unroll
      for (int i = 0; i < 4; ++i) {
        int rL = mt * 16 + quad * 4 + i;
        int row = tile0 + rL;
        const float* rb = a.er_part + (long)a.resp_map[row] * 512;
        float iv = acc[0][mt][nt][i] + rb[colL];
        float gv = acc[1][mt][nt][i] + rb[256 + colL];
        float ov = acc[2][mt][nt][i] + rb[384 + colL];
        float c = sigf(iv) * tanh_f(gv);
        float h = sigf(ov) * tanh_f(c);
        a.states[(long)row * 128 + colL] = f2bf(h);
        hb[rL * 132 + colL] = h;
      }
    }
  }
  __syncthreads();
#pragma unroll
  for (int rr = 0; rr < 8; ++rr) {
    int rL = wv * 8 + rr;
    float p = hb[rL * 132 + lane] * a.qw[lane] + hb[rL * 132 + 64 + lane] * a.qw[64 + lane];
#pragma unroll
    for (int off = 32; off > 0; off >>= 1) p += __shfl_xor(p, off);
    if (lane == 0) a.a_state[tile0 + rL] = p + a.scal[0];
  }
}

// ---------------------------------------------------------------------------
// bprep: per-batch: gmax -> ev, prefix-scan Z -> invZ
// ---------------------------------------------------------------------------
__global__ __launch_bounds__(256) void bprep(Args a)
{
  __shared__ float red[256];
  __shared__ float evl[256];
  const int b = blockIdx.x, tid = threadIdx.x;
  float v = (tid < Td) ? a.a_state[b * Td + tid] : -1e30f;
  red[tid] = v; __syncthreads();
  for (int s = 128; s > 0; s >>= 1) { if (tid < s) red[tid] = fmaxf(red[tid], red[tid + s]); __syncthreads(); }
  float gmax = red[0];
  float e = (tid < Td) ? __expf(v - gmax) : 0.f;
  evl[tid] = e;
  if (tid < Td) a.ev[b * PB + tid] = e;
  __syncthreads();
  for (int off = 1; off < 256; off <<= 1) {
    float add = (tid >= off) ? evl[tid - off] : 0.f;
    __syncthreads();
    evl[tid] += add;
    __syncthreads();
  }
  if (tid < Td) a.invZ[b * PB + tid] = 1.f / evl[tid];
}

// ---------------------------------------------------------------------------
// gk_pred: sigmoid(states.qs) * ev[n] * pm[t,m] * invZ[t] accumulated
// DIRECTLY into out[b, t+1] (out pre-zeroed in prep2)
// ---------------------------------------------------------------------------
__global__ __launch_bounds__(256) void gk_pred(Args a, float* __restrict__ out)
{
  const int n0 = blockIdx.x * 32;
  const int c0 = blockIdx.y * 128;
  const int b  = blockIdx.z;
  int c_hi = c0 + 127; if (c_hi > 994) c_hi = 994;
  const int tmax = c_hi / 5, tmin = c0 / 5;
  if (n0 > tmax) return;

  __shared__ __align__(16) u16 smem[21760];
  __shared__ float predl[32];
  u16* Ql = smem;
  u16* Sl = smem + 17408;
  const int tid = threadIdx.x;
  if (tid < 32) predl[tid] = 0.f;
  {
    int r = tid & 31, k0 = (tid >> 5) * 16;
    int n = n0 + r; if (n > 198) n = 198;
    const u16* sp = a.states + ((long)b * Td + n) * 128 + k0;
    *(uint4*)&Sl[r * 136 + k0]     = *(const uint4*)sp;
    *(uint4*)&Sl[r * 136 + k0 + 8] = *(const uint4*)(sp + 8);
  }
  {
    int j = tid >> 1, k0 = (tid & 1) * 64;
    int col = c0 + j;
    uint4* dst = (uint4*)&Ql[j * 136 + k0];
    if (col < 995) {
      int t = col / 5, m = col - t * 5;
      int qn = a.question[b * Sd + t + 1];
      const u16* src = (m == 0) ? a.embq_bf + (long)qn * 128
                                : a.embs_bf + (long)a.qs_sk[qn * 4 + (m - 1)] * 128;
      src += k0;
#pragma unroll
      for (int q = 0; q < 8; ++q) dst[q] = ((const uint4*)src)[q];
    } else {
      uint4 z = make_uint4(0, 0, 0, 0);
#pragma unroll
      for (int q = 0; q < 8; ++q) dst[q] = z;
    }
  }
  __syncthreads();
  const int lane = tid & 63, wv = tid >> 6;
  const int l15 = lane & 15, quad = lane >> 4, cw = wv * 32;
  f32x4 acc[2][2];
  zero_acc(acc);
#pragma unroll
  for (int kc = 0; kc < 4; ++kc) {
    const int ko = kc * 32 + quad * 8;
    bf16x8 af[2], bfv[2];
    af[0]  = *(const bf16x8*)&Sl[l15 * 136 + ko];
    af[1]  = *(const bf16x8*)&Sl[(16 + l15) * 136 + ko];
    bfv[0] = *(const bf16x8*)&Ql[(cw + l15) * 136 + ko];
    bfv[1] = *(const bf16x8*)&Ql[(cw + 16 + l15) * 136 + ko];
#pragma unroll
    for (int mt = 0; mt < 2; ++mt)
#pragma unroll
      for (int nt = 0; nt < 2; ++nt)
        acc[mt][nt] = __builtin_amdgcn_mfma_f32_16x16x32_bf16(af[mt], bfv[nt], acc[mt][nt], 0, 0, 0);
  }

#pragma unroll
  for (int nt = 0; nt < 2; ++nt) {
    int col = c0 + cw + nt * 16 + l15;
    if (col >= 995) continue;
    int t = col / 5, m = col - t * 5;
    float pmv = a.pm[((long)b * PB + t) * 5 + m];
    float part = 0.f;
#pragma unroll
    for (int mt = 0; mt < 2; ++mt) {
      int nb = n0 + mt * 16 + quad * 4;
      if (nb > t) continue;
      float4 ev4 = *(const float4*)&a.ev[b * PB + nb];
      float evv[4] = {ev4.x, ev4.y, ev4.z, ev4.w};
#pragma unroll
      for (int i = 0; i < 4; ++i) {
        int n = nb + i;
        if (n > t || n > 198) continue;
        part += evv[i] * sigf(acc[mt][nt][i]);
      }
    }
    part *= pmv;
    if (part != 0.f) atomicAdd(&predl[t - tmin], part);
  }
  __syncthreads();
  const int tcnt = tmax - tmin + 1;
  if (tid < tcnt) {
    int t = tmin + tid;
    float pv = predl[tid];
    if (pv != 0.f)
      atomicAdd(&out[b * Sd + t + 1], pv * a.invZ[b * PB + t]);
  }
}

// ---------------------------------------------------------------------------
extern "C" void kernel_launch(void* const* d_in, const int* in_sizes, int n_in,
                              void* d_out, int out_size, void* d_ws, size_t ws_size,
                              hipStream_t stream)
{
  Args a;
  a.question = (const int*)d_in[0];
  a.response = (const int*)d_in[1];
  a.q_nb     = (const int*)d_in[3];
  a.s_nb     = (const int*)d_in[4];
  a.qs_sk    = (const int*)d_in[5];
  a.emb_q    = (const float*)d_in[6];
  a.emb_s    = (const float*)d_in[7];
  a.emb_r    = (const float*)d_in[8];
  a.W_ih     = (const float*)d_in[9];
  a.b_ih     = (const float*)d_in[10];
  a.b_hh     = (const float*)d_in[11];
  a.ft_W     = (const float*)d_in[12];
  a.ft_b     = (const float*)d_in[13];
  a.agg_W    = (const float*)d_in[14];
  a.agg_b    = (const float*)d_in[15];
  a.last_W   = (const float*)d_in[16];
  a.last_b   = (const float*)d_in[17];
  a.q_W      = (const float*)d_in[18];
  a.q_b      = (const float*)d_in[19];
  a.k_W      = (const float*)d_in[20];
  a.k_b      = (const float*)d_in[21];
  a.w_W      = (const float*)d_in[22];

  u16* wsu = (u16*)d_ws;
  const long NT = 1280000, ST = 64000, RT = (long)NR * Dd;
  a.tabA  = wsu;                 // NT (f2, later compact qt)
  a.tabB  = a.tabA + NT;         // NT (f0)
  a.tabs1 = a.tabB + NT;         // ST (f1)
  a.tabs2 = a.tabs1 + ST;        // ST (g1)
  a.states  = a.tabs2 + ST;      // RT
  a.embq_bf = a.states + RT;     // NT
  a.embs_bf = a.embq_bf + NT;    // ST
  a.wts     = a.embs_bf + ST;    // 5*16384
  a.wiht    = a.wts + 5 * 16384; // 65536
  float* fp = (float*)(a.wiht + 65536);
  a.a_state = fp;                       // 6368
  a.qw      = fp + 6368;                // 128
  a.kw      = fp + 6496;                // 128
  a.scal    = fp + 6624;                // 16
  a.er_part = fp + 6640;                // 1024
  a.ev      = fp + 7664;                // 32*208
  a.invZ    = a.ev + 32 * PB;
  a.pm      = a.invZ + 32 * PB;         // 32*208*5
  a.qid_map  = (int*)(a.pm + 32 * PB * 5);
  a.resp_map = a.qid_map + NR;
  a.flag     = a.resp_map + NR;         // 10000  (memset 0)
  a.cnt      = a.flag + NQd;            // 4      (memset 0)
  a.list     = a.cnt + 4;               // 10000
  a.newidx   = a.list + NQd;            // 10000

  float* out = (float*)d_out;

  hipMemsetAsync(a.flag, 0, (NQd + 4) * sizeof(int), stream);  // flag + cnt
  prep2<<<969, 256, 0, stream>>>(a, out);   // conv | f2+f0 | f1 all-in-one
  g1k<<<16, 256, 0, stream>>>(a);
  chain4<<<199, 256, 0, stream>>>(a);       // compact rows, early-exit on cnt
  gates_k<<<224, 256, 0, stream>>>(a);      // gates | pm filler
  bprep<<<Bd, 256, 0, stream>>>(a);
  gk_pred<<<dim3(7, 8, Bd), 256, 0, stream>>>(a, out);
}

// Round 12
// 180.442 us; speedup vs baseline: 1.1829x; 1.0329x over previous
//
#include <hip/hip_runtime.h>

typedef unsigned short u16;
typedef unsigned int   u32;

#define NQd 10000
#define NSd 500
#define Bd  32
#define Sd  200
#define Td  199   // S-1
#define Dd  128
#define NR  6368  // Bd*Td
#define PB  208   // padded per-batch stride for pm

typedef __attribute__((ext_vector_type(8))) short bf16x8;
typedef __attribute__((ext_vector_type(4))) float f32x4;

__device__ __forceinline__ float sigf(float x) {
  return __builtin_amdgcn_rcpf(1.f + __expf(-x));
}
__device__ __forceinline__ float tanh_f(float x) {
  float ax = fminf(fabsf(x), 15.f);
  float e = __expf(2.f * ax);
  float r = 1.f - 2.f * __builtin_amdgcn_rcpf(e + 1.f);
  return copysignf(r, x);
}
__device__ __forceinline__ float bf2f(u16 u) { return __uint_as_float(((u32)u) << 16); }
__device__ __forceinline__ u16 f2bf(float f) {            // round-to-nearest-even
  u32 b = __float_as_uint(f);
  b += 0x7FFFu + ((b >> 16) & 1u);
  return (u16)(b >> 16);
}
__device__ __forceinline__ float rnd(float x) { return bf2f(f2bf(x)); }  // bf16 round
__device__ __forceinline__ void unp2(u32 u, float &a, float &b) {
  a = __uint_as_float(u << 16);
  b = __uint_as_float(u & 0xffff0000u);
}
__device__ __forceinline__ void unpack16(uint4 a0, uint4 a1, float* f) {
  unp2(a0.x, f[0], f[1]);  unp2(a0.y, f[2], f[3]);
  unp2(a0.z, f[4], f[5]);  unp2(a0.w, f[6], f[7]);
  unp2(a1.x, f[8], f[9]);  unp2(a1.y, f[10], f[11]);
  unp2(a1.z, f[12], f[13]); unp2(a1.w, f[14], f[15]);
}

struct Args {
  const int *question, *response, *q_nb, *s_nb, *qs_sk;
  const float *emb_q, *emb_s, *emb_r;
  const float *W_ih, *b_ih, *b_hh, *ft_W, *ft_b, *agg_W, *agg_b, *last_W, *last_b;
  const float *q_W, *q_b, *k_W, *k_b, *w_W;
  u16 *tabA, *tabB, *tabs1, *tabs2, *states, *embq_bf, *embs_bf, *wts, *wiht;
  float *a_state, *qw, *kw, *scal, *er_part, *pm;
  int *qid_map, *resp_map, *flag, *cnt, *list, *newidx;
};

// W fragment held in registers: 2 n-tiles x 4 k-chunks x bf16x8 = 16 VGPR
struct WF { bf16x8 v[2][4]; };

__device__ __forceinline__ void load_WF(const u16* Wt, int l15, int quad, int cw, WF& w)
{
#pragma unroll
  for (int nt = 0; nt < 2; ++nt)
#pragma unroll
    for (int kc = 0; kc < 4; ++kc)
      w.v[nt][kc] = *(const bf16x8*)&Wt[(long)(cw + nt * 16 + l15) * 128 + kc * 32 + quad * 8];
}

// same fragment loaded straight from f32 W[k][col] with inline bf16 rounding
__device__ __forceinline__ void load_WF_f32(const float* W, int l15, int quad, int cw, WF& w)
{
#pragma unroll
  for (int nt = 0; nt < 2; ++nt) {
    int col = cw + nt * 16 + l15;
#pragma unroll
    for (int kc = 0; kc < 4; ++kc) {
      int kb = kc * 32 + quad * 8;
      bf16x8 t;
#pragma unroll
      for (int j = 0; j < 8; ++j) t[j] = (short)f2bf(W[(long)(kb + j) * 128 + col]);
      w.v[nt][kc] = t;
    }
  }
}

__device__ __forceinline__ void zero_acc(f32x4 acc[2][2]) {
#pragma unroll
  for (int x = 0; x < 2; ++x)
#pragma unroll
    for (int y = 0; y < 2; ++y) acc[x][y] = (f32x4){0.f, 0.f, 0.f, 0.f};
}

// MFMA with A from LDS, B from register fragments
__device__ __forceinline__ void mfma_WF(const u16* Al, const WF& w,
                                        int l15, int quad, f32x4 acc[2][2])
{
#pragma unroll
  for (int kc = 0; kc < 4; ++kc) {
    const int ko = kc * 32 + quad * 8;
    bf16x8 a0 = *(const bf16x8*)&Al[l15 * 136 + ko];
    bf16x8 a1 = *(const bf16x8*)&Al[(16 + l15) * 136 + ko];
    acc[0][0] = __builtin_amdgcn_mfma_f32_16x16x32_bf16(a0, w.v[0][kc], acc[0][0], 0, 0, 0);
    acc[0][1] = __builtin_amdgcn_mfma_f32_16x16x32_bf16(a0, w.v[1][kc], acc[0][1], 0, 0, 0);
    acc[1][0] = __builtin_amdgcn_mfma_f32_16x16x32_bf16(a1, w.v[0][kc], acc[1][0], 0, 0, 0);
    acc[1][1] = __builtin_amdgcn_mfma_f32_16x16x32_bf16(a1, w.v[1][kc], acc[1][1], 0, 0, 0);
  }
}

// stage one 32-row gathered input tile into Al (bf16). rowmap: optional compaction.
__device__ __forceinline__ void stage_A(const u16* Atab, const u16* Btab,
                                        const int* nbr, int K, const int* rowmap,
                                        int tile0, int rows, int tid, u16* Al)
{
  int r = tid & 31, k0 = (tid >> 5) * 16;
  int row = tile0 + r; if (row >= rows) row = rows - 1;
  int arow = rowmap ? rowmap[row] : row;
  const u16* ap = Atab + (long)arow * 128 + k0;
  if (K == 0) {
    *(uint4*)&Al[r * 136 + k0]     = *(const uint4*)ap;
    *(uint4*)&Al[r * 136 + k0 + 8] = *(const uint4*)(ap + 8);
  } else {
    float f[16];
    unpack16(*(const uint4*)ap, *(const uint4*)(ap + 8), f);
    float s[16];
#pragma unroll
    for (int q = 0; q < 16; ++q) s[q] = 0.f;
    for (int l = 0; l < K; ++l) {
      int id = nbr[(long)arow * K + l];
      const u16* np = Btab + (long)id * 128 + k0;
      float g[16];
      unpack16(*(const uint4*)np, *(const uint4*)(np + 8), g);
#pragma unroll
      for (int q = 0; q < 16; ++q) s[q] += g[q];
    }
    float inv = 1.f / (float)K;
#pragma unroll
    for (int q = 0; q < 16; ++q) f[q] += s[q] * inv;
    u32 p[8];
#pragma unroll
    for (int q = 0; q < 8; ++q)
      p[q] = (u32)f2bf(f[2 * q]) | ((u32)f2bf(f[2 * q + 1]) << 16);
    *(uint4*)&Al[r * 136 + k0]     = make_uint4(p[0], p[1], p[2], p[3]);
    *(uint4*)&Al[r * 136 + k0 + 8] = make_uint4(p[4], p[5], p[6], p[7]);
  }
}

// gather from RAW f32 tables with inline bf16 rounding
__device__ __forceinline__ void ld16_rnd(const float* p, float* f)
{
#pragma unroll
  for (int q4 = 0; q4 < 4; ++q4) {
    float4 v = *(const float4*)(p + q4 * 4);
    f[q4 * 4 + 0] = rnd(v.x); f[q4 * 4 + 1] = rnd(v.y);
    f[q4 * 4 + 2] = rnd(v.z); f[q4 * 4 + 3] = rnd(v.w);
  }
}

__device__ __forceinline__ void stage_A_f32(const float* Atab, const float* Btab,
                                            const int* nbr, int K,
                                            int tile0, int rows, int tid, u16* Al)
{
  int r = tid & 31, k0 = (tid >> 5) * 16;
  int row = tile0 + r; if (row >= rows) row = rows - 1;
  float f[16];
  ld16_rnd(Atab + (long)row * 128 + k0, f);
  float s[16];
#pragma unroll
  for (int q = 0; q < 16; ++q) s[q] = 0.f;
  for (int l = 0; l < K; ++l) {
    int id = nbr[(long)row * K + l];
    float g[16];
    ld16_rnd(Btab + (long)id * 128 + k0, g);
#pragma unroll
    for (int q = 0; q < 16; ++q) s[q] += g[q];
  }
  float inv = 1.f / (float)K;
#pragma unroll
  for (int q = 0; q < 16; ++q) f[q] += s[q] * inv;
  u32 p[8];
#pragma unroll
  for (int q = 0; q < 8; ++q)
    p[q] = (u32)f2bf(f[2 * q]) | ((u32)f2bf(f[2 * q + 1]) << 16);
  *(uint4*)&Al[r * 136 + k0]     = make_uint4(p[0], p[1], p[2], p[3]);
  *(uint4*)&Al[r * 136 + k0 + 8] = make_uint4(p[4], p[5], p[6], p[7]);
}

// Al := bf16(Al + mean_{l<4} Btab[nbr[arow*4+l]])
__device__ __forceinline__ void update_A(const u16* Btab, const int* nbr,
                                         const int* rowmap, int tile0, int rows,
                                         int tid, u16* Al)
{
  int r = tid & 31, k0 = (tid >> 5) * 16;
  int row = tile0 + r; if (row >= rows) row = rows - 1;
  int arow = rowmap ? rowmap[row] : row;
  float f[16];
  unpack16(*(const uint4*)&Al[r * 136 + k0], *(const uint4*)&Al[r * 136 + k0 + 8], f);
  float s[16];
#pragma unroll
  for (int q = 0; q < 16; ++q) s[q] = 0.f;
#pragma unroll
  for (int l = 0; l < 4; ++l) {
    int id = nbr[(long)arow * 4 + l];
    const u16* np = Btab + (long)id * 128 + k0;
    float g[16];
    unpack16(*(const uint4*)np, *(const uint4*)(np + 8), g);
#pragma unroll
    for (int q = 0; q < 16; ++q) s[q] += g[q];
  }
#pragma unroll
  for (int q = 0; q < 16; ++q) f[q] += s[q] * 0.25f;
  u32 p[8];
#pragma unroll
  for (int q = 0; q < 8; ++q)
    p[q] = (u32)f2bf(f[2 * q]) | ((u32)f2bf(f[2 * q + 1]) << 16);
  *(uint4*)&Al[r * 136 + k0]     = make_uint4(p[0], p[1], p[2], p[3]);
  *(uint4*)&Al[r * 136 + k0 + 8] = make_uint4(p[4], p[5], p[6], p[7]);
}

// epilogue: tanh -> global table
__device__ __forceinline__ void epi_tanh_global(const f32x4 acc[2][2], const float* cbias,
                                                u16* out, int rows, int tile0,
                                                int l15, int quad, int cw)
{
#pragma unroll
  for (int nt = 0; nt < 2; ++nt) {
    int col = cw + nt * 16 + l15;
    float cb = cbias[col];
#pragma unroll
    for (int mt = 0; mt < 2; ++mt) {
      int rbase = tile0 + mt * 16 + quad * 4;
#pragma unroll
      for (int i = 0; i < 4; ++i) {
        int row = rbase + i;
        if (row >= rows) continue;
        out[(long)row * 128 + col] = f2bf(tanh_f(acc[mt][nt][i] + cb));
      }
    }
  }
}

// epilogue: tanh -> LDS Al
__device__ __forceinline__ void epi_tanh_lds(const f32x4 acc[2][2], const float* cbias,
                                             u16* Al, int l15, int quad, int cw)
{
#pragma unroll
  for (int nt = 0; nt < 2; ++nt) {
    int col = cw + nt * 16 + l15;
    float cb = cbias[col];
#pragma unroll
    for (int mt = 0; mt < 2; ++mt)
#pragma unroll
      for (int i = 0; i < 4; ++i) {
        int rL = mt * 16 + quad * 4 + i;
        Al[rL * 136 + col] = f2bf(tanh_f(acc[mt][nt][i] + cb));
      }
  }
}

// ---------------------------------------------------------------------------
// prep2: blocks 0..312: f2+f0; 313..328: f1; 329..968: conversions, maps,
// used-qid list, small dots, zero d_out (grid-stride)
// ---------------------------------------------------------------------------
__global__ __launch_bounds__(256) void prep2(Args a, float* __restrict__ out)
{
  __shared__ __align__(16) u16 Al[32 * 136];
  const int i = blockIdx.x, tid = threadIdx.x;
  const int lane = tid & 63, wv = tid >> 6;
  const int l15 = lane & 15, quad = lane >> 4, cw = wv * 32;

  if (i < 313) {           // f2 + f0 from one gather
    const int tile0 = i * 32;
    WF w2, w0;
    load_WF_f32(a.agg_W + 2 * 16384, l15, quad, cw, w2);
    load_WF_f32(a.agg_W, l15, quad, cw, w0);
    stage_A_f32(a.emb_q, a.emb_s, a.q_nb, 4, tile0, NQd, tid, Al);
    __syncthreads();
    f32x4 acc[2][2];
    zero_acc(acc);
    mfma_WF(Al, w2, l15, quad, acc);
    epi_tanh_global(acc, a.agg_b + 256, a.tabA, NQd, tile0, l15, quad, cw);  // f2
    zero_acc(acc);
    mfma_WF(Al, w0, l15, quad, acc);
    epi_tanh_global(acc, a.agg_b, a.tabB, NQd, tile0, l15, quad, cw);        // f0
    return;
  }
  if (i < 329) {           // f1
    const int tile0 = (i - 313) * 32;
    WF w1;
    load_WF_f32(a.agg_W + 16384, l15, quad, cw, w1);
    stage_A_f32(a.emb_s, a.emb_q, a.s_nb, 10, tile0, NSd, tid, Al);
    __syncthreads();
    f32x4 acc[2][2];
    zero_acc(acc);
    mfma_WF(Al, w1, l15, quad, acc);
    epi_tanh_global(acc, a.agg_b + 128, a.tabs1, NSd, tile0, l15, quad, cw);
    return;
  }

  // conversion / scalar region
  const int T = 640 * 256;
  for (int j = (i - 329) * 256 + tid; j < 497506; j += T) {
    if (j < 320000) {
      float4 v = *(const float4*)&a.emb_q[(long)j * 4];
      ((uint2*)a.embq_bf)[j] = make_uint2(
          (u32)f2bf(v.x) | ((u32)f2bf(v.y) << 16),
          (u32)f2bf(v.z) | ((u32)f2bf(v.w) << 16));
    } else if (j < 336000) {
      int c = j - 320000;
      float4 v = *(const float4*)&a.emb_s[(long)c * 4];
      ((uint2*)a.embs_bf)[c] = make_uint2(
          (u32)f2bf(v.x) | ((u32)f2bf(v.y) << 16),
          (u32)f2bf(v.z) | ((u32)f2bf(v.w) << 16));
    } else if (j < 417920) {
      int e = j - 336000;
      int seg = e >> 14, r = e & 16383;
      int col = r >> 7, k = r & 127;
      const float* src = (seg < 3) ? (a.agg_W + seg * 16384)
                                   : (seg == 3 ? a.last_W : a.ft_W);
      a.wts[e] = f2bf(src[k * 128 + col]);
    } else if (j < 483456) {
      int e = j - 417920;
      int col = e >> 7, k = e & 127;
      a.wiht[e] = f2bf(a.W_ih[k * 512 + col]);
    } else if (j < 489824) {
      int jj = j - 483456;
      int b = jj / Td, s = jj - b * Td;
      int qid = a.question[b * Sd + s];
      a.qid_map[jj]  = qid;
      a.resp_map[jj] = a.response[b * Sd + s];
      if (atomicExch(&a.flag[qid], 1) == 0) {     // first toucher appends
        int idx = atomicAdd(a.cnt, 1);
        a.list[idx] = qid;
        a.newidx[qid] = idx;
      }
    } else if (j < 491106) {
      int s = j - 489824;
      if (s < 128) {
        float acc = 0;
        for (int e = 0; e < 128; ++e) acc += a.q_W[s * 128 + e] * a.w_W[e];
        a.qw[s] = acc;
      } else if (s < 256) {
        int d = s - 128; float acc = 0;
        for (int e = 0; e < 128; ++e) acc += a.k_W[d * 128 + e] * a.w_W[128 + e];
        a.kw[d] = acc;
      } else if (s == 256) {
        float acc = 0;
        for (int e = 0; e < 128; ++e) acc += a.q_b[e] * a.w_W[e];
        a.scal[0] = acc;
      } else if (s == 257) {
        float acc = 0;
        for (int e = 0; e < 128; ++e) acc += a.k_b[e] * a.w_W[128 + e];
        a.scal[1] = acc;
      } else {
        int e2 = s - 258, rr = e2 >> 9, col = e2 & 511;
        float acc = a.b_ih[col] + a.b_hh[col];
        for (int d = 0; d < 128; ++d) acc += a.emb_r[rr * Dd + d] * a.W_ih[(128 + d) * 512 + col];
        a.er_part[rr * 512 + col] = acc;
      }
    } else {
      out[j - 491106] = 0.f;     // zero d_out (gk_pred accumulates into it)
    }
  }
}

// g1k: g1 = tanh((f1 + mean f2[s_nb]) @ W1 + b1), 16 blocks
__global__ __launch_bounds__(256) void g1k(Args a)
{
  __shared__ __align__(16) u16 Al[32 * 136];
  const int tid = threadIdx.x, tile0 = blockIdx.x * 32;
  const int lane = tid & 63, wv = tid >> 6;
  const int l15 = lane & 15, quad = lane >> 4, cw = wv * 32;
  WF w1; load_WF(a.wts + 16384, l15, quad, cw, w1);
  stage_A(a.tabs1, a.tabA, a.s_nb, 10, nullptr, tile0, NSd, tid, Al);
  __syncthreads();
  f32x4 acc[2][2];
  zero_acc(acc);
  mfma_WF(Al, w1, l15, quad, acc);
  epi_tanh_global(acc, a.agg_b + 128, a.tabs2, NSd, tile0, l15, quad, cw);
}

// chain4: g0 -> h0 -> agg -> qt fused in-block, COMPACT rows (used qids only)
__global__ __launch_bounds__(256) void chain4(Args a)
{
  const int cnt = *a.cnt;
  const int tile0 = blockIdx.x * 32;
  if (tile0 >= cnt) return;
  __shared__ __align__(16) u16 Al[32 * 136];
  const int tid = threadIdx.x;
  const int lane = tid & 63, wv = tid >> 6;
  const int l15 = lane & 15, quad = lane >> 4, cw = wv * 32;
  WF w0, w3, w4;
  load_WF(a.wts, l15, quad, cw, w0);
  load_WF(a.wts + 3 * 16384, l15, quad, cw, w3);
  load_WF(a.wts + 4 * 16384, l15, quad, cw, w4);
  f32x4 acc[2][2];

  // phase 0: g0 = tanh((f0 + mean f1[q_nb]) @ W0 + b0)
  stage_A(a.tabB, a.tabs1, a.q_nb, 4, a.list, tile0, cnt, tid, Al);
  __syncthreads();
  zero_acc(acc);
  mfma_WF(Al, w0, l15, quad, acc);
  __syncthreads();
  epi_tanh_lds(acc, a.agg_b, Al, l15, quad, cw);       // Al = g0
  __syncthreads();
  // phase 1: h0 = tanh((g0 + mean g1[q_nb]) @ W0 + b0)
  update_A(a.tabs2, a.q_nb, a.list, tile0, cnt, tid, Al);
  __syncthreads();
  zero_acc(acc);
  mfma_WF(Al, w0, l15, quad, acc);
  __syncthreads();
  epi_tanh_lds(acc, a.agg_b, Al, l15, quad, cw);       // Al = h0
  __syncthreads();
  // phase 2: agg = tanh(h0 @ last_W + last_b)
  zero_acc(acc);
  mfma_WF(Al, w3, l15, quad, acc);
  __syncthreads();
  epi_tanh_lds(acc, a.last_b, Al, l15, quad, cw);      // Al = agg
  __syncthreads();
  // phase 3: qt = relu(agg @ ft_W + ft_b) -> compact tabA
  zero_acc(acc);
  mfma_WF(Al, w4, l15, quad, acc);
#pragma unroll
  for (int nt = 0; nt < 2; ++nt) {
    int col = cw + nt * 16 + l15;
    float cb = a.ft_b[col];
#pragma unroll
    for (int mt = 0; mt < 2; ++mt) {
      int rbase = tile0 + mt * 16 + quad * 4;
#pragma unroll
      for (int i = 0; i < 4; ++i) {
        int row = rbase + i;
        if (row >= cnt) continue;
        a.tabA[(long)row * 128 + col] = f2bf(fmaxf(acc[mt][nt][i] + cb, 0.f));
      }
    }
  }
}

// gates (i,g,o) + LSTM + a_state (blocks 0..198) | pm table (blocks 199..223)
__global__ __launch_bounds__(256) void gates_k(Args a)
{
  __shared__ __align__(16) u16 Al[32 * 136];
  __shared__ float hb[32 * 132];
  const int tid = threadIdx.x;
  const int lane = tid & 63, wv = tid >> 6;
  const int l15 = lane & 15, quad = lane >> 4, cw = wv * 32;

  if (blockIdx.x >= 199) {   // pm: one (b,t) per thread
    int item = (blockIdx.x - 199) * 256 + tid;
    if (item >= NR) return;
    int b = item / Td, t = item - b * Td;
    int qn = a.question[b * Sd + t + 1];
    float am[5];
#pragma unroll
    for (int m = 0; m < 5; ++m) {
      const u16* src = (m == 0) ? a.embq_bf + (long)qn * 128
                                : a.embs_bf + (long)a.qs_sk[qn * 4 + (m - 1)] * 128;
      float s = 0.f;
      for (int k = 0; k < 128; k += 8) {
        uint4 u = *(const uint4*)&src[k];
        float f[8];
        unp2(u.x, f[0], f[1]); unp2(u.y, f[2], f[3]);
        unp2(u.z, f[4], f[5]); unp2(u.w, f[6], f[7]);
#pragma unroll
        for (int q = 0; q < 8; ++q) s = fmaf(f[q], a.kw[k + q], s);
      }
      am[m] = s + a.scal[1];
    }
    float mx = am[0];
#pragma unroll
    for (int m = 1; m < 5; ++m) mx = fmaxf(mx, am[m]);
    float ex[5], z = 0.f;
#pragma unroll
    for (int m = 0; m < 5; ++m) { ex[m] = __expf(am[m] - mx); z += ex[m]; }
    float iz = __builtin_amdgcn_rcpf(z);
#pragma unroll
    for (int m = 0; m < 5; ++m) a.pm[((long)b * PB + t) * 5 + m] = ex[m] * iz;
    return;
  }

  const int tile0 = blockIdx.x * 32;
  WF wg0, wg1, wg2;
  load_WF(a.wiht, l15, quad, cw, wg0);                     // i-gate
  load_WF(a.wiht + (long)256 * 128, l15, quad, cw, wg1);   // g-gate
  load_WF(a.wiht + (long)384 * 128, l15, quad, cw, wg2);   // o-gate
  {
    int r = tid & 31, k0 = (tid >> 5) * 16;
    int row = tile0 + r;
    int arow = a.newidx[a.qid_map[row]];                   // compact qt row
    const u16* ap = a.tabA + (long)arow * 128 + k0;
    *(uint4*)&Al[r * 136 + k0]     = *(const uint4*)ap;
    *(uint4*)&Al[r * 136 + k0 + 8] = *(const uint4*)(ap + 8);
  }
  __syncthreads();
  f32x4 acc[3][2][2];
  zero_acc(acc[0]); mfma_WF(Al, wg0, l15, quad, acc[0]);
  zero_acc(acc[1]); mfma_WF(Al, wg1, l15, quad, acc[1]);
  zero_acc(acc[2]); mfma_WF(Al, wg2, l15, quad, acc[2]);
#pragma unroll
  for (int nt = 0; nt < 2; ++nt) {
    int colL = cw + nt * 16 + l15;
#pragma unroll
    for (int mt = 0; mt < 2; ++mt) {
#pragma unroll
      for (int i = 0; i < 4; ++i) {
        int rL = mt * 16 + quad * 4 + i;
        int row = tile0 + rL;
        const float* rb = a.er_part + (long)a.resp_map[row] * 512;
        float iv = acc[0][mt][nt][i] + rb[colL];
        float gv = acc[1][mt][nt][i] + rb[256 + colL];
        float ov = acc[2][mt][nt][i] + rb[384 + colL];
        float c = sigf(iv) * tanh_f(gv);
        float h = sigf(ov) * tanh_f(c);
        a.states[(long)row * 128 + colL] = f2bf(h);
        hb[rL * 132 + colL] = h;
      }
    }
  }
  __syncthreads();
#pragma unroll
  for (int rr = 0; rr < 8; ++rr) {
    int rL = wv * 8 + rr;
    float p = hb[rL * 132 + lane] * a.qw[lane] + hb[rL * 132 + 64 + lane] * a.qw[64 + lane];
#pragma unroll
    for (int off = 32; off > 0; off >>= 1) p += __shfl_xor(p, off);
    if (lane == 0) a.a_state[tile0 + rL] = p + a.scal[0];
  }
}

// ---------------------------------------------------------------------------
// gk_pred: chunked (cy, nx-range) work units; Ql staged ONCE per chunk and
// reused across n-tiles; per-batch softmax (ev / prefix Z) computed in-block
// (bit-identical op order to the old bprep). Accumulates into out[b,t+1].
// Grid: (14 chunks, 32 b).
// ---------------------------------------------------------------------------
__global__ __launch_bounds__(256) void gk_pred(Args a, float* __restrict__ out)
{
  static const int cys[14]   = {0,1,2,3,3,4,4,5,5,6,6,7,7,7};
  static const int nx0s[14]  = {0,0,0,0,3,0,3,0,3,0,3,0,3,6};
  static const int ncnts[14] = {1,2,3,3,1,3,1,3,2,3,3,3,3,1};
  const int chunk = blockIdx.x, b = blockIdx.y;
  const int cy = cys[chunk], nx0 = nx0s[chunk], ncnt = ncnts[chunk];
  const int c0 = cy * 128;
  int c_hi = c0 + 127; if (c_hi > 994) c_hi = 994;
  const int tmax = c_hi / 5, tmin = c0 / 5;

  __shared__ __align__(16) u16 smem[21760];
  __shared__ float predl[32];
  __shared__ float evl[256];   // ev values
  __shared__ float scl[256];   // max-reduce, then inclusive scan
  u16* Ql = smem;
  u16* Sl = smem + 17408;
  const int tid = threadIdx.x;

  // per-block softmax prep (identical op order to old bprep)
  float v = (tid < Td) ? a.a_state[b * Td + tid] : -1e30f;
  scl[tid] = v; __syncthreads();
  for (int s = 128; s > 0; s >>= 1) { if (tid < s) scl[tid] = fmaxf(scl[tid], scl[tid + s]); __syncthreads(); }
  float gmax = scl[0]; __syncthreads();
  float e = (tid < Td) ? __expf(v - gmax) : 0.f;
  evl[tid] = e;
  scl[tid] = e;
  if (tid < 32) predl[tid] = 0.f;
  __syncthreads();
  for (int off = 1; off < 256; off <<= 1) {
    float add = (tid >= off) ? scl[tid - off] : 0.f;
    __syncthreads();
    scl[tid] += add;
    __syncthreads();
  }

  // stage Ql once for this (b, cy)
  {
    int j = tid >> 1, k0 = (tid & 1) * 64;
    int col = c0 + j;
    uint4* dst = (uint4*)&Ql[j * 136 + k0];
    if (col < 995) {
      int t = col / 5, m = col - t * 5;
      int qn = a.question[b * Sd + t + 1];
      const u16* src = (m == 0) ? a.embq_bf + (long)qn * 128
                                : a.embs_bf + (long)a.qs_sk[qn * 4 + (m - 1)] * 128;
      src += k0;
#pragma unroll
      for (int q = 0; q < 8; ++q) dst[q] = ((const uint4*)src)[q];
    } else {
      uint4 z = make_uint4(0, 0, 0, 0);
#pragma unroll
      for (int q = 0; q < 8; ++q) dst[q] = z;
    }
  }

  const int lane = tid & 63, wv = tid >> 6;
  const int l15 = lane & 15, quad = lane >> 4, cw = wv * 32;

  for (int xi = 0; xi < ncnt; ++xi) {
    const int n0 = (nx0 + xi) * 32;
    __syncthreads();   // Ql/Sl safe to (re)use; predl from prior iter drained
    {
      int r = tid & 31, k0 = (tid >> 5) * 16;
      int n = n0 + r; if (n > 198) n = 198;
      const u16* sp = a.states + ((long)b * Td + n) * 128 + k0;
      *(uint4*)&Sl[r * 136 + k0]     = *(const uint4*)sp;
      *(uint4*)&Sl[r * 136 + k0 + 8] = *(const uint4*)(sp + 8);
    }
    __syncthreads();
    f32x4 acc[2][2];
    zero_acc(acc);
#pragma unroll
    for (int kc = 0; kc < 4; ++kc) {
      const int ko = kc * 32 + quad * 8;
      bf16x8 af[2], bfv[2];
      af[0]  = *(const bf16x8*)&Sl[l15 * 136 + ko];
      af[1]  = *(const bf16x8*)&Sl[(16 + l15) * 136 + ko];
      bfv[0] = *(const bf16x8*)&Ql[(cw + l15) * 136 + ko];
      bfv[1] = *(const bf16x8*)&Ql[(cw + 16 + l15) * 136 + ko];
#pragma unroll
      for (int mt = 0; mt < 2; ++mt)
#pragma unroll
        for (int nt = 0; nt < 2; ++nt)
          acc[mt][nt] = __builtin_amdgcn_mfma_f32_16x16x32_bf16(af[mt], bfv[nt], acc[mt][nt], 0, 0, 0);
    }

#pragma unroll
    for (int nt = 0; nt < 2; ++nt) {
      int col = c0 + cw + nt * 16 + l15;
      if (col >= 995) continue;
      int t = col / 5, m = col - t * 5;
      float pmv = a.pm[((long)b * PB + t) * 5 + m];
      float part = 0.f;
#pragma unroll
      for (int mt = 0; mt < 2; ++mt) {
        int nb = n0 + mt * 16 + quad * 4;
        if (nb > t) continue;
#pragma unroll
        for (int i = 0; i < 4; ++i) {
          int n = nb + i;
          if (n > t || n > 198) continue;
          part += evl[n] * sigf(acc[mt][nt][i]);
        }
      }
      part *= pmv;
      if (part != 0.f) atomicAdd(&predl[t - tmin], part);
    }
  }
  __syncthreads();
  const int tcnt = tmax - tmin + 1;
  if (tid < tcnt) {
    int t = tmin + tid;
    float pv = predl[tid];
    if (pv != 0.f)
      atomicAdd(&out[b * Sd + t + 1], pv * (1.f / scl[t]));
  }
}

// ---------------------------------------------------------------------------
extern "C" void kernel_launch(void* const* d_in, const int* in_sizes, int n_in,
                              void* d_out, int out_size, void* d_ws, size_t ws_size,
                              hipStream_t stream)
{
  Args a;
  a.question = (const int*)d_in[0];
  a.response = (const int*)d_in[1];
  a.q_nb     = (const int*)d_in[3];
  a.s_nb     = (const int*)d_in[4];
  a.qs_sk    = (const int*)d_in[5];
  a.emb_q    = (const float*)d_in[6];
  a.emb_s    = (const float*)d_in[7];
  a.emb_r    = (const float*)d_in[8];
  a.W_ih     = (const float*)d_in[9];
  a.b_ih     = (const float*)d_in[10];
  a.b_hh     = (const float*)d_in[11];
  a.ft_W     = (const float*)d_in[12];
  a.ft_b     = (const float*)d_in[13];
  a.agg_W    = (const float*)d_in[14];
  a.agg_b    = (const float*)d_in[15];
  a.last_W   = (const float*)d_in[16];
  a.last_b   = (const float*)d_in[17];
  a.q_W      = (const float*)d_in[18];
  a.q_b      = (const float*)d_in[19];
  a.k_W      = (const float*)d_in[20];
  a.k_b      = (const float*)d_in[21];
  a.w_W      = (const float*)d_in[22];

  u16* wsu = (u16*)d_ws;
  const long NT = 1280000, ST = 64000, RT = (long)NR * Dd;
  a.tabA  = wsu;                 // NT (f2, later compact qt)
  a.tabB  = a.tabA + NT;         // NT (f0)
  a.tabs1 = a.tabB + NT;         // ST (f1)
  a.tabs2 = a.tabs1 + ST;        // ST (g1)
  a.states  = a.tabs2 + ST;      // RT
  a.embq_bf = a.states + RT;     // NT
  a.embs_bf = a.embq_bf + NT;    // ST
  a.wts     = a.embs_bf + ST;    // 5*16384
  a.wiht    = a.wts + 5 * 16384; // 65536
  float* fp = (float*)(a.wiht + 65536);
  a.a_state = fp;                       // 6368
  a.qw      = fp + 6368;                // 128
  a.kw      = fp + 6496;                // 128
  a.scal    = fp + 6624;                // 16
  a.er_part = fp + 6640;                // 1024
  a.pm      = fp + 7664;                // 32*208*5
  a.qid_map  = (int*)(a.pm + 32 * PB * 5);
  a.resp_map = a.qid_map + NR;
  a.flag     = a.resp_map + NR;         // 10000  (memset 0)
  a.cnt      = a.flag + NQd;            // 4      (memset 0)
  a.list     = a.cnt + 4;               // 10000
  a.newidx   = a.list + NQd;            // 10000

  float* out = (float*)d_out;

  hipMemsetAsync(a.flag, 0, (NQd + 4) * sizeof(int), stream);  // flag + cnt
  prep2<<<969, 256, 0, stream>>>(a, out);   // conv | f2+f0 | f1 all-in-one
  g1k<<<16, 256, 0, stream>>>(a);
  chain4<<<199, 256, 0, stream>>>(a);       // compact rows, early-exit on cnt
  gates_k<<<224, 256, 0, stream>>>(a);      // gates | pm filler
  gk_pred<<<dim3(14, Bd), 256, 0, stream>>>(a, out);
}

// Round 13
// 167.786 us; speedup vs baseline: 1.2721x; 1.0754x over previous
//
#include <hip/hip_runtime.h>

typedef unsigned short u16;
typedef unsigned int   u32;

#define NQd 10000
#define NSd 500
#define Bd  32
#define Sd  200
#define Td  199   // S-1
#define Dd  128
#define NR  6368  // Bd*Td
#define PB  208   // padded per-batch stride for pm

typedef __attribute__((ext_vector_type(8))) short bf16x8;
typedef __attribute__((ext_vector_type(4))) float f32x4;

__device__ __forceinline__ float sigf(float x) {
  return __builtin_amdgcn_rcpf(1.f + __expf(-x));
}
__device__ __forceinline__ float tanh_f(float x) {
  float ax = fminf(fabsf(x), 15.f);
  float e = __expf(2.f * ax);
  float r = 1.f - 2.f * __builtin_amdgcn_rcpf(e + 1.f);
  return copysignf(r, x);
}
__device__ __forceinline__ float bf2f(u16 u) { return __uint_as_float(((u32)u) << 16); }
__device__ __forceinline__ u16 f2bf(float f) {            // round-to-nearest-even
  u32 b = __float_as_uint(f);
  b += 0x7FFFu + ((b >> 16) & 1u);
  return (u16)(b >> 16);
}
__device__ __forceinline__ float rnd(float x) { return bf2f(f2bf(x)); }  // bf16 round
__device__ __forceinline__ void unp2(u32 u, float &a, float &b) {
  a = __uint_as_float(u << 16);
  b = __uint_as_float(u & 0xffff0000u);
}
__device__ __forceinline__ void unpack16(uint4 a0, uint4 a1, float* f) {
  unp2(a0.x, f[0], f[1]);  unp2(a0.y, f[2], f[3]);
  unp2(a0.z, f[4], f[5]);  unp2(a0.w, f[6], f[7]);
  unp2(a1.x, f[8], f[9]);  unp2(a1.y, f[10], f[11]);
  unp2(a1.z, f[12], f[13]); unp2(a1.w, f[14], f[15]);
}

struct Args {
  const int *question, *response, *q_nb, *s_nb, *qs_sk;
  const float *emb_q, *emb_s, *emb_r;
  const float *W_ih, *b_ih, *b_hh, *ft_W, *ft_b, *agg_W, *agg_b, *last_W, *last_b;
  const float *q_W, *q_b, *k_W, *k_b, *w_W;
  u16 *tabA, *tabB, *tabs1, *tabs2, *states, *embq_bf, *embs_bf, *wts, *wiht;
  float *a_state, *qw, *kw, *scal, *er_part, *pm;
  int *qid_map, *resp_map, *flag, *cnt, *gflag, *list, *newidx;
};

// W fragment held in registers: 2 n-tiles x 4 k-chunks x bf16x8 = 16 VGPR
struct WF { bf16x8 v[2][4]; };

__device__ __forceinline__ void load_WF(const u16* Wt, int l15, int quad, int cw, WF& w)
{
#pragma unroll
  for (int nt = 0; nt < 2; ++nt)
#pragma unroll
    for (int kc = 0; kc < 4; ++kc)
      w.v[nt][kc] = *(const bf16x8*)&Wt[(long)(cw + nt * 16 + l15) * 128 + kc * 32 + quad * 8];
}

// same fragment loaded straight from f32 W[k][col] with inline bf16 rounding
__device__ __forceinline__ void load_WF_f32(const float* W, int l15, int quad, int cw, WF& w)
{
#pragma unroll
  for (int nt = 0; nt < 2; ++nt) {
    int col = cw + nt * 16 + l15;
#pragma unroll
    for (int kc = 0; kc < 4; ++kc) {
      int kb = kc * 32 + quad * 8;
      bf16x8 t;
#pragma unroll
      for (int j = 0; j < 8; ++j) t[j] = (short)f2bf(W[(long)(kb + j) * 128 + col]);
      w.v[nt][kc] = t;
    }
  }
}

__device__ __forceinline__ void zero_acc(f32x4 acc[2][2]) {
#pragma unroll
  for (int x = 0; x < 2; ++x)
#pragma unroll
    for (int y = 0; y < 2; ++y) acc[x][y] = (f32x4){0.f, 0.f, 0.f, 0.f};
}

// MFMA with A from LDS, B from register fragments
__device__ __forceinline__ void mfma_WF(const u16* Al, const WF& w,
                                        int l15, int quad, f32x4 acc[2][2])
{
#pragma unroll
  for (int kc = 0; kc < 4; ++kc) {
    const int ko = kc * 32 + quad * 8;
    bf16x8 a0 = *(const bf16x8*)&Al[l15 * 136 + ko];
    bf16x8 a1 = *(const bf16x8*)&Al[(16 + l15) * 136 + ko];
    acc[0][0] = __builtin_amdgcn_mfma_f32_16x16x32_bf16(a0, w.v[0][kc], acc[0][0], 0, 0, 0);
    acc[0][1] = __builtin_amdgcn_mfma_f32_16x16x32_bf16(a0, w.v[1][kc], acc[0][1], 0, 0, 0);
    acc[1][0] = __builtin_amdgcn_mfma_f32_16x16x32_bf16(a1, w.v[0][kc], acc[1][0], 0, 0, 0);
    acc[1][1] = __builtin_amdgcn_mfma_f32_16x16x32_bf16(a1, w.v[1][kc], acc[1][1], 0, 0, 0);
  }
}

// stage one 32-row gathered input tile into Al (bf16). rowmap: optional compaction.
__device__ __forceinline__ void stage_A(const u16* Atab, const u16* Btab,
                                        const int* nbr, int K, const int* rowmap,
                                        int tile0, int rows, int tid, u16* Al)
{
  int r = tid & 31, k0 = (tid >> 5) * 16;
  int row = tile0 + r; if (row >= rows) row = rows - 1;
  int arow = rowmap ? rowmap[row] : row;
  const u16* ap = Atab + (long)arow * 128 + k0;
  if (K == 0) {
    *(uint4*)&Al[r * 136 + k0]     = *(const uint4*)ap;
    *(uint4*)&Al[r * 136 + k0 + 8] = *(const uint4*)(ap + 8);
  } else {
    float f[16];
    unpack16(*(const uint4*)ap, *(const uint4*)(ap + 8), f);
    float s[16];
#pragma unroll
    for (int q = 0; q < 16; ++q) s[q] = 0.f;
    for (int l = 0; l < K; ++l) {
      int id = nbr[(long)arow * K + l];
      const u16* np = Btab + (long)id * 128 + k0;
      float g[16];
      unpack16(*(const uint4*)np, *(const uint4*)(np + 8), g);
#pragma unroll
      for (int q = 0; q < 16; ++q) s[q] += g[q];
    }
    float inv = 1.f / (float)K;
#pragma unroll
    for (int q = 0; q < 16; ++q) f[q] += s[q] * inv;
    u32 p[8];
#pragma unroll
    for (int q = 0; q < 8; ++q)
      p[q] = (u32)f2bf(f[2 * q]) | ((u32)f2bf(f[2 * q + 1]) << 16);
    *(uint4*)&Al[r * 136 + k0]     = make_uint4(p[0], p[1], p[2], p[3]);
    *(uint4*)&Al[r * 136 + k0 + 8] = make_uint4(p[4], p[5], p[6], p[7]);
  }
}

// gather from RAW f32 tables with inline bf16 rounding
__device__ __forceinline__ void ld16_rnd(const float* p, float* f)
{
#pragma unroll
  for (int q4 = 0; q4 < 4; ++q4) {
    float4 v = *(const float4*)(p + q4 * 4);
    f[q4 * 4 + 0] = rnd(v.x); f[q4 * 4 + 1] = rnd(v.y);
    f[q4 * 4 + 2] = rnd(v.z); f[q4 * 4 + 3] = rnd(v.w);
  }
}

__device__ __forceinline__ void stage_A_f32(const float* Atab, const float* Btab,
                                            const int* nbr, int K,
                                            int tile0, int rows, int tid, u16* Al)
{
  int r = tid & 31, k0 = (tid >> 5) * 16;
  int row = tile0 + r; if (row >= rows) row = rows - 1;
  float f[16];
  ld16_rnd(Atab + (long)row * 128 + k0, f);
  float s[16];
#pragma unroll
  for (int q = 0; q < 16; ++q) s[q] = 0.f;
  for (int l = 0; l < K; ++l) {
    int id = nbr[(long)row * K + l];
    float g[16];
    ld16_rnd(Btab + (long)id * 128 + k0, g);
#pragma unroll
    for (int q = 0; q < 16; ++q) s[q] += g[q];
  }
  float inv = 1.f / (float)K;
#pragma unroll
  for (int q = 0; q < 16; ++q) f[q] += s[q] * inv;
  u32 p[8];
#pragma unroll
  for (int q = 0; q < 8; ++q)
    p[q] = (u32)f2bf(f[2 * q]) | ((u32)f2bf(f[2 * q + 1]) << 16);
  *(uint4*)&Al[r * 136 + k0]     = make_uint4(p[0], p[1], p[2], p[3]);
  *(uint4*)&Al[r * 136 + k0 + 8] = make_uint4(p[4], p[5], p[6], p[7]);
}

// Al := bf16(Al + mean_{l<4} Btab[nbr[arow*4+l]])
__device__ __forceinline__ void update_A(const u16* Btab, const int* nbr,
                                         const int* rowmap, int tile0, int rows,
                                         int tid, u16* Al)
{
  int r = tid & 31, k0 = (tid >> 5) * 16;
  int row = tile0 + r; if (row >= rows) row = rows - 1;
  int arow = rowmap ? rowmap[row] : row;
  float f[16];
  unpack16(*(const uint4*)&Al[r * 136 + k0], *(const uint4*)&Al[r * 136 + k0 + 8], f);
  float s[16];
#pragma unroll
  for (int q = 0; q < 16; ++q) s[q] = 0.f;
#pragma unroll
  for (int l = 0; l < 4; ++l) {
    int id = nbr[(long)arow * 4 + l];
    const u16* np = Btab + (long)id * 128 + k0;
    float g[16];
    unpack16(*(const uint4*)np, *(const uint4*)(np + 8), g);
#pragma unroll
    for (int q = 0; q < 16; ++q) s[q] += g[q];
  }
#pragma unroll
  for (int q = 0; q < 16; ++q) f[q] += s[q] * 0.25f;
  u32 p[8];
#pragma unroll
  for (int q = 0; q < 8; ++q)
    p[q] = (u32)f2bf(f[2 * q]) | ((u32)f2bf(f[2 * q + 1]) << 16);
  *(uint4*)&Al[r * 136 + k0]     = make_uint4(p[0], p[1], p[2], p[3]);
  *(uint4*)&Al[r * 136 + k0 + 8] = make_uint4(p[4], p[5], p[6], p[7]);
}

// epilogue: tanh -> global table
__device__ __forceinline__ void epi_tanh_global(const f32x4 acc[2][2], const float* cbias,
                                                u16* out, int rows, int tile0,
                                                int l15, int quad, int cw)
{
#pragma unroll
  for (int nt = 0; nt < 2; ++nt) {
    int col = cw + nt * 16 + l15;
    float cb = cbias[col];
#pragma unroll
    for (int mt = 0; mt < 2; ++mt) {
      int rbase = tile0 + mt * 16 + quad * 4;
#pragma unroll
      for (int i = 0; i < 4; ++i) {
        int row = rbase + i;
        if (row >= rows) continue;
        out[(long)row * 128 + col] = f2bf(tanh_f(acc[mt][nt][i] + cb));
      }
    }
  }
}

// epilogue: tanh -> LDS Al
__device__ __forceinline__ void epi_tanh_lds(const f32x4 acc[2][2], const float* cbias,
                                             u16* Al, int l15, int quad, int cw)
{
#pragma unroll
  for (int nt = 0; nt < 2; ++nt) {
    int col = cw + nt * 16 + l15;
    float cb = cbias[col];
#pragma unroll
    for (int mt = 0; mt < 2; ++mt)
#pragma unroll
      for (int i = 0; i < 4; ++i) {
        int rL = mt * 16 + quad * 4 + i;
        Al[rL * 136 + col] = f2bf(tanh_f(acc[mt][nt][i] + cb));
      }
  }
}

// ---------------------------------------------------------------------------
// prep2: blocks 0..312: f2+f0; 313..328: f1; 329..968: conversions, maps,
// used-qid list, small dots, zero d_out (grid-stride)
// ---------------------------------------------------------------------------
__global__ __launch_bounds__(256) void prep2(Args a, float* __restrict__ out)
{
  __shared__ __align__(16) u16 Al[32 * 136];
  const int i = blockIdx.x, tid = threadIdx.x;
  const int lane = tid & 63, wv = tid >> 6;
  const int l15 = lane & 15, quad = lane >> 4, cw = wv * 32;

  if (i < 313) {           // f2 + f0 from one gather
    const int tile0 = i * 32;
    WF w2, w0;
    load_WF_f32(a.agg_W + 2 * 16384, l15, quad, cw, w2);
    load_WF_f32(a.agg_W, l15, quad, cw, w0);
    stage_A_f32(a.emb_q, a.emb_s, a.q_nb, 4, tile0, NQd, tid, Al);
    __syncthreads();
    f32x4 acc[2][2];
    zero_acc(acc);
    mfma_WF(Al, w2, l15, quad, acc);
    epi_tanh_global(acc, a.agg_b + 256, a.tabA, NQd, tile0, l15, quad, cw);  // f2
    zero_acc(acc);
    mfma_WF(Al, w0, l15, quad, acc);
    epi_tanh_global(acc, a.agg_b, a.tabB, NQd, tile0, l15, quad, cw);        // f0
    return;
  }
  if (i < 329) {           // f1
    const int tile0 = (i - 313) * 32;
    WF w1;
    load_WF_f32(a.agg_W + 16384, l15, quad, cw, w1);
    stage_A_f32(a.emb_s, a.emb_q, a.s_nb, 10, tile0, NSd, tid, Al);
    __syncthreads();
    f32x4 acc[2][2];
    zero_acc(acc);
    mfma_WF(Al, w1, l15, quad, acc);
    epi_tanh_global(acc, a.agg_b + 128, a.tabs1, NSd, tile0, l15, quad, cw);
    return;
  }

  // conversion / scalar region
  const int T = 640 * 256;
  for (int j = (i - 329) * 256 + tid; j < 497506; j += T) {
    if (j < 320000) {
      float4 v = *(const float4*)&a.emb_q[(long)j * 4];
      ((uint2*)a.embq_bf)[j] = make_uint2(
          (u32)f2bf(v.x) | ((u32)f2bf(v.y) << 16),
          (u32)f2bf(v.z) | ((u32)f2bf(v.w) << 16));
    } else if (j < 336000) {
      int c = j - 320000;
      float4 v = *(const float4*)&a.emb_s[(long)c * 4];
      ((uint2*)a.embs_bf)[c] = make_uint2(
          (u32)f2bf(v.x) | ((u32)f2bf(v.y) << 16),
          (u32)f2bf(v.z) | ((u32)f2bf(v.w) << 16));
    } else if (j < 417920) {
      int e = j - 336000;
      int seg = e >> 14, r = e & 16383;
      int col = r >> 7, k = r & 127;
      const float* src = (seg < 3) ? (a.agg_W + seg * 16384)
                                   : (seg == 3 ? a.last_W : a.ft_W);
      a.wts[e] = f2bf(src[k * 128 + col]);
    } else if (j < 483456) {
      int e = j - 417920;
      int col = e >> 7, k = e & 127;
      a.wiht[e] = f2bf(a.W_ih[k * 512 + col]);
    } else if (j < 489824) {
      int jj = j - 483456;
      int b = jj / Td, s = jj - b * Td;
      int qid = a.question[b * Sd + s];
      a.qid_map[jj]  = qid;
      a.resp_map[jj] = a.response[b * Sd + s];
      if (atomicExch(&a.flag[qid], 1) == 0) {     // first toucher appends
        int idx = atomicAdd(a.cnt, 1);
        a.list[idx] = qid;
        a.newidx[qid] = idx;
      }
    } else if (j < 491106) {
      int s = j - 489824;
      if (s < 128) {
        float acc = 0;
        for (int e = 0; e < 128; ++e) acc += a.q_W[s * 128 + e] * a.w_W[e];
        a.qw[s] = acc;
      } else if (s < 256) {
        int d = s - 128; float acc = 0;
        for (int e = 0; e < 128; ++e) acc += a.k_W[d * 128 + e] * a.w_W[128 + e];
        a.kw[d] = acc;
      } else if (s == 256) {
        float acc = 0;
        for (int e = 0; e < 128; ++e) acc += a.q_b[e] * a.w_W[e];
        a.scal[0] = acc;
      } else if (s == 257) {
        float acc = 0;
        for (int e = 0; e < 128; ++e) acc += a.k_b[e] * a.w_W[128 + e];
        a.scal[1] = acc;
      } else {
        int e2 = s - 258, rr = e2 >> 9, col = e2 & 511;
        float acc = a.b_ih[col] + a.b_hh[col];
        for (int d = 0; d < 128; ++d) acc += a.emb_r[rr * Dd + d] * a.W_ih[(128 + d) * 512 + col];
        a.er_part[rr * 512 + col] = acc;
      }
    } else {
      out[j - 491106] = 0.f;     // zero d_out (gk_pred accumulates into it)
    }
  }
}

// ---------------------------------------------------------------------------
// chain4m: ONE launch, 240 blocks (all co-resident on 256 CUs):
//   blocks 0..15  : g1 tiles -> tabs2, then device-scope release-signal gflag
//   blocks 16..40 : pm table (independent filler)
//   blocks 41..239: chain g0 -> [acquire-wait gflag==16] -> h0 -> agg -> qt
// Deadlock-free: 240 <= 256 CUs so every block is resident; producers never
// wait on consumers.
// ---------------------------------------------------------------------------
__global__ __launch_bounds__(256) void chain4m(Args a)
{
  __shared__ __align__(16) u16 Al[32 * 136];
  const int i = blockIdx.x, tid = threadIdx.x;
  const int lane = tid & 63, wv = tid >> 6;
  const int l15 = lane & 15, quad = lane >> 4, cw = wv * 32;

  if (i < 16) {            // g1 producer: g1 = tanh((f1 + mean f2[s_nb]) @ W1 + b1)
    const int tile0 = i * 32;
    WF w1; load_WF(a.wts + 16384, l15, quad, cw, w1);
    stage_A(a.tabs1, a.tabA, a.s_nb, 10, nullptr, tile0, NSd, tid, Al);
    __syncthreads();
    f32x4 acc[2][2];
    zero_acc(acc);
    mfma_WF(Al, w1, l15, quad, acc);
    epi_tanh_global(acc, a.agg_b + 128, a.tabs2, NSd, tile0, l15, quad, cw);
    __syncthreads();       // all tabs2 stores issued block-wide
    if (tid == 0)
      __hip_atomic_fetch_add(a.gflag, 1, __ATOMIC_RELEASE, __HIP_MEMORY_SCOPE_AGENT);
    return;
  }

  if (i < 41) {            // pm: one (b,t) per thread
    int item = (i - 16) * 256 + tid;
    if (item >= NR) return;
    int b = item / Td, t = item - b * Td;
    int qn = a.question[b * Sd + t + 1];
    float am[5];
#pragma unroll
    for (int m = 0; m < 5; ++m) {
      const u16* src = (m == 0) ? a.embq_bf + (long)qn * 128
                                : a.embs_bf + (long)a.qs_sk[qn * 4 + (m - 1)] * 128;
      float s = 0.f;
      for (int k = 0; k < 128; k += 8) {
        uint4 u = *(const uint4*)&src[k];
        float f[8];
        unp2(u.x, f[0], f[1]); unp2(u.y, f[2], f[3]);
        unp2(u.z, f[4], f[5]); unp2(u.w, f[6], f[7]);
#pragma unroll
        for (int q = 0; q < 8; ++q) s = fmaf(f[q], a.kw[k + q], s);
      }
      am[m] = s + a.scal[1];
    }
    float mx = am[0];
#pragma unroll
    for (int m = 1; m < 5; ++m) mx = fmaxf(mx, am[m]);
    float ex[5], z = 0.f;
#pragma unroll
    for (int m = 0; m < 5; ++m) { ex[m] = __expf(am[m] - mx); z += ex[m]; }
    float iz = __builtin_amdgcn_rcpf(z);
#pragma unroll
    for (int m = 0; m < 5; ++m) a.pm[((long)b * PB + t) * 5 + m] = ex[m] * iz;
    return;
  }

  // chain blocks
  const int cnt = *a.cnt;
  const int tile0 = (i - 41) * 32;
  if (tile0 >= cnt) return;
  WF w0, w3, w4;
  load_WF(a.wts, l15, quad, cw, w0);
  load_WF(a.wts + 3 * 16384, l15, quad, cw, w3);
  load_WF(a.wts + 4 * 16384, l15, quad, cw, w4);
  f32x4 acc[2][2];

  // phase 0: g0 = tanh((f0 + mean f1[q_nb]) @ W0 + b0)   (independent of g1)
  stage_A(a.tabB, a.tabs1, a.q_nb, 4, a.list, tile0, cnt, tid, Al);
  __syncthreads();
  zero_acc(acc);
  mfma_WF(Al, w0, l15, quad, acc);
  __syncthreads();
  epi_tanh_lds(acc, a.agg_b, Al, l15, quad, cw);       // Al = g0
  __syncthreads();
  // wait for all 16 g1 producers (device-scope acquire)
  if (tid == 0) {
    while (__hip_atomic_load(a.gflag, __ATOMIC_ACQUIRE, __HIP_MEMORY_SCOPE_AGENT) < 16) {}
  }
  __syncthreads();
  // phase 1: h0 = tanh((g0 + mean g1[q_nb]) @ W0 + b0)
  update_A(a.tabs2, a.q_nb, a.list, tile0, cnt, tid, Al);
  __syncthreads();
  zero_acc(acc);
  mfma_WF(Al, w0, l15, quad, acc);
  __syncthreads();
  epi_tanh_lds(acc, a.agg_b, Al, l15, quad, cw);       // Al = h0
  __syncthreads();
  // phase 2: agg = tanh(h0 @ last_W + last_b)
  zero_acc(acc);
  mfma_WF(Al, w3, l15, quad, acc);
  __syncthreads();
  epi_tanh_lds(acc, a.last_b, Al, l15, quad, cw);      // Al = agg
  __syncthreads();
  // phase 3: qt = relu(agg @ ft_W + ft_b) -> compact tabA
  zero_acc(acc);
  mfma_WF(Al, w4, l15, quad, acc);
#pragma unroll
  for (int nt = 0; nt < 2; ++nt) {
    int col = cw + nt * 16 + l15;
    float cb = a.ft_b[col];
#pragma unroll
    for (int mt = 0; mt < 2; ++mt) {
      int rbase = tile0 + mt * 16 + quad * 4;
#pragma unroll
      for (int i2 = 0; i2 < 4; ++i2) {
        int row = rbase + i2;
        if (row >= cnt) continue;
        a.tabA[(long)row * 128 + col] = f2bf(fmaxf(acc[mt][nt][i2] + cb, 0.f));
      }
    }
  }
}

// gates (i,g,o) + LSTM + a_state. 199 blocks x 32 rows.
__global__ __launch_bounds__(256) void gates_k(Args a)
{
  __shared__ __align__(16) u16 Al[32 * 136];
  __shared__ float hb[32 * 132];
  const int tid = threadIdx.x;
  const int lane = tid & 63, wv = tid >> 6;
  const int l15 = lane & 15, quad = lane >> 4, cw = wv * 32;

  const int tile0 = blockIdx.x * 32;
  WF wg0, wg1, wg2;
  load_WF(a.wiht, l15, quad, cw, wg0);                     // i-gate
  load_WF(a.wiht + (long)256 * 128, l15, quad, cw, wg1);   // g-gate
  load_WF(a.wiht + (long)384 * 128, l15, quad, cw, wg2);   // o-gate
  {
    int r = tid & 31, k0 = (tid >> 5) * 16;
    int row = tile0 + r;
    int arow = a.newidx[a.qid_map[row]];                   // compact qt row
    const u16* ap = a.tabA + (long)arow * 128 + k0;
    *(uint4*)&Al[r * 136 + k0]     = *(const uint4*)ap;
    *(uint4*)&Al[r * 136 + k0 + 8] = *(const uint4*)(ap + 8);
  }
  __syncthreads();
  f32x4 acc[3][2][2];
  zero_acc(acc[0]); mfma_WF(Al, wg0, l15, quad, acc[0]);
  zero_acc(acc[1]); mfma_WF(Al, wg1, l15, quad, acc[1]);
  zero_acc(acc[2]); mfma_WF(Al, wg2, l15, quad, acc[2]);
#pragma unroll
  for (int nt = 0; nt < 2; ++nt) {
    int colL = cw + nt * 16 + l15;
#pragma unroll
    for (int mt = 0; mt < 2; ++mt) {
#pragma unroll
      for (int i = 0; i < 4; ++i) {
        int rL = mt * 16 + quad * 4 + i;
        int row = tile0 + rL;
        const float* rb = a.er_part + (long)a.resp_map[row] * 512;
        float iv = acc[0][mt][nt][i] + rb[colL];
        float gv = acc[1][mt][nt][i] + rb[256 + colL];
        float ov = acc[2][mt][nt][i] + rb[384 + colL];
        float c = sigf(iv) * tanh_f(gv);
        float h = sigf(ov) * tanh_f(c);
        a.states[(long)row * 128 + colL] = f2bf(h);
        hb[rL * 132 + colL] = h;
      }
    }
  }
  __syncthreads();
#pragma unroll
  for (int rr = 0; rr < 8; ++rr) {
    int rL = wv * 8 + rr;
    float p = hb[rL * 132 + lane] * a.qw[lane] + hb[rL * 132 + 64 + lane] * a.qw[64 + lane];
#pragma unroll
    for (int off = 32; off > 0; off >>= 1) p += __shfl_xor(p, off);
    if (lane == 0) a.a_state[tile0 + rL] = p + a.scal[0];
  }
}

// ---------------------------------------------------------------------------
// gk_pred: chunked (cy, nx-range) work units; Ql staged ONCE per chunk and
// reused across n-tiles; per-batch softmax computed in-block.
// Grid: (14 chunks, 32 b).
// ---------------------------------------------------------------------------
__global__ __launch_bounds__(256) void gk_pred(Args a, float* __restrict__ out)
{
  static const int cys[14]   = {0,1,2,3,3,4,4,5,5,6,6,7,7,7};
  static const int nx0s[14]  = {0,0,0,0,3,0,3,0,3,0,3,0,3,6};
  static const int ncnts[14] = {1,2,3,3,1,3,1,3,2,3,3,3,3,1};
  const int chunk = blockIdx.x, b = blockIdx.y;
  const int cy = cys[chunk], nx0 = nx0s[chunk], ncnt = ncnts[chunk];
  const int c0 = cy * 128;
  int c_hi = c0 + 127; if (c_hi > 994) c_hi = 994;
  const int tmax = c_hi / 5, tmin = c0 / 5;

  __shared__ __align__(16) u16 smem[21760];
  __shared__ float predl[32];
  __shared__ float evl[256];   // ev values
  __shared__ float scl[256];   // max-reduce, then inclusive scan
  u16* Ql = smem;
  u16* Sl = smem + 17408;
  const int tid = threadIdx.x;

  // per-block softmax prep
  float v = (tid < Td) ? a.a_state[b * Td + tid] : -1e30f;
  scl[tid] = v; __syncthreads();
  for (int s = 128; s > 0; s >>= 1) { if (tid < s) scl[tid] = fmaxf(scl[tid], scl[tid + s]); __syncthreads(); }
  float gmax = scl[0]; __syncthreads();
  float e = (tid < Td) ? __expf(v - gmax) : 0.f;
  evl[tid] = e;
  scl[tid] = e;
  if (tid < 32) predl[tid] = 0.f;
  __syncthreads();
  for (int off = 1; off < 256; off <<= 1) {
    float add = (tid >= off) ? scl[tid - off] : 0.f;
    __syncthreads();
    scl[tid] += add;
    __syncthreads();
  }

  // stage Ql once for this (b, cy)
  {
    int j = tid >> 1, k0 = (tid & 1) * 64;
    int col = c0 + j;
    uint4* dst = (uint4*)&Ql[j * 136 + k0];
    if (col < 995) {
      int t = col / 5, m = col - t * 5;
      int qn = a.question[b * Sd + t + 1];
      const u16* src = (m == 0) ? a.embq_bf + (long)qn * 128
                                : a.embs_bf + (long)a.qs_sk[qn * 4 + (m - 1)] * 128;
      src += k0;
#pragma unroll
      for (int q = 0; q < 8; ++q) dst[q] = ((const uint4*)src)[q];
    } else {
      uint4 z = make_uint4(0, 0, 0, 0);
#pragma unroll
      for (int q = 0; q < 8; ++q) dst[q] = z;
    }
  }

  const int lane = tid & 63, wv = tid >> 6;
  const int l15 = lane & 15, quad = lane >> 4, cw = wv * 32;

  for (int xi = 0; xi < ncnt; ++xi) {
    const int n0 = (nx0 + xi) * 32;
    __syncthreads();
    {
      int r = tid & 31, k0 = (tid >> 5) * 16;
      int n = n0 + r; if (n > 198) n = 198;
      const u16* sp = a.states + ((long)b * Td + n) * 128 + k0;
      *(uint4*)&Sl[r * 136 + k0]     = *(const uint4*)sp;
      *(uint4*)&Sl[r * 136 + k0 + 8] = *(const uint4*)(sp + 8);
    }
    __syncthreads();
    f32x4 acc[2][2];
    zero_acc(acc);
#pragma unroll
    for (int kc = 0; kc < 4; ++kc) {
      const int ko = kc * 32 + quad * 8;
      bf16x8 af[2], bfv[2];
      af[0]  = *(const bf16x8*)&Sl[l15 * 136 + ko];
      af[1]  = *(const bf16x8*)&Sl[(16 + l15) * 136 + ko];
      bfv[0] = *(const bf16x8*)&Ql[(cw + l15) * 136 + ko];
      bfv[1] = *(const bf16x8*)&Ql[(cw + 16 + l15) * 136 + ko];
#pragma unroll
      for (int mt = 0; mt < 2; ++mt)
#pragma unroll
        for (int nt = 0; nt < 2; ++nt)
          acc[mt][nt] = __builtin_amdgcn_mfma_f32_16x16x32_bf16(af[mt], bfv[nt], acc[mt][nt], 0, 0, 0);
    }

#pragma unroll
    for (int nt = 0; nt < 2; ++nt) {
      int col = c0 + cw + nt * 16 + l15;
      if (col >= 995) continue;
      int t = col / 5, m = col - t * 5;
      float pmv = a.pm[((long)b * PB + t) * 5 + m];
      float part = 0.f;
#pragma unroll
      for (int mt = 0; mt < 2; ++mt) {
        int nb = n0 + mt * 16 + quad * 4;
        if (nb > t) continue;
#pragma unroll
        for (int i = 0; i < 4; ++i) {
          int n = nb + i;
          if (n > t || n > 198) continue;
          part += evl[n] * sigf(acc[mt][nt][i]);
        }
      }
      part *= pmv;
      if (part != 0.f) atomicAdd(&predl[t - tmin], part);
    }
  }
  __syncthreads();
  const int tcnt = tmax - tmin + 1;
  if (tid < tcnt) {
    int t = tmin + tid;
    float pv = predl[tid];
    if (pv != 0.f)
      atomicAdd(&out[b * Sd + t + 1], pv * (1.f / scl[t]));
  }
}

// ---------------------------------------------------------------------------
extern "C" void kernel_launch(void* const* d_in, const int* in_sizes, int n_in,
                              void* d_out, int out_size, void* d_ws, size_t ws_size,
                              hipStream_t stream)
{
  Args a;
  a.question = (const int*)d_in[0];
  a.response = (const int*)d_in[1];
  a.q_nb     = (const int*)d_in[3];
  a.s_nb     = (const int*)d_in[4];
  a.qs_sk    = (const int*)d_in[5];
  a.emb_q    = (const float*)d_in[6];
  a.emb_s    = (const float*)d_in[7];
  a.emb_r    = (const float*)d_in[8];
  a.W_ih     = (const float*)d_in[9];
  a.b_ih     = (const float*)d_in[10];
  a.b_hh     = (const float*)d_in[11];
  a.ft_W     = (const float*)d_in[12];
  a.ft_b     = (const float*)d_in[13];
  a.agg_W    = (const float*)d_in[14];
  a.agg_b    = (const float*)d_in[15];
  a.last_W   = (const float*)d_in[16];
  a.last_b   = (const float*)d_in[17];
  a.q_W      = (const float*)d_in[18];
  a.q_b      = (const float*)d_in[19];
  a.k_W      = (const float*)d_in[20];
  a.k_b      = (const float*)d_in[21];
  a.w_W      = (const float*)d_in[22];

  u16* wsu = (u16*)d_ws;
  const long NT = 1280000, ST = 64000, RT = (long)NR * Dd;
  a.tabA  = wsu;                 // NT (f2, later compact qt)
  a.tabB  = a.tabA + NT;         // NT (f0)
  a.tabs1 = a.tabB + NT;         // ST (f1)
  a.tabs2 = a.tabs1 + ST;        // ST (g1)
  a.states  = a.tabs2 + ST;      // RT
  a.embq_bf = a.states + RT;     // NT
  a.embs_bf = a.embq_bf + NT;    // ST
  a.wts     = a.embs_bf + ST;    // 5*16384
  a.wiht    = a.wts + 5 * 16384; // 65536
  float* fp = (float*)(a.wiht + 65536);
  a.a_state = fp;                       // 6368
  a.qw      = fp + 6368;                // 128
  a.kw      = fp + 6496;                // 128
  a.scal    = fp + 6624;                // 16
  a.er_part = fp + 6640;                // 1024
  a.pm      = fp + 7664;                // 32*208*5
  a.qid_map  = (int*)(a.pm + 32 * PB * 5);
  a.resp_map = a.qid_map + NR;
  a.flag     = a.resp_map + NR;         // 10000  (memset 0)
  a.cnt      = a.flag + NQd;            // cnt[0]; cnt[1] = gflag (memset 0)
  a.gflag    = a.cnt + 1;
  a.list     = a.cnt + 4;               // 10000
  a.newidx   = a.list + NQd;            // 10000

  float* out = (float*)d_out;

  hipMemsetAsync(a.flag, 0, (NQd + 4) * sizeof(int), stream);  // flag + cnt + gflag
  prep2<<<969, 256, 0, stream>>>(a, out);      // conv | f2+f0 | f1 all-in-one
  chain4m<<<240, 256, 0, stream>>>(a);         // g1 | pm | g0->h0->agg->qt
  gates_k<<<199, 256, 0, stream>>>(a);
  gk_pred<<<dim3(14, Bd), 256, 0, stream>>>(a, out);
}